// Round 8
// baseline (485.395 us; speedup 1.0000x reference)
//
#include <hip/hip_runtime.h>
#include <hip/hip_bf16.h>
#include <math.h>

// ---------- constants ----------
#define Bsz 4
#define Cin 512
#define Hh 16
#define Ww 16
#define Lsp 256
#define DIM 128
#define DM 1024      // dim*4 + 512
#define DI 2048
#define KK 4
#define NST 16
#define RR 64
#define PW 384       // K*96 projection rows
#define NCH 4
#define CHUNK 64     // Lsp / NCH

// ---------- ws layout (floats) — round-4 proven layout ----------
#define OFF_FEAT    0u
#define SZ_FEAT     (Bsz*Lsp*DM)                 // 1048576
#define OFF_POOLED  (OFF_FEAT + SZ_FEAT)
#define SZ_POOLED   (Bsz*Cin*275)                // 563200
#define OFF_PCONV   (OFF_POOLED + SZ_POOLED)
#define SZ_PCONV    (Bsz*275*DIM)                // 140800
#define OFF_Y0M     (OFF_PCONV + SZ_PCONV)
#define SZ_Y0M      (Bsz*DIM)                    // 512
#define OFF_XZ      (OFF_Y0M + SZ_Y0M)
#define SZ_XZ       (Bsz*Lsp*2*DI)               // 4194304
#define OFF_XCT     (OFF_XZ + SZ_XZ)
#define SZ_XCT      (Bsz*Lsp*DI)                 // 2097152
#define OFF_XDBL    (OFF_XCT + SZ_XCT)
#define SZ_XDBL     (Bsz*Lsp*PW)                 // 393216  (P matrix f32)
#define OFF_DELTA   (OFF_XDBL + SZ_XDBL)
#define SZ_DELTA    (Bsz*KK*Lsp*DI)              // 8388608 (delta_scan f32)
#define OFF_OUTY    (OFF_DELTA + SZ_DELTA)
#define SZ_OUTY     (Bsz*KK*Lsp*DI)              // 8388608 (oyB bf16 + Pa + Hend)
#define OFF_YG      (OFF_OUTY + SZ_OUTY)
#define SZ_YG       (Bsz*Lsp*DI)                 // 2097152 (Hstart)
#define OFF_O1      (OFF_YG + SZ_YG)
#define SZ_O1       (Bsz*Lsp*DM)                 // 1048576 (xcB then o1B)
#define OFF_O2      (OFF_O1 + SZ_O1)
#define SZ_O2       (Bsz*Lsp*DIM)                // 131072
#define WS_FLOATS   (OFF_O2 + SZ_O2)

typedef __attribute__((ext_vector_type(8))) short short8;
typedef __attribute__((ext_vector_type(4))) float f32x4;

__device__ __forceinline__ short f2bf(float x) {
  __hip_bfloat16 h = __float2bfloat16(x);
  short s;
  __builtin_memcpy(&s, &h, 2);
  return s;
}
__device__ __forceinline__ float bf2f(short s) {
  unsigned u = ((unsigned)(unsigned short)s) << 16;
  float f;
  __builtin_memcpy(&f, &u, 4);
  return f;
}

// ---------- f32 -> bf16 bulk convert (n multiple of 8) ----------
__global__ __launch_bounds__(256) void f2bf_kernel(const float* __restrict__ in,
    short* __restrict__ out, int n) {
  int i = (blockIdx.x*256 + threadIdx.x)*8;
  if (i >= n) return;
  float4 a = *(const float4*)(in + i);
  float4 b = *(const float4*)(in + i + 4);
  short8 o;
  o[0]=f2bf(a.x); o[1]=f2bf(a.y); o[2]=f2bf(a.z); o[3]=f2bf(a.w);
  o[4]=f2bf(b.x); o[5]=f2bf(b.y); o[6]=f2bf(b.z); o[7]=f2bf(b.w);
  *(short8*)(out + i) = o;
}

// ---------- pool layer 0: conv1x1+BN+ReLU then global mean (ILP version) ----------
__global__ __launch_bounds__(256) void pool0_kernel(
    const float* __restrict__ x, const float* __restrict__ pw, const float* __restrict__ pb,
    const float* __restrict__ g, const float* __restrict__ bb,
    const float* __restrict__ m, const float* __restrict__ v, float* __restrict__ y0m) {
  int bd = blockIdx.x;             // b*128+d
  int b = bd >> 7, d = bd & 127;
  int l = threadIdx.x;
  const float* xb = x + (b*Cin)*Lsp + l;
  const float* w = pw + d*Cin;
  float a0 = 0.f, a1 = 0.f, a2 = 0.f, a3 = 0.f;
  #pragma unroll 4
  for (int c = 0; c < Cin; c += 4) {
    float4 wv = *(const float4*)(w + c);
    a0 += xb[(c+0)*Lsp] * wv.x;
    a1 += xb[(c+1)*Lsp] * wv.y;
    a2 += xb[(c+2)*Lsp] * wv.z;
    a3 += xb[(c+3)*Lsp] * wv.w;
  }
  float s = (a0 + a1) + (a2 + a3) + pb[d];
  float inv = g[d] * rsqrtf(v[d] + 1e-5f);
  s = s*inv + (bb[d] - m[d]*inv);
  s = fmaxf(s, 0.f);
  __shared__ float red[256];
  red[l] = s; __syncthreads();
  for (int off = 128; off > 0; off >>= 1) {
    if (l < off) red[l] += red[l+off];
    __syncthreads();
  }
  if (l == 0) y0m[bd] = red[0] * (1.f/256.f);
}

// ---------- adaptive avg pool of x to 5x5,9x9,13x13 (concatenated 275 positions) ----------
__device__ __forceinline__ void decode_pos(int pos, int& s, int& pp, int& qq, int& layer) {
  if (pos < 25)       { s = 5;  layer = 1; int t = pos;       pp = t/5;  qq = t%5;  }
  else if (pos < 106) { s = 9;  layer = 2; int t = pos - 25;  pp = t/9;  qq = t%9;  }
  else                { s = 13; layer = 3; int t = pos - 106; pp = t/13; qq = t%13; }
}

__global__ void pool_avg_kernel(const float* __restrict__ x, float* __restrict__ pooled) {
  int bc = blockIdx.x;             // b*512+c
  int pos = threadIdx.x;
  if (pos >= 275) return;
  int s, pp, qq, layer;
  decode_pos(pos, s, pp, qq, layer);
  int hs = (pp*Hh)/s, he = ((pp+1)*Hh + s-1)/s;
  int ws = (qq*Ww)/s, we = ((qq+1)*Ww + s-1)/s;
  const float* xb = x + (size_t)bc*Lsp;
  float acc = 0.f;
  for (int hh = hs; hh < he; ++hh)
    for (int ww2 = ws; ww2 < we; ++ww2)
      acc += xb[hh*Ww + ww2];
  pooled[(size_t)bc*275 + pos] = acc / (float)((he-hs)*(we-ws));
}

// ---------- conv1x1 + BN + ReLU on pooled features (ILP version) ----------
__global__ void pconv_kernel(const float* __restrict__ pooled, const float* __restrict__ pw,
    const float* __restrict__ pb, const float* __restrict__ g, const float* __restrict__ bb,
    const float* __restrict__ m, const float* __restrict__ v, float* __restrict__ pconv) {
  int bp = blockIdx.x;             // b*275+pos
  int b = bp / 275, pos = bp % 275;
  int d = threadIdx.x;             // 0..127
  int s, pp, qq, layer;
  decode_pos(pos, s, pp, qq, layer);
  const float* pc = pooled + b*Cin*275 + pos;
  const float* w = pw + (layer*DIM + d)*Cin;
  float a0 = 0.f, a1 = 0.f, a2 = 0.f, a3 = 0.f;
  #pragma unroll 4
  for (int c = 0; c < Cin; c += 4) {
    float4 wv = *(const float4*)(w + c);
    a0 += pc[(c+0)*275] * wv.x;
    a1 += pc[(c+1)*275] * wv.y;
    a2 += pc[(c+2)*275] * wv.z;
    a3 += pc[(c+3)*275] * wv.w;
  }
  float acc = (a0 + a1) + (a2 + a3) + pb[layer*DIM + d];
  int ld = layer*DIM + d;
  float inv = g[ld] * rsqrtf(v[ld] + 1e-5f);
  acc = acc*inv + (bb[ld] - m[ld]*inv);
  pconv[bp*DIM + d] = fmaxf(acc, 0.f);
}

// ---------- assemble feat (B,L,1024) in bf16 ----------
__global__ __launch_bounds__(256) void feat_kernel(const float* __restrict__ x,
    const float* __restrict__ y0m, const float* __restrict__ pconv, short* __restrict__ featB) {
  int bl = blockIdx.x;             // b*256+l
  int b = bl >> 8, l = bl & 255;
  int h = l >> 4, w = l & 15;
  for (int c = threadIdx.x; c < DM; c += 256) {
    float val;
    if (c < Cin) {
      val = x[(b*Cin + c)*Lsp + l];
    } else if (c < Cin + DIM) {
      val = y0m[b*DIM + (c - Cin)];
    } else {
      int i = (c - (Cin+DIM)) >> 7;          // 0,1,2 -> s=5,9,13
      int d = (c - (Cin+DIM)) & 127;
      int s = (i==0) ? 5 : (i==1) ? 9 : 13;
      int off = (i==0) ? 0 : (i==1) ? 25 : 106;
      float scale = (float)s / 16.f;
      float sh = fmaxf((h + 0.5f)*scale - 0.5f, 0.f);
      int h0 = min((int)sh, s-1); float wh = sh - (float)h0; int h1 = min(h0+1, s-1);
      float sw = fmaxf((w + 0.5f)*scale - 0.5f, 0.f);
      int w0 = min((int)sw, s-1); float ww2 = sw - (float)w0; int w1 = min(w0+1, s-1);
      const float* pc = pconv + b*275*DIM;
      float v00 = pc[(off + h0*s + w0)*DIM + d];
      float v01 = pc[(off + h0*s + w1)*DIM + d];
      float v10 = pc[(off + h1*s + w0)*DIM + d];
      float v11 = pc[(off + h1*s + w1)*DIM + d];
      val = (1.f-wh)*((1.f-ww2)*v00 + ww2*v01) + wh*((1.f-ww2)*v10 + ww2*v11);
    }
    featB[bl*DM + c] = f2bf(val);
  }
}

// scan-direction spatial index map (l -> sp)
__device__ __forceinline__ int dir_map(int k, int l) {
  if (k == 0) return l;
  if (k == 1) return ((l & 15) << 4) | (l >> 4);
  if (k == 2) return 255 - l;
  int m = 255 - l; return ((m & 15) << 4) | (m >> 4);
}
// inverse map (sp -> scan l) per direction
__device__ __forceinline__ int inv_map(int k, int sp) {
  int t = ((sp & 15) << 4) | (sp >> 4);
  if (k == 0) return sp;
  if (k == 1) return t;
  if (k == 2) return 255 - sp;
  return 255 - t;
}

// ---------- bf16 MFMA GEMM: C[M][N] = A[M][K] * B[N][K]^T ----------
// MODE 0: f32 store.  MODE 1: bf16 store.  MODE 2: f32 softplus(acc + bias[col]).
// MODE 4: delta: dl=softplus(acc+bias[col]); du=dl*u; both stored at scan-order row.
__device__ __forceinline__ void gload_lds16(const short* g, short* l) {
  __builtin_amdgcn_global_load_lds((const __attribute__((address_space(1))) void*)g,
                                   (__attribute__((address_space(3))) void*)l, 16, 0, 0);
}

template<int MODE>
__global__ __launch_bounds__(256) void gemm_bf(const short* __restrict__ Ag,
    const short* __restrict__ Bg, void* __restrict__ Cout, const float* __restrict__ bias,
    int M, int N, int K, int lda, int ldb,
    const short* __restrict__ xcb, short* __restrict__ duo, int kdir) {
  __shared__ short Als[128*64];
  __shared__ short Bls[128*64];
  int tid = threadIdx.x;
  int w = tid >> 6, lane = tid & 63;
  int wm = w >> 1, wn = w & 1;
  int row0 = blockIdx.y * 128, col0 = blockIdx.x * 128;
  f32x4 acc[4][4];
  #pragma unroll
  for (int i = 0; i < 4; ++i)
    #pragma unroll
    for (int j = 0; j < 4; ++j)
      acc[i][j] = (f32x4){0.f, 0.f, 0.f, 0.f};

  for (int k0 = 0; k0 < K; k0 += 64) {
    #pragma unroll
    for (int i = 0; i < 4; ++i) {
      int slot = i*256 + w*64 + lane;
      int r = slot >> 3, pc = slot & 7;
      int c = pc ^ (r & 7);
      gload_lds16(Ag + (size_t)(row0 + r)*lda + k0 + c*8, &Als[(i*256 + w*64)*8]);
      gload_lds16(Bg + (size_t)(col0 + r)*ldb + k0 + c*8, &Bls[(i*256 + w*64)*8]);
    }
    __syncthreads();
    #pragma unroll
    for (int ks = 0; ks < 2; ++ks) {
      short8 af[4], bfr[4];
      int rsel = lane & 15, csel = ks*4 + (lane >> 4);
      #pragma unroll
      for (int mi = 0; mi < 4; ++mi) {
        int row = wm*64 + mi*16 + rsel;
        af[mi] = *(const short8*)&Als[row*64 + ((csel ^ (row & 7)) << 3)];
      }
      #pragma unroll
      for (int ni = 0; ni < 4; ++ni) {
        int row = wn*64 + ni*16 + rsel;
        bfr[ni] = *(const short8*)&Bls[row*64 + ((csel ^ (row & 7)) << 3)];
      }
      #pragma unroll
      for (int mi = 0; mi < 4; ++mi)
        #pragma unroll
        for (int ni = 0; ni < 4; ++ni)
          acc[mi][ni] = __builtin_amdgcn_mfma_f32_16x16x32_bf16(af[mi], bfr[ni], acc[mi][ni], 0, 0, 0);
    }
    __syncthreads();
  }
  // epilogue: D row = (lane>>4)*4 + j, col = lane&15
  #pragma unroll
  for (int mi = 0; mi < 4; ++mi) {
    int rbase = row0 + wm*64 + mi*16 + ((lane >> 4) << 2);
    #pragma unroll
    for (int ni = 0; ni < 4; ++ni) {
      int colg = col0 + wn*64 + ni*16 + (lane & 15);
      #pragma unroll
      for (int j = 0; j < 4; ++j) {
        if (MODE == 1) {
          ((short*)Cout)[(size_t)(rbase + j)*N + colg] = f2bf(acc[mi][ni][j]);
        } else if (MODE == 2) {
          float sv = acc[mi][ni][j] + bias[colg];
          ((float*)Cout)[(size_t)(rbase + j)*N + colg] = (sv > 20.f) ? sv : log1pf(__expf(sv));
        } else if (MODE == 4) {
          int rowg = rbase + j;                 // b*256 + sp
          int b_ = rowg >> 8, sp_ = rowg & 255;
          int lsc = inv_map(kdir, sp_);
          float dl = acc[mi][ni][j] + bias[colg];
          dl = (dl > 20.f) ? dl : log1pf(__expf(dl));
          float ul = bf2f(xcb[(size_t)rowg*N + colg]);   // N == DI
          size_t oidx = (size_t)(b_*Lsp + lsc)*N + colg;
          ((float*)Cout)[oidx] = dl;
          duo[oidx] = f2bf(dl*ul);
        } else {
          ((float*)Cout)[(size_t)(rbase + j)*N + colg] = acc[mi][ni][j];
        }
      }
    }
  }
}

// ---------- depthwise 3x3 conv + bias + silu -> xcB (bf16); xz is bf16 now ----------
__global__ __launch_bounds__(256) void dwconv_kernel(const short* __restrict__ xzB,
    const float* __restrict__ cw, const float* __restrict__ cb, short* __restrict__ xcB) {
  int bl = blockIdx.x;
  int b = bl >> 8, l = bl & 255;
  int h = l >> 4, w = l & 15;
  const short* xzb = xzB + (size_t)b*Lsp*(2*DI);
  for (int d = threadIdx.x; d < DI; d += 256) {
    float s = 0.f;
    #pragma unroll
    for (int dh = -1; dh <= 1; ++dh) {
      int hh = h + dh; if (hh < 0 || hh > 15) continue;
      #pragma unroll
      for (int dw = -1; dw <= 1; ++dw) {
        int ww2 = w + dw; if (ww2 < 0 || ww2 > 15) continue;
        s += bf2f(xzb[(size_t)(hh*16 + ww2)*(2*DI) + d]) * cw[d*9 + (dh+1)*3 + (dw+1)];
      }
    }
    s += cb[d];
    float r = s / (1.f + __expf(-s));   // silu
    xcB[((size_t)b*Lsp + l)*DI + d] = f2bf(r);
  }
}

// ---------- pack B/C columns of P into scan order: PS[(k*4+b)][l][32] ----------
__global__ __launch_bounds__(256) void ps_build(const float* __restrict__ P,
    float* __restrict__ PS) {
  int slab = blockIdx.x;           // k*4 + b
  int k = slab >> 2, b = slab & 3;
  int l = threadIdx.x;
  int sp = dir_map(k, l);
  const float* src = P + (size_t)(b*Lsp + sp)*PW + k*96 + RR;   // 32 floats: B then C
  float* dst = PS + ((size_t)slab*Lsp + l)*32;
  #pragma unroll
  for (int n = 0; n < 32; n += 4)
    *(float4*)(dst + n) = *(const float4*)(src + n);
}

// ---------- scan pass 1: per-chunk local scan -> Pa (decay product), Hend ----------
__global__ __launch_bounds__(256) void scan_pass1(const float* __restrict__ dls,
    const short* __restrict__ dus, const float* __restrict__ PS,
    const float* __restrict__ A_logs, float* __restrict__ Pa, float* __restrict__ Hend) {
  int bk = blockIdx.x;             // b*4+k
  int b = bk >> 2, k = bk & 3;
  int slab = k*Bsz + b;
  int tid = threadIdx.x;
  int wv = tid >> 6, lane = tid & 63;
  int dloc = lane >> 2, ng = lane & 3;
  int d = blockIdx.y*64 + wv*16 + dloc;
  int c = blockIdx.z;
  int n0 = ng*4;
  const float LOG2E = 1.4426950408889634f;
  float A2[4], h[4] = {0.f,0.f,0.f,0.f}, pa[4] = {1.f,1.f,1.f,1.f};
  #pragma unroll
  for (int j = 0; j < 4; ++j)
    A2[j] = -__expf(A_logs[((size_t)k*DI + d)*NST + n0 + j]) * LOG2E;
  const float* dlp = dls + (size_t)slab*Lsp*DI;
  const short* dup = dus + (size_t)slab*Lsp*DI;
  const float* ps  = PS + (size_t)slab*Lsp*32;
  for (int l = c*CHUNK; l < (c+1)*CHUNK; ++l) {
    float dl = dlp[(size_t)l*DI + d];
    float du = bf2f(dup[(size_t)l*DI + d]);
    float4 Bv = *(const float4*)(ps + l*32 + n0);
    float e0 = exp2f(dl*A2[0]); h[0] = h[0]*e0 + du*Bv.x; pa[0] *= e0;
    float e1 = exp2f(dl*A2[1]); h[1] = h[1]*e1 + du*Bv.y; pa[1] *= e1;
    float e2 = exp2f(dl*A2[2]); h[2] = h[2]*e2 + du*Bv.z; pa[2] *= e2;
    float e3 = exp2f(dl*A2[3]); h[3] = h[3]*e3 + du*Bv.w; pa[3] *= e3;
  }
  size_t base = ((size_t)(c*16 + bk)*DI + d)*NST + n0;
  #pragma unroll
  for (int j = 0; j < 4; ++j) {
    Pa[base + j] = pa[j];
    Hend[base + j] = h[j];
  }
}

// ---------- combine chunk boundaries ----------
__global__ __launch_bounds__(256) void scan_combine(const float* __restrict__ Pa,
    const float* __restrict__ Hend, float* __restrict__ Hstart) {
  int idx = blockIdx.x*256 + threadIdx.x;    // (bk*DI + d)*16 + n
  const int stride = 16*DI*NST;              // 524288
  float h = 0.f;
  #pragma unroll
  for (int c = 0; c < NCH; ++c) {
    Hstart[c*stride + idx] = h;
    h = Pa[c*stride + idx]*h + Hend[c*stride + idx];
  }
}

// ---------- scan pass 2: rescan with correct Hstart, emit y (bf16) ----------
__global__ __launch_bounds__(256) void scan_pass2(const float* __restrict__ dls,
    const short* __restrict__ dus, const float* __restrict__ PS,
    const float* __restrict__ A_logs, const float* __restrict__ Hstart,
    short* __restrict__ oyB) {
  int bk = blockIdx.x;             // b*4+k
  int b = bk >> 2, k = bk & 3;
  int slab = k*Bsz + b;
  int tid = threadIdx.x;
  int wv = tid >> 6, lane = tid & 63;
  int dloc = lane >> 2, ng = lane & 3;
  int d = blockIdx.y*64 + wv*16 + dloc;
  int c = blockIdx.z;
  int n0 = ng*4;
  const float LOG2E = 1.4426950408889634f;
  float A2[4], h[4];
  #pragma unroll
  for (int j = 0; j < 4; ++j)
    A2[j] = -__expf(A_logs[((size_t)k*DI + d)*NST + n0 + j]) * LOG2E;
  size_t hbase = ((size_t)(c*16 + bk)*DI + d)*NST + n0;
  #pragma unroll
  for (int j = 0; j < 4; ++j) h[j] = Hstart[hbase + j];
  const float* dlp = dls + (size_t)slab*Lsp*DI;
  const short* dup = dus + (size_t)slab*Lsp*DI;
  const float* ps  = PS + (size_t)slab*Lsp*32;
  short* oy = oyB + (size_t)bk*Lsp*DI;
  for (int l = c*CHUNK; l < (c+1)*CHUNK; ++l) {
    float dl = dlp[(size_t)l*DI + d];
    float du = bf2f(dup[(size_t)l*DI + d]);
    float4 Bv = *(const float4*)(ps + l*32 + n0);
    float4 Cv = *(const float4*)(ps + l*32 + 16 + n0);
    float y;
    float e0 = exp2f(dl*A2[0]); h[0] = h[0]*e0 + du*Bv.x; y  = h[0]*Cv.x;
    float e1 = exp2f(dl*A2[1]); h[1] = h[1]*e1 + du*Bv.y; y += h[1]*Cv.y;
    float e2 = exp2f(dl*A2[2]); h[2] = h[2]*e2 + du*Bv.z; y += h[2]*Cv.z;
    float e3 = exp2f(dl*A2[3]); h[3] = h[3]*e3 + du*Bv.w; y += h[3]*Cv.w;
    y += __shfl_xor(y, 1);
    y += __shfl_xor(y, 2);
    if (ng == 0) oy[(size_t)l*DI + d] = f2bf(y);
  }
}

// ---------- combine 4 directions + D*u + LayerNorm + gate with silu(z) -> bf16 ----------
__global__ __launch_bounds__(256) void combine_ln_kernel(const short* __restrict__ oyB,
    const short* __restrict__ xzB, const short* __restrict__ xcB,
    const float* __restrict__ Ds, const float* __restrict__ lng,
    const float* __restrict__ lnb, short* __restrict__ ygB) {
  int bl = blockIdx.x;
  int b = bl >> 8, l = bl & 255;
  int h = l >> 4, w = l & 15;
  int lT = (w << 4) | h;
  const short* oy = oyB + (size_t)b*KK*Lsp*DI;
  float vals[8];
  float sum = 0.f, sumsq = 0.f;
  #pragma unroll
  for (int i = 0; i < 8; ++i) {
    int d = threadIdx.x + i*256;
    float dsum = Ds[d] + Ds[DI + d] + Ds[2*DI + d] + Ds[3*DI + d];
    float yv = bf2f(oy[(size_t)(0*Lsp + l       )*DI + d])
             + bf2f(oy[(size_t)(2*Lsp + (255-l ))*DI + d])
             + bf2f(oy[(size_t)(1*Lsp + lT      )*DI + d])
             + bf2f(oy[(size_t)(3*Lsp + (255-lT))*DI + d])
             + bf2f(xcB[(size_t)bl*DI + d]) * dsum;
    vals[i] = yv; sum += yv; sumsq += yv*yv;
  }
  __shared__ float r1[256], r2[256];
  r1[threadIdx.x] = sum; r2[threadIdx.x] = sumsq; __syncthreads();
  for (int off = 128; off > 0; off >>= 1) {
    if (threadIdx.x < off) { r1[threadIdx.x] += r1[threadIdx.x+off]; r2[threadIdx.x] += r2[threadIdx.x+off]; }
    __syncthreads();
  }
  float mu = r1[0] * (1.f/2048.f);
  float var = r2[0] * (1.f/2048.f) - mu*mu;
  float rstd = rsqrtf(var + 1e-5f);
  const short* zrow = xzB + (size_t)bl*(2*DI) + DI;
  #pragma unroll
  for (int i = 0; i < 8; ++i) {
    int d = threadIdx.x + i*256;
    float z = bf2f(zrow[d]);
    float sz = z / (1.f + __expf(-z));
    ygB[(size_t)bl*DI + d] = f2bf(((vals[i]-mu)*rstd*lng[d] + lnb[d]) * sz);
  }
}

// ---------- cbr epilogue: bias + BN + exact GELU, write NCHW ----------
__global__ void cbr_epilogue(const float* __restrict__ o2, const float* __restrict__ cb,
    const float* __restrict__ g, const float* __restrict__ beta, const float* __restrict__ m_,
    const float* __restrict__ v_, float* __restrict__ out) {
  int idx = blockIdx.x*256 + threadIdx.x;   // (b*128+dd)*256 + l
  int l = idx & 255;
  int rest = idx >> 8;
  int dd = rest & 127;
  int b = rest >> 7;
  float s = o2[((size_t)b*Lsp + l)*DIM + dd] + cb[dd];
  float inv = g[dd] * rsqrtf(v_[dd] + 1e-5f);
  s = s*inv + (beta[dd] - m_[dd]*inv);
  out[idx] = s * 0.5f * (1.f + erff(s * 0.70710678118f));
}

extern "C" void kernel_launch(void* const* d_in, const int* in_sizes, int n_in,
                              void* d_out, int out_size, void* d_ws, size_t ws_size,
                              hipStream_t stream) {
  const float* x        = (const float*)d_in[0];
  const float* pool_w   = (const float*)d_in[1];
  const float* pool_b   = (const float*)d_in[2];
  const float* bn_g     = (const float*)d_in[3];
  const float* bn_b     = (const float*)d_in[4];
  const float* bn_m     = (const float*)d_in[5];
  const float* bn_v     = (const float*)d_in[6];
  const float* in_proj_w= (const float*)d_in[7];
  const float* conv_w   = (const float*)d_in[8];
  const float* conv_b   = (const float*)d_in[9];
  const float* x_proj_w = (const float*)d_in[10];
  const float* dt_w     = (const float*)d_in[11];
  const float* dt_b     = (const float*)d_in[12];
  const float* A_logs   = (const float*)d_in[13];
  const float* Ds       = (const float*)d_in[14];
  const float* ln_g     = (const float*)d_in[15];
  const float* ln_b     = (const float*)d_in[16];
  const float* out_proj_w=(const float*)d_in[17];
  const float* cbr_w    = (const float*)d_in[18];
  const float* cbr_b    = (const float*)d_in[19];
  const float* cbr_g    = (const float*)d_in[20];
  const float* cbr_beta = (const float*)d_in[21];
  const float* cbr_m    = (const float*)d_in[22];
  const float* cbr_v    = (const float*)d_in[23];
  float* out = (float*)d_out;

  if (ws_size < (size_t)WS_FLOATS * sizeof(float)) return;
  float* ws = (float*)d_ws;
  float* pooled   = ws + OFF_POOLED;
  float* pconv    = ws + OFF_PCONV;
  float* y0m      = ws + OFF_Y0M;
  float* P        = ws + OFF_XDBL;
  float* delta_sc = ws + OFF_DELTA;                    // scan-order dl (f32)
  float* o2       = ws + OFF_O2;

  // overlays (lifetimes audited):
  short* featB = (short*)(ws + OFF_POOLED);            // written end A (pooled dead), read B
  float* PS    = ws + OFF_POOLED;                      // written after D (featB dead), read F (131072 fl)
  short* xzB   = (short*)(ws + OFF_XZ);                // written B (bf16, 2097152 fl), read C & G
  short* du_sc = (short*)(ws + OFF_XZ + 2097152);      // written E, read F (4194304 fl = rest of XZ + XCT)
  short* wInB  = (short*)(ws + OFF_DELTA);             // read B; delta_sc written E
  short* wXB   = (short*)(ws + OFF_DELTA + 2097152);   // read D; delta_sc written E
  short* wOB   = (short*)(ws + OFF_FEAT);              // read H
  short* wCB   = (short*)(ws + OFF_PCONV);             // written after feat (pconv dead), read I
  short* xcB   = (short*)(ws + OFF_O1);                // written C, read E (gemm) & G; o1B after
  short* oyB   = (short*)(ws + OFF_OUTY);              // written pass2, read G
  float* Pa    = ws + OFF_OUTY + 4194304;              // written pass1, read combine
  float* Hend  = ws + OFF_OUTY + 4194304 + 2097152;    // written pass1, read combine
  short* dtwB  = (short*)(ws + OFF_OUTY + 4194304);    // read E; Pa written pass1 (after E)
  short* PB    = (short*)(ws + OFF_OUTY + 4194304 + 262144); // written after D, read E
  float* Hstart= ws + OFF_YG;                          // written combine, read pass2
  short* ygB   = (short*)(ws + OFF_DELTA);             // written G (delta_sc dead), read H
  short* o1B   = (short*)(ws + OFF_O1);                // written H, read I

  // stage A: pyramid pooling
  pool0_kernel<<<Bsz*DIM, 256, 0, stream>>>(x, pool_w, pool_b, bn_g, bn_b, bn_m, bn_v, y0m);
  pool_avg_kernel<<<Bsz*Cin, 288, 0, stream>>>(x, pooled);
  pconv_kernel<<<Bsz*275, 128, 0, stream>>>(pooled, pool_w, pool_b, bn_g, bn_b, bn_m, bn_v, pconv);
  feat_kernel<<<Bsz*Lsp, 256, 0, stream>>>(x, y0m, pconv, featB);

  // weight conversions
  f2bf_kernel<<<(4096*1024)/2048, 256, 0, stream>>>(in_proj_w, wInB, 4096*1024);
  f2bf_kernel<<<(PW*2048)/2048,   256, 0, stream>>>(x_proj_w,  wXB,  PW*2048);
  f2bf_kernel<<<(1024*2048)/2048, 256, 0, stream>>>(out_proj_w, wOB, 1024*2048);
  f2bf_kernel<<<(DIM*1024)/2048,  256, 0, stream>>>(cbr_w,      wCB, DIM*1024);
  f2bf_kernel<<<(KK*DI*RR)/2048,  256, 0, stream>>>(dt_w,       dtwB, KK*DI*RR);

  // stage B: in_proj GEMM (M=1024, N=4096, K=1024), bf16 out
  gemm_bf<1><<<dim3(4096/128, 1024/128), 256, 0, stream>>>(featB, wInB, xzB, nullptr,
      1024, 4096, 1024, 1024, 1024, nullptr, nullptr, 0);

  // stage C: depthwise conv + silu -> bf16
  dwconv_kernel<<<Bsz*Lsp, 256, 0, stream>>>(xzB, conv_w, conv_b, xcB);

  // stage D: x_proj GEMM: P[1024x384] = xcB * wXB^T (K=2048), f32 out
  gemm_bf<0><<<dim3(PW/128, 1024/128), 256, 0, stream>>>(xcB, wXB, P, nullptr,
      1024, PW, 2048, 2048, 2048, nullptr, nullptr, 0);
  f2bf_kernel<<<(Bsz*Lsp*PW)/2048, 256, 0, stream>>>(P, PB, Bsz*Lsp*PW);
  ps_build<<<16, 256, 0, stream>>>(P, PS);

  // stage E: delta as 4 GEMMs (M=1024, N=2048, K=64) with softplus epilogue,
  // outputs dl (f32) and du=dl*u (bf16), both permuted into scan order [k][b][l][d]
  for (int k = 0; k < KK; ++k)
    gemm_bf<4><<<dim3(DI/128, 1024/128), 256, 0, stream>>>(PB + k*96, dtwB + (size_t)k*DI*RR,
        delta_sc + (size_t)k*Bsz*Lsp*DI, dt_b + k*DI, 1024, DI, 64, PW, RR,
        xcB, du_sc + (size_t)k*Bsz*Lsp*DI, k);

  // stage F: chunked two-pass selective scan (sequential streams, no index math)
  scan_pass1<<<dim3(Bsz*KK, DI/64, NCH), 256, 0, stream>>>(delta_sc, du_sc, PS, A_logs, Pa, Hend);
  scan_combine<<<(16*DI*NST)/256, 256, 0, stream>>>(Pa, Hend, Hstart);
  scan_pass2<<<dim3(Bsz*KK, DI/64, NCH), 256, 0, stream>>>(delta_sc, du_sc, PS, A_logs, Hstart, oyB);

  // stage G: combine + D*u + LN + gate -> bf16 (delta_sc dead; ygB overlays it)
  combine_ln_kernel<<<Bsz*Lsp, 256, 0, stream>>>(oyB, xzB, xcB, Ds, ln_g, ln_b, ygB);

  // stage H: out_proj GEMM (M=1024, N=1024, K=2048), bf16 out
  gemm_bf<1><<<dim3(1024/128, 1024/128), 256, 0, stream>>>(ygB, wOB, o1B, nullptr,
      1024, 1024, 2048, 2048, 2048, nullptr, nullptr, 0);

  // stage I: cbr GEMM (M=1024, N=128, K=1024), f32 out + epilogue
  gemm_bf<0><<<dim3(DIM/128, 1024/128), 256, 0, stream>>>(o1B, wCB, o2, nullptr,
      1024, DIM, 1024, 1024, 1024, nullptr, nullptr, 0);
  cbr_epilogue<<<(Bsz*DIM*Lsp)/256, 256, 0, stream>>>(o2, cbr_b, cbr_g, cbr_beta, cbr_m, cbr_v, out);
}

// Round 9
// 456.180 us; speedup vs baseline: 1.0640x; 1.0640x over previous
//
#include <hip/hip_runtime.h>
#include <hip/hip_bf16.h>
#include <math.h>

// ---------- constants ----------
#define Bsz 4
#define Cin 512
#define Hh 16
#define Ww 16
#define Lsp 256
#define DIM 128
#define DM 1024      // dim*4 + 512
#define DI 2048
#define KK 4
#define NST 16
#define RR 64
#define PW 384       // K*96 projection rows
#define NCH 4
#define CHUNK 64     // Lsp / NCH

// ---------- ws layout (floats) — round-4 proven layout ----------
#define OFF_FEAT    0u
#define SZ_FEAT     (Bsz*Lsp*DM)                 // 1048576
#define OFF_POOLED  (OFF_FEAT + SZ_FEAT)
#define SZ_POOLED   (Bsz*Cin*275)                // 563200
#define OFF_PCONV   (OFF_POOLED + SZ_POOLED)
#define SZ_PCONV    (Bsz*275*DIM)                // 140800
#define OFF_Y0M     (OFF_PCONV + SZ_PCONV)
#define SZ_Y0M      (Bsz*DIM)                    // 512
#define OFF_XZ      (OFF_Y0M + SZ_Y0M)
#define SZ_XZ       (Bsz*Lsp*2*DI)               // 4194304
#define OFF_XCT     (OFF_XZ + SZ_XZ)
#define SZ_XCT      (Bsz*Lsp*DI)                 // 2097152
#define OFF_XDBL    (OFF_XCT + SZ_XCT)
#define SZ_XDBL     (Bsz*Lsp*PW)                 // 393216  (P matrix f32)
#define OFF_DELTA   (OFF_XDBL + SZ_XDBL)
#define SZ_DELTA    (Bsz*KK*Lsp*DI)              // 8388608 (delta_scan f32)
#define OFF_OUTY    (OFF_DELTA + SZ_DELTA)
#define SZ_OUTY     (Bsz*KK*Lsp*DI)              // 8388608 (oyB bf16 + Pa + Hend)
#define OFF_YG      (OFF_OUTY + SZ_OUTY)
#define SZ_YG       (Bsz*Lsp*DI)                 // 2097152 (Hstart)
#define OFF_O1      (OFF_YG + SZ_YG)
#define SZ_O1       (Bsz*Lsp*DM)                 // 1048576 (xcB then o1B)
#define OFF_O2      (OFF_O1 + SZ_O1)
#define SZ_O2       (Bsz*Lsp*DIM)                // 131072
#define WS_FLOATS   (OFF_O2 + SZ_O2)

typedef __attribute__((ext_vector_type(8))) short short8;
typedef __attribute__((ext_vector_type(4))) float f32x4;

__device__ __forceinline__ short f2bf(float x) {
  __hip_bfloat16 h = __float2bfloat16(x);
  short s;
  __builtin_memcpy(&s, &h, 2);
  return s;
}
__device__ __forceinline__ float bf2f(short s) {
  unsigned u = ((unsigned)(unsigned short)s) << 16;
  float f;
  __builtin_memcpy(&f, &u, 4);
  return f;
}

// ---------- f32 -> bf16 bulk convert (n multiple of 8) ----------
__global__ __launch_bounds__(256) void f2bf_kernel(const float* __restrict__ in,
    short* __restrict__ out, int n) {
  int i = (blockIdx.x*256 + threadIdx.x)*8;
  if (i >= n) return;
  float4 a = *(const float4*)(in + i);
  float4 b = *(const float4*)(in + i + 4);
  short8 o;
  o[0]=f2bf(a.x); o[1]=f2bf(a.y); o[2]=f2bf(a.z); o[3]=f2bf(a.w);
  o[4]=f2bf(b.x); o[5]=f2bf(b.y); o[6]=f2bf(b.z); o[7]=f2bf(b.w);
  *(short8*)(out + i) = o;
}

// ---------- pool layer 0: conv1x1+BN+ReLU then global mean (ILP version) ----------
__global__ __launch_bounds__(256) void pool0_kernel(
    const float* __restrict__ x, const float* __restrict__ pw, const float* __restrict__ pb,
    const float* __restrict__ g, const float* __restrict__ bb,
    const float* __restrict__ m, const float* __restrict__ v, float* __restrict__ y0m) {
  int bd = blockIdx.x;             // b*128+d
  int b = bd >> 7, d = bd & 127;
  int l = threadIdx.x;
  const float* xb = x + (b*Cin)*Lsp + l;
  const float* w = pw + d*Cin;
  float a0 = 0.f, a1 = 0.f, a2 = 0.f, a3 = 0.f;
  #pragma unroll 4
  for (int c = 0; c < Cin; c += 4) {
    float4 wv = *(const float4*)(w + c);
    a0 += xb[(c+0)*Lsp] * wv.x;
    a1 += xb[(c+1)*Lsp] * wv.y;
    a2 += xb[(c+2)*Lsp] * wv.z;
    a3 += xb[(c+3)*Lsp] * wv.w;
  }
  float s = (a0 + a1) + (a2 + a3) + pb[d];
  float inv = g[d] * rsqrtf(v[d] + 1e-5f);
  s = s*inv + (bb[d] - m[d]*inv);
  s = fmaxf(s, 0.f);
  __shared__ float red[256];
  red[l] = s; __syncthreads();
  for (int off = 128; off > 0; off >>= 1) {
    if (l < off) red[l] += red[l+off];
    __syncthreads();
  }
  if (l == 0) y0m[bd] = red[0] * (1.f/256.f);
}

// ---------- adaptive avg pool of x to 5x5,9x9,13x13 (concatenated 275 positions) ----------
__device__ __forceinline__ void decode_pos(int pos, int& s, int& pp, int& qq, int& layer) {
  if (pos < 25)       { s = 5;  layer = 1; int t = pos;       pp = t/5;  qq = t%5;  }
  else if (pos < 106) { s = 9;  layer = 2; int t = pos - 25;  pp = t/9;  qq = t%9;  }
  else                { s = 13; layer = 3; int t = pos - 106; pp = t/13; qq = t%13; }
}

__global__ void pool_avg_kernel(const float* __restrict__ x, float* __restrict__ pooled) {
  int bc = blockIdx.x;             // b*512+c
  int pos = threadIdx.x;
  if (pos >= 275) return;
  int s, pp, qq, layer;
  decode_pos(pos, s, pp, qq, layer);
  int hs = (pp*Hh)/s, he = ((pp+1)*Hh + s-1)/s;
  int ws = (qq*Ww)/s, we = ((qq+1)*Ww + s-1)/s;
  const float* xb = x + (size_t)bc*Lsp;
  float acc = 0.f;
  for (int hh = hs; hh < he; ++hh)
    for (int ww2 = ws; ww2 < we; ++ww2)
      acc += xb[hh*Ww + ww2];
  pooled[(size_t)bc*275 + pos] = acc / (float)((he-hs)*(we-ws));
}

// ---------- conv1x1 + BN + ReLU on pooled features (ILP version) ----------
__global__ void pconv_kernel(const float* __restrict__ pooled, const float* __restrict__ pw,
    const float* __restrict__ pb, const float* __restrict__ g, const float* __restrict__ bb,
    const float* __restrict__ m, const float* __restrict__ v, float* __restrict__ pconv) {
  int bp = blockIdx.x;             // b*275+pos
  int b = bp / 275, pos = bp % 275;
  int d = threadIdx.x;             // 0..127
  int s, pp, qq, layer;
  decode_pos(pos, s, pp, qq, layer);
  const float* pc = pooled + b*Cin*275 + pos;
  const float* w = pw + (layer*DIM + d)*Cin;
  float a0 = 0.f, a1 = 0.f, a2 = 0.f, a3 = 0.f;
  #pragma unroll 4
  for (int c = 0; c < Cin; c += 4) {
    float4 wv = *(const float4*)(w + c);
    a0 += pc[(c+0)*275] * wv.x;
    a1 += pc[(c+1)*275] * wv.y;
    a2 += pc[(c+2)*275] * wv.z;
    a3 += pc[(c+3)*275] * wv.w;
  }
  float acc = (a0 + a1) + (a2 + a3) + pb[layer*DIM + d];
  int ld = layer*DIM + d;
  float inv = g[ld] * rsqrtf(v[ld] + 1e-5f);
  acc = acc*inv + (bb[ld] - m[ld]*inv);
  pconv[bp*DIM + d] = fmaxf(acc, 0.f);
}

// ---------- assemble feat (B,L,1024) in bf16 ----------
__global__ __launch_bounds__(256) void feat_kernel(const float* __restrict__ x,
    const float* __restrict__ y0m, const float* __restrict__ pconv, short* __restrict__ featB) {
  int bl = blockIdx.x;             // b*256+l
  int b = bl >> 8, l = bl & 255;
  int h = l >> 4, w = l & 15;
  for (int c = threadIdx.x; c < DM; c += 256) {
    float val;
    if (c < Cin) {
      val = x[(b*Cin + c)*Lsp + l];
    } else if (c < Cin + DIM) {
      val = y0m[b*DIM + (c - Cin)];
    } else {
      int i = (c - (Cin+DIM)) >> 7;          // 0,1,2 -> s=5,9,13
      int d = (c - (Cin+DIM)) & 127;
      int s = (i==0) ? 5 : (i==1) ? 9 : 13;
      int off = (i==0) ? 0 : (i==1) ? 25 : 106;
      float scale = (float)s / 16.f;
      float sh = fmaxf((h + 0.5f)*scale - 0.5f, 0.f);
      int h0 = min((int)sh, s-1); float wh = sh - (float)h0; int h1 = min(h0+1, s-1);
      float sw = fmaxf((w + 0.5f)*scale - 0.5f, 0.f);
      int w0 = min((int)sw, s-1); float ww2 = sw - (float)w0; int w1 = min(w0+1, s-1);
      const float* pc = pconv + b*275*DIM;
      float v00 = pc[(off + h0*s + w0)*DIM + d];
      float v01 = pc[(off + h0*s + w1)*DIM + d];
      float v10 = pc[(off + h1*s + w0)*DIM + d];
      float v11 = pc[(off + h1*s + w1)*DIM + d];
      val = (1.f-wh)*((1.f-ww2)*v00 + ww2*v01) + wh*((1.f-ww2)*v10 + ww2*v11);
    }
    featB[bl*DM + c] = f2bf(val);
  }
}

// scan-direction spatial index map (l -> sp)
__device__ __forceinline__ int dir_map(int k, int l) {
  if (k == 0) return l;
  if (k == 1) return ((l & 15) << 4) | (l >> 4);
  if (k == 2) return 255 - l;
  int m = 255 - l; return ((m & 15) << 4) | (m >> 4);
}
// inverse map (sp -> scan l) per direction
__device__ __forceinline__ int inv_map(int k, int sp) {
  int t = ((sp & 15) << 4) | (sp >> 4);
  if (k == 0) return sp;
  if (k == 1) return t;
  if (k == 2) return 255 - sp;
  return 255 - t;
}

// ---------- bf16 MFMA GEMM: C[M][N] = A[M][K] * B[N][K]^T ----------
// MODE 0: f32 store.  MODE 1: bf16 store.  MODE 2: f32 softplus(acc + bias[col]).
// MODE 4: delta: dl=softplus(acc+bias[col]); du=dl*u; both stored at scan-order row.
__device__ __forceinline__ void gload_lds16(const short* g, short* l) {
  __builtin_amdgcn_global_load_lds((const __attribute__((address_space(1))) void*)g,
                                   (__attribute__((address_space(3))) void*)l, 16, 0, 0);
}

template<int MODE>
__global__ __launch_bounds__(256) void gemm_bf(const short* __restrict__ Ag,
    const short* __restrict__ Bg, void* __restrict__ Cout, const float* __restrict__ bias,
    int M, int N, int K, int lda, int ldb,
    const short* __restrict__ xcb, short* __restrict__ duo, int kdir) {
  __shared__ short Als[128*64];
  __shared__ short Bls[128*64];
  int tid = threadIdx.x;
  int w = tid >> 6, lane = tid & 63;
  int wm = w >> 1, wn = w & 1;
  int row0 = blockIdx.y * 128, col0 = blockIdx.x * 128;
  f32x4 acc[4][4];
  #pragma unroll
  for (int i = 0; i < 4; ++i)
    #pragma unroll
    for (int j = 0; j < 4; ++j)
      acc[i][j] = (f32x4){0.f, 0.f, 0.f, 0.f};

  for (int k0 = 0; k0 < K; k0 += 64) {
    #pragma unroll
    for (int i = 0; i < 4; ++i) {
      int slot = i*256 + w*64 + lane;
      int r = slot >> 3, pc = slot & 7;
      int c = pc ^ (r & 7);
      gload_lds16(Ag + (size_t)(row0 + r)*lda + k0 + c*8, &Als[(i*256 + w*64)*8]);
      gload_lds16(Bg + (size_t)(col0 + r)*ldb + k0 + c*8, &Bls[(i*256 + w*64)*8]);
    }
    __syncthreads();
    #pragma unroll
    for (int ks = 0; ks < 2; ++ks) {
      short8 af[4], bfr[4];
      int rsel = lane & 15, csel = ks*4 + (lane >> 4);
      #pragma unroll
      for (int mi = 0; mi < 4; ++mi) {
        int row = wm*64 + mi*16 + rsel;
        af[mi] = *(const short8*)&Als[row*64 + ((csel ^ (row & 7)) << 3)];
      }
      #pragma unroll
      for (int ni = 0; ni < 4; ++ni) {
        int row = wn*64 + ni*16 + rsel;
        bfr[ni] = *(const short8*)&Bls[row*64 + ((csel ^ (row & 7)) << 3)];
      }
      #pragma unroll
      for (int mi = 0; mi < 4; ++mi)
        #pragma unroll
        for (int ni = 0; ni < 4; ++ni)
          acc[mi][ni] = __builtin_amdgcn_mfma_f32_16x16x32_bf16(af[mi], bfr[ni], acc[mi][ni], 0, 0, 0);
    }
    __syncthreads();
  }
  // epilogue: D row = (lane>>4)*4 + j, col = lane&15
  #pragma unroll
  for (int mi = 0; mi < 4; ++mi) {
    int rbase = row0 + wm*64 + mi*16 + ((lane >> 4) << 2);
    #pragma unroll
    for (int ni = 0; ni < 4; ++ni) {
      int colg = col0 + wn*64 + ni*16 + (lane & 15);
      #pragma unroll
      for (int j = 0; j < 4; ++j) {
        if (MODE == 1) {
          ((short*)Cout)[(size_t)(rbase + j)*N + colg] = f2bf(acc[mi][ni][j]);
        } else if (MODE == 2) {
          float sv = acc[mi][ni][j] + bias[colg];
          ((float*)Cout)[(size_t)(rbase + j)*N + colg] = (sv > 20.f) ? sv : log1pf(__expf(sv));
        } else if (MODE == 4) {
          int rowg = rbase + j;                 // b*256 + sp
          int b_ = rowg >> 8, sp_ = rowg & 255;
          int lsc = inv_map(kdir, sp_);
          float dl = acc[mi][ni][j] + bias[colg];
          dl = (dl > 20.f) ? dl : log1pf(__expf(dl));
          float ul = bf2f(xcb[(size_t)rowg*N + colg]);   // N == DI
          size_t oidx = (size_t)(b_*Lsp + lsc)*N + colg;
          ((float*)Cout)[oidx] = dl;
          duo[oidx] = f2bf(dl*ul);
        } else {
          ((float*)Cout)[(size_t)(rbase + j)*N + colg] = acc[mi][ni][j];
        }
      }
    }
  }
}

// ---------- depthwise 3x3 conv + bias + silu -> xcB (bf16); xz is bf16 ----------
__global__ __launch_bounds__(256) void dwconv_kernel(const short* __restrict__ xzB,
    const float* __restrict__ cw, const float* __restrict__ cb, short* __restrict__ xcB) {
  int bl = blockIdx.x;
  int b = bl >> 8, l = bl & 255;
  int h = l >> 4, w = l & 15;
  const short* xzb = xzB + (size_t)b*Lsp*(2*DI);
  for (int d = threadIdx.x; d < DI; d += 256) {
    float s = 0.f;
    #pragma unroll
    for (int dh = -1; dh <= 1; ++dh) {
      int hh = h + dh; if (hh < 0 || hh > 15) continue;
      #pragma unroll
      for (int dw = -1; dw <= 1; ++dw) {
        int ww2 = w + dw; if (ww2 < 0 || ww2 > 15) continue;
        s += bf2f(xzb[(size_t)(hh*16 + ww2)*(2*DI) + d]) * cw[d*9 + (dh+1)*3 + (dw+1)];
      }
    }
    s += cb[d];
    float r = s / (1.f + __expf(-s));   // silu
    xcB[((size_t)b*Lsp + l)*DI + d] = f2bf(r);
  }
}

// ---------- pack B/C columns of P into scan order: PS[(k*4+b)][l][32] ----------
__global__ __launch_bounds__(256) void ps_build(const float* __restrict__ P,
    float* __restrict__ PS) {
  int slab = blockIdx.x;           // k*4 + b
  int k = slab >> 2, b = slab & 3;
  int l = threadIdx.x;
  int sp = dir_map(k, l);
  const float* src = P + (size_t)(b*Lsp + sp)*PW + k*96 + RR;   // 32 floats: B then C
  float* dst = PS + ((size_t)slab*Lsp + l)*32;
  #pragma unroll
  for (int n = 0; n < 32; n += 4)
    *(float4*)(dst + n) = *(const float4*)(src + n);
}

// ---------- scan pass 1: per-chunk local scan -> Pa (decay product), Hend ----------
__global__ __launch_bounds__(256) void scan_pass1(const float* __restrict__ dls,
    const short* __restrict__ dus, const float* __restrict__ PS,
    const float* __restrict__ A_logs, float* __restrict__ Pa, float* __restrict__ Hend) {
  int bk = blockIdx.x;             // b*4+k
  int b = bk >> 2, k = bk & 3;
  int slab = k*Bsz + b;
  int tid = threadIdx.x;
  int wv = tid >> 6, lane = tid & 63;
  int dloc = lane >> 2, ng = lane & 3;
  int d = blockIdx.y*64 + wv*16 + dloc;
  int c = blockIdx.z;
  int n0 = ng*4;
  float A[4], h[4] = {0.f,0.f,0.f,0.f}, pa[4] = {1.f,1.f,1.f,1.f};
  #pragma unroll
  for (int j = 0; j < 4; ++j)
    A[j] = -__expf(A_logs[((size_t)k*DI + d)*NST + n0 + j]);
  const float* dlp = dls + (size_t)slab*Lsp*DI;
  const short* dup = dus + (size_t)slab*Lsp*DI;
  const float* ps  = PS + (size_t)slab*Lsp*32;
  #pragma unroll 2
  for (int l = c*CHUNK; l < (c+1)*CHUNK; ++l) {
    float dl = dlp[(size_t)l*DI + d];
    float du = bf2f(dup[(size_t)l*DI + d]);
    float4 Bv = *(const float4*)(ps + l*32 + n0);
    float e0 = __expf(dl*A[0]); h[0] = h[0]*e0 + du*Bv.x; pa[0] *= e0;
    float e1 = __expf(dl*A[1]); h[1] = h[1]*e1 + du*Bv.y; pa[1] *= e1;
    float e2 = __expf(dl*A[2]); h[2] = h[2]*e2 + du*Bv.z; pa[2] *= e2;
    float e3 = __expf(dl*A[3]); h[3] = h[3]*e3 + du*Bv.w; pa[3] *= e3;
  }
  size_t base = ((size_t)(c*16 + bk)*DI + d)*NST + n0;
  #pragma unroll
  for (int j = 0; j < 4; ++j) {
    Pa[base + j] = pa[j];
    Hend[base + j] = h[j];
  }
}

// ---------- combine chunk boundaries ----------
__global__ __launch_bounds__(256) void scan_combine(const float* __restrict__ Pa,
    const float* __restrict__ Hend, float* __restrict__ Hstart) {
  int idx = blockIdx.x*256 + threadIdx.x;    // (bk*DI + d)*16 + n
  const int stride = 16*DI*NST;              // 524288
  float h = 0.f;
  #pragma unroll
  for (int c = 0; c < NCH; ++c) {
    Hstart[c*stride + idx] = h;
    h = Pa[c*stride + idx]*h + Hend[c*stride + idx];
  }
}

// ---------- scan pass 2: rescan with correct Hstart, emit y (bf16) ----------
__global__ __launch_bounds__(256) void scan_pass2(const float* __restrict__ dls,
    const short* __restrict__ dus, const float* __restrict__ PS,
    const float* __restrict__ A_logs, const float* __restrict__ Hstart,
    short* __restrict__ oyB) {
  int bk = blockIdx.x;             // b*4+k
  int b = bk >> 2, k = bk & 3;
  int slab = k*Bsz + b;
  int tid = threadIdx.x;
  int wv = tid >> 6, lane = tid & 63;
  int dloc = lane >> 2, ng = lane & 3;
  int d = blockIdx.y*64 + wv*16 + dloc;
  int c = blockIdx.z;
  int n0 = ng*4;
  float A[4], h[4];
  #pragma unroll
  for (int j = 0; j < 4; ++j)
    A[j] = -__expf(A_logs[((size_t)k*DI + d)*NST + n0 + j]);
  size_t hbase = ((size_t)(c*16 + bk)*DI + d)*NST + n0;
  #pragma unroll
  for (int j = 0; j < 4; ++j) h[j] = Hstart[hbase + j];
  const float* dlp = dls + (size_t)slab*Lsp*DI;
  const short* dup = dus + (size_t)slab*Lsp*DI;
  const float* ps  = PS + (size_t)slab*Lsp*32;
  short* oy = oyB + (size_t)bk*Lsp*DI;
  #pragma unroll 2
  for (int l = c*CHUNK; l < (c+1)*CHUNK; ++l) {
    float dl = dlp[(size_t)l*DI + d];
    float du = bf2f(dup[(size_t)l*DI + d]);
    float4 Bv = *(const float4*)(ps + l*32 + n0);
    float4 Cv = *(const float4*)(ps + l*32 + 16 + n0);
    float y;
    float e0 = __expf(dl*A[0]); h[0] = h[0]*e0 + du*Bv.x; y  = h[0]*Cv.x;
    float e1 = __expf(dl*A[1]); h[1] = h[1]*e1 + du*Bv.y; y += h[1]*Cv.y;
    float e2 = __expf(dl*A[2]); h[2] = h[2]*e2 + du*Bv.z; y += h[2]*Cv.z;
    float e3 = __expf(dl*A[3]); h[3] = h[3]*e3 + du*Bv.w; y += h[3]*Cv.w;
    y += __shfl_xor(y, 1);
    y += __shfl_xor(y, 2);
    if (ng == 0) oy[(size_t)l*DI + d] = f2bf(y);
  }
}

// ---------- combine 4 directions + D*u + LayerNorm + gate with silu(z) -> bf16 ----------
__global__ __launch_bounds__(256) void combine_ln_kernel(const short* __restrict__ oyB,
    const short* __restrict__ xzB, const short* __restrict__ xcB,
    const float* __restrict__ Ds, const float* __restrict__ lng,
    const float* __restrict__ lnb, short* __restrict__ ygB) {
  int bl = blockIdx.x;
  int b = bl >> 8, l = bl & 255;
  int h = l >> 4, w = l & 15;
  int lT = (w << 4) | h;
  const short* oy = oyB + (size_t)b*KK*Lsp*DI;
  float vals[8];
  float sum = 0.f, sumsq = 0.f;
  #pragma unroll
  for (int i = 0; i < 8; ++i) {
    int d = threadIdx.x + i*256;
    float dsum = Ds[d] + Ds[DI + d] + Ds[2*DI + d] + Ds[3*DI + d];
    float yv = bf2f(oy[(size_t)(0*Lsp + l       )*DI + d])
             + bf2f(oy[(size_t)(2*Lsp + (255-l ))*DI + d])
             + bf2f(oy[(size_t)(1*Lsp + lT      )*DI + d])
             + bf2f(oy[(size_t)(3*Lsp + (255-lT))*DI + d])
             + bf2f(xcB[(size_t)bl*DI + d]) * dsum;
    vals[i] = yv; sum += yv; sumsq += yv*yv;
  }
  __shared__ float r1[256], r2[256];
  r1[threadIdx.x] = sum; r2[threadIdx.x] = sumsq; __syncthreads();
  for (int off = 128; off > 0; off >>= 1) {
    if (threadIdx.x < off) { r1[threadIdx.x] += r1[threadIdx.x+off]; r2[threadIdx.x] += r2[threadIdx.x+off]; }
    __syncthreads();
  }
  float mu = r1[0] * (1.f/2048.f);
  float var = r2[0] * (1.f/2048.f) - mu*mu;
  float rstd = rsqrtf(var + 1e-5f);
  const short* zrow = xzB + (size_t)bl*(2*DI) + DI;
  #pragma unroll
  for (int i = 0; i < 8; ++i) {
    int d = threadIdx.x + i*256;
    float z = bf2f(zrow[d]);
    float sz = z / (1.f + __expf(-z));
    ygB[(size_t)bl*DI + d] = f2bf(((vals[i]-mu)*rstd*lng[d] + lnb[d]) * sz);
  }
}

// ---------- cbr epilogue: bias + BN + exact GELU, write NCHW ----------
__global__ void cbr_epilogue(const float* __restrict__ o2, const float* __restrict__ cb,
    const float* __restrict__ g, const float* __restrict__ beta, const float* __restrict__ m_,
    const float* __restrict__ v_, float* __restrict__ out) {
  int idx = blockIdx.x*256 + threadIdx.x;   // (b*128+dd)*256 + l
  int l = idx & 255;
  int rest = idx >> 8;
  int dd = rest & 127;
  int b = rest >> 7;
  float s = o2[((size_t)b*Lsp + l)*DIM + dd] + cb[dd];
  float inv = g[dd] * rsqrtf(v_[dd] + 1e-5f);
  s = s*inv + (beta[dd] - m_[dd]*inv);
  out[idx] = s * 0.5f * (1.f + erff(s * 0.70710678118f));
}

extern "C" void kernel_launch(void* const* d_in, const int* in_sizes, int n_in,
                              void* d_out, int out_size, void* d_ws, size_t ws_size,
                              hipStream_t stream) {
  const float* x        = (const float*)d_in[0];
  const float* pool_w   = (const float*)d_in[1];
  const float* pool_b   = (const float*)d_in[2];
  const float* bn_g     = (const float*)d_in[3];
  const float* bn_b     = (const float*)d_in[4];
  const float* bn_m     = (const float*)d_in[5];
  const float* bn_v     = (const float*)d_in[6];
  const float* in_proj_w= (const float*)d_in[7];
  const float* conv_w   = (const float*)d_in[8];
  const float* conv_b   = (const float*)d_in[9];
  const float* x_proj_w = (const float*)d_in[10];
  const float* dt_w     = (const float*)d_in[11];
  const float* dt_b     = (const float*)d_in[12];
  const float* A_logs   = (const float*)d_in[13];
  const float* Ds       = (const float*)d_in[14];
  const float* ln_g     = (const float*)d_in[15];
  const float* ln_b     = (const float*)d_in[16];
  const float* out_proj_w=(const float*)d_in[17];
  const float* cbr_w    = (const float*)d_in[18];
  const float* cbr_b    = (const float*)d_in[19];
  const float* cbr_g    = (const float*)d_in[20];
  const float* cbr_beta = (const float*)d_in[21];
  const float* cbr_m    = (const float*)d_in[22];
  const float* cbr_v    = (const float*)d_in[23];
  float* out = (float*)d_out;

  if (ws_size < (size_t)WS_FLOATS * sizeof(float)) return;
  float* ws = (float*)d_ws;
  float* pooled   = ws + OFF_POOLED;
  float* pconv    = ws + OFF_PCONV;
  float* y0m      = ws + OFF_Y0M;
  float* P        = ws + OFF_XDBL;
  float* delta_sc = ws + OFF_DELTA;                    // scan-order dl (f32)
  float* o2       = ws + OFF_O2;

  // overlays (lifetimes audited):
  short* featB = (short*)(ws + OFF_POOLED);            // written end A (pooled dead), read B
  float* PS    = ws + OFF_POOLED;                      // written after D (featB dead), read F
  short* xzB   = (short*)(ws + OFF_XZ);                // written B (bf16), read C & G
  short* du_sc = (short*)(ws + OFF_XZ + 2097152);      // written E, read F
  short* wInB  = (short*)(ws + OFF_DELTA);             // read B; delta_sc written E
  short* wXB   = (short*)(ws + OFF_DELTA + 2097152);   // read D; delta_sc written E
  short* wOB   = (short*)(ws + OFF_FEAT);              // read H
  short* wCB   = (short*)(ws + OFF_PCONV);             // written after feat (pconv dead), read I
  short* xcB   = (short*)(ws + OFF_O1);                // written C, read D/E & G; o1B after
  short* oyB   = (short*)(ws + OFF_OUTY);              // written pass2, read G
  float* Pa    = ws + OFF_OUTY + 4194304;              // written pass1, read combine
  float* Hend  = ws + OFF_OUTY + 4194304 + 2097152;    // written pass1, read combine
  short* dtwB  = (short*)(ws + OFF_OUTY + 4194304);    // read E; Pa written pass1 (after E)
  short* PB    = (short*)(ws + OFF_OUTY + 4194304 + 262144); // written after D, read E
  float* Hstart= ws + OFF_YG;                          // written combine, read pass2
  short* ygB   = (short*)(ws + OFF_DELTA);             // written G (delta_sc dead), read H
  short* o1B   = (short*)(ws + OFF_O1);                // written H, read I

  // stage A: pyramid pooling
  pool0_kernel<<<Bsz*DIM, 256, 0, stream>>>(x, pool_w, pool_b, bn_g, bn_b, bn_m, bn_v, y0m);
  pool_avg_kernel<<<Bsz*Cin, 288, 0, stream>>>(x, pooled);
  pconv_kernel<<<Bsz*275, 128, 0, stream>>>(pooled, pool_w, pool_b, bn_g, bn_b, bn_m, bn_v, pconv);
  feat_kernel<<<Bsz*Lsp, 256, 0, stream>>>(x, y0m, pconv, featB);

  // weight conversions
  f2bf_kernel<<<(4096*1024)/2048, 256, 0, stream>>>(in_proj_w, wInB, 4096*1024);
  f2bf_kernel<<<(PW*2048)/2048,   256, 0, stream>>>(x_proj_w,  wXB,  PW*2048);
  f2bf_kernel<<<(1024*2048)/2048, 256, 0, stream>>>(out_proj_w, wOB, 1024*2048);
  f2bf_kernel<<<(DIM*1024)/2048,  256, 0, stream>>>(cbr_w,      wCB, DIM*1024);
  f2bf_kernel<<<(KK*DI*RR)/2048,  256, 0, stream>>>(dt_w,       dtwB, KK*DI*RR);

  // stage B: in_proj GEMM (M=1024, N=4096, K=1024), bf16 out
  gemm_bf<1><<<dim3(4096/128, 1024/128), 256, 0, stream>>>(featB, wInB, xzB, nullptr,
      1024, 4096, 1024, 1024, 1024, nullptr, nullptr, 0);

  // stage C: depthwise conv + silu -> bf16
  dwconv_kernel<<<Bsz*Lsp, 256, 0, stream>>>(xzB, conv_w, conv_b, xcB);

  // stage D: x_proj GEMM: P[1024x384] = xcB * wXB^T (K=2048), f32 out
  gemm_bf<0><<<dim3(PW/128, 1024/128), 256, 0, stream>>>(xcB, wXB, P, nullptr,
      1024, PW, 2048, 2048, 2048, nullptr, nullptr, 0);
  f2bf_kernel<<<(Bsz*Lsp*PW)/2048, 256, 0, stream>>>(P, PB, Bsz*Lsp*PW);
  ps_build<<<16, 256, 0, stream>>>(P, PS);

  // stage E: delta as 4 GEMMs (M=1024, N=2048, K=64) with softplus epilogue,
  // outputs dl (f32) and du=dl*u (bf16), both permuted into scan order [k][b][l][d]
  for (int k = 0; k < KK; ++k)
    gemm_bf<4><<<dim3(DI/128, 1024/128), 256, 0, stream>>>(PB + k*96, dtwB + (size_t)k*DI*RR,
        delta_sc + (size_t)k*Bsz*Lsp*DI, dt_b + k*DI, 1024, DI, 64, PW, RR,
        xcB, du_sc + (size_t)k*Bsz*Lsp*DI, k);

  // stage F: chunked two-pass selective scan (sequential streams, no index math)
  scan_pass1<<<dim3(Bsz*KK, DI/64, NCH), 256, 0, stream>>>(delta_sc, du_sc, PS, A_logs, Pa, Hend);
  scan_combine<<<(16*DI*NST)/256, 256, 0, stream>>>(Pa, Hend, Hstart);
  scan_pass2<<<dim3(Bsz*KK, DI/64, NCH), 256, 0, stream>>>(delta_sc, du_sc, PS, A_logs, Hstart, oyB);

  // stage G: combine + D*u + LN + gate -> bf16 (delta_sc dead; ygB overlays it)
  combine_ln_kernel<<<Bsz*Lsp, 256, 0, stream>>>(oyB, xzB, xcB, Ds, ln_g, ln_b, ygB);

  // stage H: out_proj GEMM (M=1024, N=1024, K=2048), bf16 out
  gemm_bf<1><<<dim3(1024/128, 1024/128), 256, 0, stream>>>(ygB, wOB, o1B, nullptr,
      1024, 1024, 2048, 2048, 2048, nullptr, nullptr, 0);

  // stage I: cbr GEMM (M=1024, N=128, K=1024), f32 out + epilogue
  gemm_bf<0><<<dim3(DIM/128, 1024/128), 256, 0, stream>>>(o1B, wCB, o2, nullptr,
      1024, DIM, 1024, 1024, 1024, nullptr, nullptr, 0);
  cbr_epilogue<<<(Bsz*DIM*Lsp)/256, 256, 0, stream>>>(o2, cbr_b, cbr_g, cbr_beta, cbr_m, cbr_v, out);
}

// Round 10
// 354.365 us; speedup vs baseline: 1.3698x; 1.2873x over previous
//
#include <hip/hip_runtime.h>
#include <hip/hip_bf16.h>
#include <math.h>

// ---------- constants ----------
#define Bsz 4
#define Cin 512
#define Hh 16
#define Ww 16
#define Lsp 256
#define DIM 128
#define DM 1024      // dim*4 + 512
#define DI 2048
#define KK 4
#define NST 16
#define RR 64
#define PW 384       // K*96 projection rows
#define NCH 4
#define CHUNK 64     // Lsp / NCH

// ---------- ws layout (floats) — round-4 proven layout ----------
#define OFF_FEAT    0u
#define SZ_FEAT     (Bsz*Lsp*DM)                 // 1048576
#define OFF_POOLED  (OFF_FEAT + SZ_FEAT)
#define SZ_POOLED   (Bsz*Cin*275)                // 563200
#define OFF_PCONV   (OFF_POOLED + SZ_POOLED)
#define SZ_PCONV    (Bsz*275*DIM)                // 140800
#define OFF_Y0M     (OFF_PCONV + SZ_PCONV)
#define SZ_Y0M      (Bsz*DIM)                    // 512
#define OFF_XZ      (OFF_Y0M + SZ_Y0M)
#define SZ_XZ       (Bsz*Lsp*2*DI)               // 4194304
#define OFF_XCT     (OFF_XZ + SZ_XZ)
#define SZ_XCT      (Bsz*Lsp*DI)                 // 2097152
#define OFF_XDBL    (OFF_XCT + SZ_XCT)
#define SZ_XDBL     (Bsz*Lsp*PW)                 // 393216  (P matrix f32)
#define OFF_DELTA   (OFF_XDBL + SZ_XDBL)
#define SZ_DELTA    (Bsz*KK*Lsp*DI)              // 8388608 (pk u32: dl|du packed bf16)
#define OFF_OUTY    (OFF_DELTA + SZ_DELTA)
#define SZ_OUTY     (Bsz*KK*Lsp*DI)              // 8388608 (oyB bf16 + Pa + Hend)
#define OFF_YG      (OFF_OUTY + SZ_OUTY)
#define SZ_YG       (Bsz*Lsp*DI)                 // 2097152 (Hstart)
#define OFF_O1      (OFF_YG + SZ_YG)
#define SZ_O1       (Bsz*Lsp*DM)                 // 1048576 (xcB then o1B)
#define OFF_O2      (OFF_O1 + SZ_O1)
#define SZ_O2       (Bsz*Lsp*DIM)                // 131072
#define WS_FLOATS   (OFF_O2 + SZ_O2)

typedef __attribute__((ext_vector_type(8))) short short8;
typedef __attribute__((ext_vector_type(4))) float f32x4;

__device__ __forceinline__ short f2bf(float x) {
  __hip_bfloat16 h = __float2bfloat16(x);
  short s;
  __builtin_memcpy(&s, &h, 2);
  return s;
}
__device__ __forceinline__ float bf2f(short s) {
  unsigned u = ((unsigned)(unsigned short)s) << 16;
  float f;
  __builtin_memcpy(&f, &u, 4);
  return f;
}

// ---------- fused f32 -> bf16 convert of the 5 weight tensors ----------
__global__ __launch_bounds__(256) void f2bf5_kernel(
    const float* __restrict__ s0, short* __restrict__ d0,    // 4194304
    const float* __restrict__ s1, short* __restrict__ d1,    // 786432
    const float* __restrict__ s2, short* __restrict__ d2,    // 2097152
    const float* __restrict__ s3, short* __restrict__ d3,    // 131072
    const float* __restrict__ s4, short* __restrict__ d4) {  // 524288
  int blk = blockIdx.x;
  const float* src; short* dst; int base;
  if (blk < 2048)      { src = s0; dst = d0; base = blk; }
  else if (blk < 2432) { src = s1; dst = d1; base = blk - 2048; }
  else if (blk < 3456) { src = s2; dst = d2; base = blk - 2432; }
  else if (blk < 3520) { src = s3; dst = d3; base = blk - 3456; }
  else                 { src = s4; dst = d4; base = blk - 3520; }
  int i = (base*256 + threadIdx.x)*8;
  float4 a = *(const float4*)(src + i);
  float4 b = *(const float4*)(src + i + 4);
  short8 o;
  o[0]=f2bf(a.x); o[1]=f2bf(a.y); o[2]=f2bf(a.z); o[3]=f2bf(a.w);
  o[4]=f2bf(b.x); o[5]=f2bf(b.y); o[6]=f2bf(b.z); o[7]=f2bf(b.w);
  *(short8*)(dst + i) = o;
}

// ---------- pool layer 0: conv1x1+BN+ReLU then global mean (ILP version) ----------
__global__ __launch_bounds__(256) void pool0_kernel(
    const float* __restrict__ x, const float* __restrict__ pw, const float* __restrict__ pb,
    const float* __restrict__ g, const float* __restrict__ bb,
    const float* __restrict__ m, const float* __restrict__ v, float* __restrict__ y0m) {
  int bd = blockIdx.x;             // b*128+d
  int b = bd >> 7, d = bd & 127;
  int l = threadIdx.x;
  const float* xb = x + (b*Cin)*Lsp + l;
  const float* w = pw + d*Cin;
  float a0 = 0.f, a1 = 0.f, a2 = 0.f, a3 = 0.f;
  #pragma unroll 4
  for (int c = 0; c < Cin; c += 4) {
    float4 wv = *(const float4*)(w + c);
    a0 += xb[(c+0)*Lsp] * wv.x;
    a1 += xb[(c+1)*Lsp] * wv.y;
    a2 += xb[(c+2)*Lsp] * wv.z;
    a3 += xb[(c+3)*Lsp] * wv.w;
  }
  float s = (a0 + a1) + (a2 + a3) + pb[d];
  float inv = g[d] * rsqrtf(v[d] + 1e-5f);
  s = s*inv + (bb[d] - m[d]*inv);
  s = fmaxf(s, 0.f);
  __shared__ float red[256];
  red[l] = s; __syncthreads();
  for (int off = 128; off > 0; off >>= 1) {
    if (l < off) red[l] += red[l+off];
    __syncthreads();
  }
  if (l == 0) y0m[bd] = red[0] * (1.f/256.f);
}

// ---------- adaptive avg pool of x to 5x5,9x9,13x13 (concatenated 275 positions) ----------
__device__ __forceinline__ void decode_pos(int pos, int& s, int& pp, int& qq, int& layer) {
  if (pos < 25)       { s = 5;  layer = 1; int t = pos;       pp = t/5;  qq = t%5;  }
  else if (pos < 106) { s = 9;  layer = 2; int t = pos - 25;  pp = t/9;  qq = t%9;  }
  else                { s = 13; layer = 3; int t = pos - 106; pp = t/13; qq = t%13; }
}

__global__ void pool_avg_kernel(const float* __restrict__ x, float* __restrict__ pooled) {
  int bc = blockIdx.x;             // b*512+c
  int pos = threadIdx.x;
  if (pos >= 275) return;
  int s, pp, qq, layer;
  decode_pos(pos, s, pp, qq, layer);
  int hs = (pp*Hh)/s, he = ((pp+1)*Hh + s-1)/s;
  int ws = (qq*Ww)/s, we = ((qq+1)*Ww + s-1)/s;
  const float* xb = x + (size_t)bc*Lsp;
  float acc = 0.f;
  for (int hh = hs; hh < he; ++hh)
    for (int ww2 = ws; ww2 < we; ++ww2)
      acc += xb[hh*Ww + ww2];
  pooled[(size_t)bc*275 + pos] = acc / (float)((he-hs)*(we-ws));
}

// ---------- conv1x1 + BN + ReLU on pooled features (ILP version) ----------
__global__ void pconv_kernel(const float* __restrict__ pooled, const float* __restrict__ pw,
    const float* __restrict__ pb, const float* __restrict__ g, const float* __restrict__ bb,
    const float* __restrict__ m, const float* __restrict__ v, float* __restrict__ pconv) {
  int bp = blockIdx.x;             // b*275+pos
  int b = bp / 275, pos = bp % 275;
  int d = threadIdx.x;             // 0..127
  int s, pp, qq, layer;
  decode_pos(pos, s, pp, qq, layer);
  const float* pc = pooled + b*Cin*275 + pos;
  const float* w = pw + (layer*DIM + d)*Cin;
  float a0 = 0.f, a1 = 0.f, a2 = 0.f, a3 = 0.f;
  #pragma unroll 4
  for (int c = 0; c < Cin; c += 4) {
    float4 wv = *(const float4*)(w + c);
    a0 += pc[(c+0)*275] * wv.x;
    a1 += pc[(c+1)*275] * wv.y;
    a2 += pc[(c+2)*275] * wv.z;
    a3 += pc[(c+3)*275] * wv.w;
  }
  float acc = (a0 + a1) + (a2 + a3) + pb[layer*DIM + d];
  int ld = layer*DIM + d;
  float inv = g[ld] * rsqrtf(v[ld] + 1e-5f);
  acc = acc*inv + (bb[ld] - m[ld]*inv);
  pconv[bp*DIM + d] = fmaxf(acc, 0.f);
}

// ---------- transpose x (b,c,l) f32 -> featB cols 0..511 bf16 (coalesced reads) ----------
// NOTE: featB overlays pooled — must launch AFTER pconv_kernel.
__global__ __launch_bounds__(256) void xT_kernel(const float* __restrict__ x,
    short* __restrict__ featB) {
  int b = blockIdx.z;
  int c0 = blockIdx.x*32, l0 = blockIdx.y*32;
  __shared__ float t[32][33];
  int tx = threadIdx.x & 31, ty = threadIdx.x >> 5;   // 32 x 8
  #pragma unroll
  for (int i = 0; i < 4; ++i) {
    int c = c0 + ty + i*8;
    t[ty + i*8][tx] = x[((size_t)b*Cin + c)*Lsp + l0 + tx];
  }
  __syncthreads();
  #pragma unroll
  for (int i = 0; i < 4; ++i) {
    int l = l0 + ty + i*8;
    featB[(size_t)(b*Lsp + l)*DM + c0 + tx] = f2bf(t[tx][ty + i*8]);
  }
}

// ---------- fill feat cols 512..1023 (y0 broadcast + bilinear upsample) ----------
__global__ __launch_bounds__(256) void feat_fill(const float* __restrict__ y0m,
    const float* __restrict__ pconv, short* __restrict__ featB) {
  int bl = blockIdx.x;             // b*256+l
  int b = bl >> 8, l = bl & 255;
  int h = l >> 4, w = l & 15;
  for (int cc = threadIdx.x; cc < 512; cc += 256) {
    float val;
    if (cc < 128) {
      val = y0m[b*DIM + cc];
    } else {
      int i = (cc - 128) >> 7;               // 0,1,2 -> s=5,9,13
      int d = (cc - 128) & 127;
      int s = (i==0) ? 5 : (i==1) ? 9 : 13;
      int off = (i==0) ? 0 : (i==1) ? 25 : 106;
      float scale = (float)s / 16.f;
      float sh = fmaxf((h + 0.5f)*scale - 0.5f, 0.f);
      int h0 = min((int)sh, s-1); float wh = sh - (float)h0; int h1 = min(h0+1, s-1);
      float sw = fmaxf((w + 0.5f)*scale - 0.5f, 0.f);
      int w0 = min((int)sw, s-1); float ww2 = sw - (float)w0; int w1 = min(w0+1, s-1);
      const float* pc = pconv + b*275*DIM;
      float v00 = pc[(off + h0*s + w0)*DIM + d];
      float v01 = pc[(off + h0*s + w1)*DIM + d];
      float v10 = pc[(off + h1*s + w0)*DIM + d];
      float v11 = pc[(off + h1*s + w1)*DIM + d];
      val = (1.f-wh)*((1.f-ww2)*v00 + ww2*v01) + wh*((1.f-ww2)*v10 + ww2*v11);
    }
    featB[(size_t)bl*DM + 512 + cc] = f2bf(val);
  }
}

// scan-direction spatial index map (l -> sp)
__device__ __forceinline__ int dir_map(int k, int l) {
  if (k == 0) return l;
  if (k == 1) return ((l & 15) << 4) | (l >> 4);
  if (k == 2) return 255 - l;
  int m = 255 - l; return ((m & 15) << 4) | (m >> 4);
}
// inverse map (sp -> scan l) per direction
__device__ __forceinline__ int inv_map(int k, int sp) {
  int t = ((sp & 15) << 4) | (sp >> 4);
  if (k == 0) return sp;
  if (k == 1) return t;
  if (k == 2) return 255 - sp;
  return 255 - t;
}

// ---------- bf16 MFMA GEMM: C[M][N] = A[M][K] * B[N][K]^T ----------
// MODE 0: f32 store.  MODE 1: bf16 store.
// MODE 4: delta (z-batched over k): dl=softplus(acc+bias); pack (du|dl) bf16 into u32
//         at scan-order row.  MODE 5: f32 store + bf16 copy (aux).
__device__ __forceinline__ void gload_lds16(const short* g, short* l) {
  __builtin_amdgcn_global_load_lds((const __attribute__((address_space(1))) void*)g,
                                   (__attribute__((address_space(3))) void*)l, 16, 0, 0);
}

template<int MODE>
__global__ __launch_bounds__(256) void gemm_bf(const short* __restrict__ Ag,
    const short* __restrict__ Bg, void* __restrict__ Cout, const float* __restrict__ bias,
    int M, int N, int K, int lda, int ldb,
    int azs, int bzs, unsigned czs, int ezs,
    const short* __restrict__ xcb, void* __restrict__ aux) {
  __shared__ short Als[128*64];
  __shared__ short Bls[128*64];
  int kdir = blockIdx.z;
  Ag += (size_t)kdir * azs;
  Bg += (size_t)kdir * bzs;
  size_t cz = (size_t)kdir * czs;
  if (bias) bias += (size_t)kdir * ezs;
  int tid = threadIdx.x;
  int w = tid >> 6, lane = tid & 63;
  int wm = w >> 1, wn = w & 1;
  int row0 = blockIdx.y * 128, col0 = blockIdx.x * 128;
  f32x4 acc[4][4];
  #pragma unroll
  for (int i = 0; i < 4; ++i)
    #pragma unroll
    for (int j = 0; j < 4; ++j)
      acc[i][j] = (f32x4){0.f, 0.f, 0.f, 0.f};

  for (int k0 = 0; k0 < K; k0 += 64) {
    #pragma unroll
    for (int i = 0; i < 4; ++i) {
      int slot = i*256 + w*64 + lane;
      int r = slot >> 3, pc = slot & 7;
      int c = pc ^ (r & 7);
      gload_lds16(Ag + (size_t)(row0 + r)*lda + k0 + c*8, &Als[(i*256 + w*64)*8]);
      gload_lds16(Bg + (size_t)(col0 + r)*ldb + k0 + c*8, &Bls[(i*256 + w*64)*8]);
    }
    __syncthreads();
    #pragma unroll
    for (int ks = 0; ks < 2; ++ks) {
      short8 af[4], bfr[4];
      int rsel = lane & 15, csel = ks*4 + (lane >> 4);
      #pragma unroll
      for (int mi = 0; mi < 4; ++mi) {
        int row = wm*64 + mi*16 + rsel;
        af[mi] = *(const short8*)&Als[row*64 + ((csel ^ (row & 7)) << 3)];
      }
      #pragma unroll
      for (int ni = 0; ni < 4; ++ni) {
        int row = wn*64 + ni*16 + rsel;
        bfr[ni] = *(const short8*)&Bls[row*64 + ((csel ^ (row & 7)) << 3)];
      }
      #pragma unroll
      for (int mi = 0; mi < 4; ++mi)
        #pragma unroll
        for (int ni = 0; ni < 4; ++ni)
          acc[mi][ni] = __builtin_amdgcn_mfma_f32_16x16x32_bf16(af[mi], bfr[ni], acc[mi][ni], 0, 0, 0);
    }
    __syncthreads();
  }
  // epilogue: D row = (lane>>4)*4 + j, col = lane&15
  #pragma unroll
  for (int mi = 0; mi < 4; ++mi) {
    int rbase = row0 + wm*64 + mi*16 + ((lane >> 4) << 2);
    #pragma unroll
    for (int ni = 0; ni < 4; ++ni) {
      int colg = col0 + wn*64 + ni*16 + (lane & 15);
      #pragma unroll
      for (int j = 0; j < 4; ++j) {
        if (MODE == 1) {
          ((short*)Cout)[(size_t)(rbase + j)*N + colg] = f2bf(acc[mi][ni][j]);
        } else if (MODE == 4) {
          int rowg = rbase + j;                 // b*256 + sp
          int b_ = rowg >> 8, sp_ = rowg & 255;
          int lsc = inv_map(kdir, sp_);
          float dl = acc[mi][ni][j] + bias[colg];
          dl = (dl > 20.f) ? dl : log1pf(__expf(dl));
          float ul = bf2f(xcb[(size_t)rowg*N + colg]);   // N == DI
          unsigned pv = ((unsigned)(unsigned short)f2bf(dl*ul) << 16)
                      |  (unsigned)(unsigned short)f2bf(dl);
          ((unsigned*)Cout)[cz + (size_t)(b_*Lsp + lsc)*N + colg] = pv;
        } else if (MODE == 5) {
          float vv = acc[mi][ni][j];
          ((float*)Cout)[(size_t)(rbase + j)*N + colg] = vv;
          ((short*)aux)[(size_t)(rbase + j)*N + colg] = f2bf(vv);
        } else {
          ((float*)Cout)[(size_t)(rbase + j)*N + colg] = acc[mi][ni][j];
        }
      }
    }
  }
}

// ---------- depthwise 3x3 conv + bias + silu -> xcB (bf16); xz is bf16 ----------
__global__ __launch_bounds__(256) void dwconv_kernel(const short* __restrict__ xzB,
    const float* __restrict__ cw, const float* __restrict__ cb, short* __restrict__ xcB) {
  int bl = blockIdx.x;
  int b = bl >> 8, l = bl & 255;
  int h = l >> 4, w = l & 15;
  const short* xzb = xzB + (size_t)b*Lsp*(2*DI);
  for (int d = threadIdx.x; d < DI; d += 256) {
    float s = 0.f;
    #pragma unroll
    for (int dh = -1; dh <= 1; ++dh) {
      int hh = h + dh; if (hh < 0 || hh > 15) continue;
      #pragma unroll
      for (int dw = -1; dw <= 1; ++dw) {
        int ww2 = w + dw; if (ww2 < 0 || ww2 > 15) continue;
        s += bf2f(xzb[(size_t)(hh*16 + ww2)*(2*DI) + d]) * cw[d*9 + (dh+1)*3 + (dw+1)];
      }
    }
    s += cb[d];
    float r = s / (1.f + __expf(-s));   // silu
    xcB[((size_t)b*Lsp + l)*DI + d] = f2bf(r);
  }
}

// ---------- pack B/C columns of P into scan order: PS[(k*4+b)][l][32] ----------
__global__ __launch_bounds__(256) void ps_build(const float* __restrict__ P,
    float* __restrict__ PS) {
  int slab = blockIdx.x;           // k*4 + b
  int k = slab >> 2, b = slab & 3;
  int l = threadIdx.x;
  int sp = dir_map(k, l);
  const float* src = P + (size_t)(b*Lsp + sp)*PW + k*96 + RR;   // 32 floats: B then C
  float* dst = PS + ((size_t)slab*Lsp + l)*32;
  #pragma unroll
  for (int n = 0; n < 32; n += 4)
    *(float4*)(dst + n) = *(const float4*)(src + n);
}

// ---------- scan pass 1: per-chunk local scan -> Pa (decay product), Hend ----------
__global__ __launch_bounds__(256) void scan_pass1(const unsigned* __restrict__ pk,
    const float* __restrict__ PS, const float* __restrict__ A_logs,
    float* __restrict__ Pa, float* __restrict__ Hend) {
  int bk = blockIdx.x;             // b*4+k
  int b = bk >> 2, k = bk & 3;
  int slab = k*Bsz + b;
  int tid = threadIdx.x;
  int wv = tid >> 6, lane = tid & 63;
  int dloc = lane >> 2, ng = lane & 3;
  int d = blockIdx.y*64 + wv*16 + dloc;
  int c = blockIdx.z;
  int n0 = ng*4;
  float A[4], h[4] = {0.f,0.f,0.f,0.f}, pa[4] = {1.f,1.f,1.f,1.f};
  #pragma unroll
  for (int j = 0; j < 4; ++j)
    A[j] = -__expf(A_logs[((size_t)k*DI + d)*NST + n0 + j]);
  const unsigned* pkp = pk + (size_t)slab*Lsp*DI;
  const float* ps  = PS + (size_t)slab*Lsp*32;
  #pragma unroll 2
  for (int l = c*CHUNK; l < (c+1)*CHUNK; ++l) {
    unsigned v = pkp[(size_t)l*DI + d];
    float dl = bf2f((short)(v & 0xffff));
    float du = bf2f((short)(v >> 16));
    float4 Bv = *(const float4*)(ps + l*32 + n0);
    float e0 = __expf(dl*A[0]); h[0] = h[0]*e0 + du*Bv.x; pa[0] *= e0;
    float e1 = __expf(dl*A[1]); h[1] = h[1]*e1 + du*Bv.y; pa[1] *= e1;
    float e2 = __expf(dl*A[2]); h[2] = h[2]*e2 + du*Bv.z; pa[2] *= e2;
    float e3 = __expf(dl*A[3]); h[3] = h[3]*e3 + du*Bv.w; pa[3] *= e3;
  }
  size_t base = ((size_t)(c*16 + bk)*DI + d)*NST + n0;
  #pragma unroll
  for (int j = 0; j < 4; ++j) {
    Pa[base + j] = pa[j];
    Hend[base + j] = h[j];
  }
}

// ---------- combine chunk boundaries ----------
__global__ __launch_bounds__(256) void scan_combine(const float* __restrict__ Pa,
    const float* __restrict__ Hend, float* __restrict__ Hstart) {
  int idx = blockIdx.x*256 + threadIdx.x;    // (bk*DI + d)*16 + n
  const int stride = 16*DI*NST;              // 524288
  float h = 0.f;
  #pragma unroll
  for (int c = 0; c < NCH; ++c) {
    Hstart[c*stride + idx] = h;
    h = Pa[c*stride + idx]*h + Hend[c*stride + idx];
  }
}

// ---------- scan pass 2: rescan with correct Hstart, emit y (bf16) ----------
__global__ __launch_bounds__(256) void scan_pass2(const unsigned* __restrict__ pk,
    const float* __restrict__ PS, const float* __restrict__ A_logs,
    const float* __restrict__ Hstart, short* __restrict__ oyB) {
  int bk = blockIdx.x;             // b*4+k
  int b = bk >> 2, k = bk & 3;
  int slab = k*Bsz + b;
  int tid = threadIdx.x;
  int wv = tid >> 6, lane = tid & 63;
  int dloc = lane >> 2, ng = lane & 3;
  int d = blockIdx.y*64 + wv*16 + dloc;
  int c = blockIdx.z;
  int n0 = ng*4;
  float A[4], h[4];
  #pragma unroll
  for (int j = 0; j < 4; ++j)
    A[j] = -__expf(A_logs[((size_t)k*DI + d)*NST + n0 + j]);
  size_t hbase = ((size_t)(c*16 + bk)*DI + d)*NST + n0;
  #pragma unroll
  for (int j = 0; j < 4; ++j) h[j] = Hstart[hbase + j];
  const unsigned* pkp = pk + (size_t)slab*Lsp*DI;
  const float* ps  = PS + (size_t)slab*Lsp*32;
  short* oy = oyB + (size_t)bk*Lsp*DI;
  #pragma unroll 2
  for (int l = c*CHUNK; l < (c+1)*CHUNK; ++l) {
    unsigned v = pkp[(size_t)l*DI + d];
    float dl = bf2f((short)(v & 0xffff));
    float du = bf2f((short)(v >> 16));
    float4 Bv = *(const float4*)(ps + l*32 + n0);
    float4 Cv = *(const float4*)(ps + l*32 + 16 + n0);
    float y;
    float e0 = __expf(dl*A[0]); h[0] = h[0]*e0 + du*Bv.x; y  = h[0]*Cv.x;
    float e1 = __expf(dl*A[1]); h[1] = h[1]*e1 + du*Bv.y; y += h[1]*Cv.y;
    float e2 = __expf(dl*A[2]); h[2] = h[2]*e2 + du*Bv.z; y += h[2]*Cv.z;
    float e3 = __expf(dl*A[3]); h[3] = h[3]*e3 + du*Bv.w; y += h[3]*Cv.w;
    y += __shfl_xor(y, 1);
    y += __shfl_xor(y, 2);
    if (ng == 0) oy[(size_t)l*DI + d] = f2bf(y);
  }
}

// ---------- combine 4 directions + D*u + LayerNorm + gate with silu(z) -> bf16 ----------
__global__ __launch_bounds__(256) void combine_ln_kernel(const short* __restrict__ oyB,
    const short* __restrict__ xzB, const short* __restrict__ xcB,
    const float* __restrict__ Ds, const float* __restrict__ lng,
    const float* __restrict__ lnb, short* __restrict__ ygB) {
  int bl = blockIdx.x;
  int b = bl >> 8, l = bl & 255;
  int h = l >> 4, w = l & 15;
  int lT = (w << 4) | h;
  const short* oy = oyB + (size_t)b*KK*Lsp*DI;
  float vals[8];
  float sum = 0.f, sumsq = 0.f;
  #pragma unroll
  for (int i = 0; i < 8; ++i) {
    int d = threadIdx.x + i*256;
    float dsum = Ds[d] + Ds[DI + d] + Ds[2*DI + d] + Ds[3*DI + d];
    float yv = bf2f(oy[(size_t)(0*Lsp + l       )*DI + d])
             + bf2f(oy[(size_t)(2*Lsp + (255-l ))*DI + d])
             + bf2f(oy[(size_t)(1*Lsp + lT      )*DI + d])
             + bf2f(oy[(size_t)(3*Lsp + (255-lT))*DI + d])
             + bf2f(xcB[(size_t)bl*DI + d]) * dsum;
    vals[i] = yv; sum += yv; sumsq += yv*yv;
  }
  __shared__ float r1[256], r2[256];
  r1[threadIdx.x] = sum; r2[threadIdx.x] = sumsq; __syncthreads();
  for (int off = 128; off > 0; off >>= 1) {
    if (threadIdx.x < off) { r1[threadIdx.x] += r1[threadIdx.x+off]; r2[threadIdx.x] += r2[threadIdx.x+off]; }
    __syncthreads();
  }
  float mu = r1[0] * (1.f/2048.f);
  float var = r2[0] * (1.f/2048.f) - mu*mu;
  float rstd = rsqrtf(var + 1e-5f);
  const short* zrow = xzB + (size_t)bl*(2*DI) + DI;
  #pragma unroll
  for (int i = 0; i < 8; ++i) {
    int d = threadIdx.x + i*256;
    float z = bf2f(zrow[d]);
    float sz = z / (1.f + __expf(-z));
    ygB[(size_t)bl*DI + d] = f2bf(((vals[i]-mu)*rstd*lng[d] + lnb[d]) * sz);
  }
}

// ---------- cbr epilogue: bias + BN + exact GELU, write NCHW ----------
__global__ void cbr_epilogue(const float* __restrict__ o2, const float* __restrict__ cb,
    const float* __restrict__ g, const float* __restrict__ beta, const float* __restrict__ m_,
    const float* __restrict__ v_, float* __restrict__ out) {
  int idx = blockIdx.x*256 + threadIdx.x;   // (b*128+dd)*256 + l
  int l = idx & 255;
  int rest = idx >> 8;
  int dd = rest & 127;
  int b = rest >> 7;
  float s = o2[((size_t)b*Lsp + l)*DIM + dd] + cb[dd];
  float inv = g[dd] * rsqrtf(v_[dd] + 1e-5f);
  s = s*inv + (beta[dd] - m_[dd]*inv);
  out[idx] = s * 0.5f * (1.f + erff(s * 0.70710678118f));
}

extern "C" void kernel_launch(void* const* d_in, const int* in_sizes, int n_in,
                              void* d_out, int out_size, void* d_ws, size_t ws_size,
                              hipStream_t stream) {
  const float* x        = (const float*)d_in[0];
  const float* pool_w   = (const float*)d_in[1];
  const float* pool_b   = (const float*)d_in[2];
  const float* bn_g     = (const float*)d_in[3];
  const float* bn_b     = (const float*)d_in[4];
  const float* bn_m     = (const float*)d_in[5];
  const float* bn_v     = (const float*)d_in[6];
  const float* in_proj_w= (const float*)d_in[7];
  const float* conv_w   = (const float*)d_in[8];
  const float* conv_b   = (const float*)d_in[9];
  const float* x_proj_w = (const float*)d_in[10];
  const float* dt_w     = (const float*)d_in[11];
  const float* dt_b     = (const float*)d_in[12];
  const float* A_logs   = (const float*)d_in[13];
  const float* Ds       = (const float*)d_in[14];
  const float* ln_g     = (const float*)d_in[15];
  const float* ln_b     = (const float*)d_in[16];
  const float* out_proj_w=(const float*)d_in[17];
  const float* cbr_w    = (const float*)d_in[18];
  const float* cbr_b    = (const float*)d_in[19];
  const float* cbr_g    = (const float*)d_in[20];
  const float* cbr_beta = (const float*)d_in[21];
  const float* cbr_m    = (const float*)d_in[22];
  const float* cbr_v    = (const float*)d_in[23];
  float* out = (float*)d_out;

  if (ws_size < (size_t)WS_FLOATS * sizeof(float)) return;
  float* ws = (float*)d_ws;
  float* pooled   = ws + OFF_POOLED;
  float* pconv    = ws + OFF_PCONV;
  float* y0m      = ws + OFF_Y0M;
  float* P        = ws + OFF_XDBL;
  unsigned* pk    = (unsigned*)(ws + OFF_DELTA);       // packed (du|dl) bf16, scan order
  float* o2       = ws + OFF_O2;

  // overlays (lifetimes audited):
  short* featB = (short*)(ws + OFF_POOLED);            // written xT/feat_fill AFTER pconv, read B
  float* PS    = ws + OFF_POOLED;                      // written after D (featB dead), read F
  short* xzB   = (short*)(ws + OFF_XZ);                // written B (bf16), read C & G
  short* wInB  = (short*)(ws + OFF_DELTA);             // read B; pk written E
  short* wXB   = (short*)(ws + OFF_DELTA + 2097152);   // read D; pk written E
  short* wOB   = (short*)(ws + OFF_FEAT);              // read H
  short* wCB   = (short*)(ws + OFF_PCONV);             // written cvt (pconv still live? see below), read I
  short* xcB   = (short*)(ws + OFF_O1);                // written C, read D/E & G; o1B after
  short* oyB   = (short*)(ws + OFF_OUTY);              // written pass2, read G
  float* Pa    = ws + OFF_OUTY + 4194304;              // written pass1, read combine
  float* Hend  = ws + OFF_OUTY + 4194304 + 2097152;    // written pass1, read combine
  short* dtwB  = (short*)(ws + OFF_OUTY + 4194304);    // read E; Pa written pass1 (after E)
  short* PB    = (short*)(ws + OFF_OUTY + 4194304 + 262144); // written D (MODE5), read E
  float* Hstart= ws + OFF_YG;                          // written combine, read pass2
  short* ygB   = (short*)(ws + OFF_DELTA);             // written G (pk dead), read H
  short* o1B   = (short*)(ws + OFF_O1);                // written H, read I

  // stage A: pyramid pooling (xT AFTER pconv: featB overlays pooled)
  pool0_kernel<<<Bsz*DIM, 256, 0, stream>>>(x, pool_w, pool_b, bn_g, bn_b, bn_m, bn_v, y0m);
  pool_avg_kernel<<<Bsz*Cin, 288, 0, stream>>>(x, pooled);
  pconv_kernel<<<Bsz*275, 128, 0, stream>>>(pooled, pool_w, pool_b, bn_g, bn_b, bn_m, bn_v, pconv);
  xT_kernel<<<dim3(16, 8, Bsz), 256, 0, stream>>>(x, featB);
  feat_fill<<<Bsz*Lsp, 256, 0, stream>>>(y0m, pconv, featB);

  // weight conversions: one fused launch (wCB overlays pconv, which feat_fill still reads —
  // but f2bf5 is enqueued AFTER feat_fill on the stream, so pconv is dead by then)
  f2bf5_kernel<<<3776, 256, 0, stream>>>(in_proj_w, wInB, x_proj_w, wXB,
      out_proj_w, wOB, cbr_w, wCB, dt_w, dtwB);

  // stage B: in_proj GEMM (M=1024, N=4096, K=1024), bf16 out
  gemm_bf<1><<<dim3(32, 8, 1), 256, 0, stream>>>(featB, wInB, xzB, nullptr,
      1024, 4096, 1024, 1024, 1024, 0, 0, 0, 0, nullptr, nullptr);

  // stage C: depthwise conv + silu -> bf16
  dwconv_kernel<<<Bsz*Lsp, 256, 0, stream>>>(xzB, conv_w, conv_b, xcB);

  // stage D: x_proj GEMM -> P (f32) + PB (bf16) in one epilogue; then PS pack
  gemm_bf<5><<<dim3(3, 8, 1), 256, 0, stream>>>(xcB, wXB, P, nullptr,
      1024, PW, 2048, 2048, 2048, 0, 0, 0, 0, nullptr, PB);
  ps_build<<<16, 256, 0, stream>>>(P, PS);

  // stage E: delta as ONE z-batched GEMM (z=k): (M=1024, N=2048, K=64),
  // softplus epilogue packs (du|dl) bf16 into pk at scan-order rows
  gemm_bf<4><<<dim3(16, 8, KK), 256, 0, stream>>>(PB, dtwB, pk, dt_b,
      1024, DI, 64, PW, RR, 96, DI*RR, (unsigned)(Bsz*Lsp*DI), DI, xcB, nullptr);

  // stage F: chunked two-pass selective scan (one packed load per step)
  scan_pass1<<<dim3(Bsz*KK, DI/64, NCH), 256, 0, stream>>>(pk, PS, A_logs, Pa, Hend);
  scan_combine<<<(16*DI*NST)/256, 256, 0, stream>>>(Pa, Hend, Hstart);
  scan_pass2<<<dim3(Bsz*KK, DI/64, NCH), 256, 0, stream>>>(pk, PS, A_logs, Hstart, oyB);

  // stage G: combine + D*u + LN + gate -> bf16 (pk dead; ygB overlays it)
  combine_ln_kernel<<<Bsz*Lsp, 256, 0, stream>>>(oyB, xzB, xcB, Ds, ln_g, ln_b, ygB);

  // stage H: out_proj GEMM (M=1024, N=1024, K=2048), bf16 out
  gemm_bf<1><<<dim3(8, 8, 1), 256, 0, stream>>>(ygB, wOB, o1B, nullptr,
      1024, 1024, 2048, 2048, 2048, 0, 0, 0, 0, nullptr, nullptr);

  // stage I: cbr GEMM (M=1024, N=128, K=1024), f32 out + epilogue
  gemm_bf<0><<<dim3(1, 8, 1), 256, 0, stream>>>(o1B, wCB, o2, nullptr,
      1024, DIM, 1024, 1024, 1024, 0, 0, 0, 0, nullptr, nullptr);
  cbr_epilogue<<<(Bsz*DIM*Lsp)/256, 256, 0, stream>>>(o2, cbr_b, cbr_g, cbr_beta, cbr_m, cbr_v, out);
}

// Round 11
// 347.339 us; speedup vs baseline: 1.3975x; 1.0202x over previous
//
#include <hip/hip_runtime.h>
#include <hip/hip_bf16.h>
#include <math.h>

// ---------- constants ----------
#define Bsz 4
#define Cin 512
#define Hh 16
#define Ww 16
#define Lsp 256
#define DIM 128
#define DM 1024      // dim*4 + 512
#define DI 2048
#define KK 4
#define NST 16
#define RR 64
#define PW 384       // K*96 projection rows
#define NCH 4
#define CHUNK 64     // Lsp / NCH

// ---------- ws layout (floats) — round-4 proven layout ----------
#define OFF_FEAT    0u
#define SZ_FEAT     (Bsz*Lsp*DM)                 // 1048576
#define OFF_POOLED  (OFF_FEAT + SZ_FEAT)
#define SZ_POOLED   (Bsz*Cin*275)                // 563200
#define OFF_PCONV   (OFF_POOLED + SZ_POOLED)
#define SZ_PCONV    (Bsz*275*DIM)                // 140800
#define OFF_Y0M     (OFF_PCONV + SZ_PCONV)
#define SZ_Y0M      (Bsz*DIM)                    // 512
#define OFF_XZ      (OFF_Y0M + SZ_Y0M)
#define SZ_XZ       (Bsz*Lsp*2*DI)               // 4194304
#define OFF_XCT     (OFF_XZ + SZ_XZ)
#define SZ_XCT      (Bsz*Lsp*DI)                 // 2097152
#define OFF_XDBL    (OFF_XCT + SZ_XCT)
#define SZ_XDBL     (Bsz*Lsp*PW)                 // 393216  (P matrix f32)
#define OFF_DELTA   (OFF_XDBL + SZ_XDBL)
#define SZ_DELTA    (Bsz*KK*Lsp*DI)              // 8388608 (pk u32: du|dl packed bf16)
#define OFF_OUTY    (OFF_DELTA + SZ_DELTA)
#define SZ_OUTY     (Bsz*KK*Lsp*DI)              // 8388608 (oyB bf16 + Pa + Hend)
#define OFF_YG      (OFF_OUTY + SZ_OUTY)
#define SZ_YG       (Bsz*Lsp*DI)                 // 2097152 (Hstart)
#define OFF_O1      (OFF_YG + SZ_YG)
#define SZ_O1       (Bsz*Lsp*DM)                 // 1048576 (xcB then o1B)
#define OFF_O2      (OFF_O1 + SZ_O1)
#define SZ_O2       (Bsz*Lsp*DIM)                // 131072
#define WS_FLOATS   (OFF_O2 + SZ_O2)

typedef __attribute__((ext_vector_type(8))) short short8;
typedef __attribute__((ext_vector_type(4))) float f32x4;

__device__ __forceinline__ short f2bf(float x) {
  __hip_bfloat16 h = __float2bfloat16(x);
  short s;
  __builtin_memcpy(&s, &h, 2);
  return s;
}
__device__ __forceinline__ float bf2f(short s) {
  unsigned u = ((unsigned)(unsigned short)s) << 16;
  float f;
  __builtin_memcpy(&f, &u, 4);
  return f;
}
// unpack packed (du|dl): dl = low16<<16, du = high16 in place
__device__ __forceinline__ float unpack_lo(unsigned v) {
  unsigned u = v << 16; float f; __builtin_memcpy(&f, &u, 4); return f;
}
__device__ __forceinline__ float unpack_hi(unsigned v) {
  unsigned u = v & 0xffff0000u; float f; __builtin_memcpy(&f, &u, 4); return f;
}

// ---------- fused f32 -> bf16 convert of the 5 weight tensors ----------
__global__ __launch_bounds__(256) void f2bf5_kernel(
    const float* __restrict__ s0, short* __restrict__ d0,    // 4194304
    const float* __restrict__ s1, short* __restrict__ d1,    // 786432
    const float* __restrict__ s2, short* __restrict__ d2,    // 2097152
    const float* __restrict__ s3, short* __restrict__ d3,    // 131072
    const float* __restrict__ s4, short* __restrict__ d4) {  // 524288
  int blk = blockIdx.x;
  const float* src; short* dst; int base;
  if (blk < 2048)      { src = s0; dst = d0; base = blk; }
  else if (blk < 2432) { src = s1; dst = d1; base = blk - 2048; }
  else if (blk < 3456) { src = s2; dst = d2; base = blk - 2432; }
  else if (blk < 3520) { src = s3; dst = d3; base = blk - 3456; }
  else                 { src = s4; dst = d4; base = blk - 3520; }
  int i = (base*256 + threadIdx.x)*8;
  float4 a = *(const float4*)(src + i);
  float4 b = *(const float4*)(src + i + 4);
  short8 o;
  o[0]=f2bf(a.x); o[1]=f2bf(a.y); o[2]=f2bf(a.z); o[3]=f2bf(a.w);
  o[4]=f2bf(b.x); o[5]=f2bf(b.y); o[6]=f2bf(b.z); o[7]=f2bf(b.w);
  *(short8*)(dst + i) = o;
}

// ---------- pool layer 0: conv1x1+BN+ReLU then global mean (ILP version) ----------
__global__ __launch_bounds__(256) void pool0_kernel(
    const float* __restrict__ x, const float* __restrict__ pw, const float* __restrict__ pb,
    const float* __restrict__ g, const float* __restrict__ bb,
    const float* __restrict__ m, const float* __restrict__ v, float* __restrict__ y0m) {
  int bd = blockIdx.x;             // b*128+d
  int b = bd >> 7, d = bd & 127;
  int l = threadIdx.x;
  const float* xb = x + (b*Cin)*Lsp + l;
  const float* w = pw + d*Cin;
  float a0 = 0.f, a1 = 0.f, a2 = 0.f, a3 = 0.f;
  #pragma unroll 4
  for (int c = 0; c < Cin; c += 4) {
    float4 wv = *(const float4*)(w + c);
    a0 += xb[(c+0)*Lsp] * wv.x;
    a1 += xb[(c+1)*Lsp] * wv.y;
    a2 += xb[(c+2)*Lsp] * wv.z;
    a3 += xb[(c+3)*Lsp] * wv.w;
  }
  float s = (a0 + a1) + (a2 + a3) + pb[d];
  float inv = g[d] * rsqrtf(v[d] + 1e-5f);
  s = s*inv + (bb[d] - m[d]*inv);
  s = fmaxf(s, 0.f);
  __shared__ float red[256];
  red[l] = s; __syncthreads();
  for (int off = 128; off > 0; off >>= 1) {
    if (l < off) red[l] += red[l+off];
    __syncthreads();
  }
  if (l == 0) y0m[bd] = red[0] * (1.f/256.f);
}

// ---------- adaptive avg pool of x to 5x5,9x9,13x13 (concatenated 275 positions) ----------
__device__ __forceinline__ void decode_pos(int pos, int& s, int& pp, int& qq, int& layer) {
  if (pos < 25)       { s = 5;  layer = 1; int t = pos;       pp = t/5;  qq = t%5;  }
  else if (pos < 106) { s = 9;  layer = 2; int t = pos - 25;  pp = t/9;  qq = t%9;  }
  else                { s = 13; layer = 3; int t = pos - 106; pp = t/13; qq = t%13; }
}

__global__ void pool_avg_kernel(const float* __restrict__ x, float* __restrict__ pooled) {
  int bc = blockIdx.x;             // b*512+c
  int pos = threadIdx.x;
  if (pos >= 275) return;
  int s, pp, qq, layer;
  decode_pos(pos, s, pp, qq, layer);
  int hs = (pp*Hh)/s, he = ((pp+1)*Hh + s-1)/s;
  int ws = (qq*Ww)/s, we = ((qq+1)*Ww + s-1)/s;
  const float* xb = x + (size_t)bc*Lsp;
  float acc = 0.f;
  for (int hh = hs; hh < he; ++hh)
    for (int ww2 = ws; ww2 < we; ++ww2)
      acc += xb[hh*Ww + ww2];
  pooled[(size_t)bc*275 + pos] = acc / (float)((he-hs)*(we-ws));
}

// ---------- conv1x1 + BN + ReLU on pooled features (ILP version) ----------
__global__ void pconv_kernel(const float* __restrict__ pooled, const float* __restrict__ pw,
    const float* __restrict__ pb, const float* __restrict__ g, const float* __restrict__ bb,
    const float* __restrict__ m, const float* __restrict__ v, float* __restrict__ pconv) {
  int bp = blockIdx.x;             // b*275+pos
  int b = bp / 275, pos = bp % 275;
  int d = threadIdx.x;             // 0..127
  int s, pp, qq, layer;
  decode_pos(pos, s, pp, qq, layer);
  const float* pc = pooled + b*Cin*275 + pos;
  const float* w = pw + (layer*DIM + d)*Cin;
  float a0 = 0.f, a1 = 0.f, a2 = 0.f, a3 = 0.f;
  #pragma unroll 4
  for (int c = 0; c < Cin; c += 4) {
    float4 wv = *(const float4*)(w + c);
    a0 += pc[(c+0)*275] * wv.x;
    a1 += pc[(c+1)*275] * wv.y;
    a2 += pc[(c+2)*275] * wv.z;
    a3 += pc[(c+3)*275] * wv.w;
  }
  float acc = (a0 + a1) + (a2 + a3) + pb[layer*DIM + d];
  int ld = layer*DIM + d;
  float inv = g[ld] * rsqrtf(v[ld] + 1e-5f);
  acc = acc*inv + (bb[ld] - m[ld]*inv);
  pconv[bp*DIM + d] = fmaxf(acc, 0.f);
}

// ---------- transpose x (b,c,l) f32 -> featB cols 0..511 bf16 (coalesced reads) ----------
// NOTE: featB overlays pooled — must launch AFTER pconv_kernel.
__global__ __launch_bounds__(256) void xT_kernel(const float* __restrict__ x,
    short* __restrict__ featB) {
  int b = blockIdx.z;
  int c0 = blockIdx.x*32, l0 = blockIdx.y*32;
  __shared__ float t[32][33];
  int tx = threadIdx.x & 31, ty = threadIdx.x >> 5;   // 32 x 8
  #pragma unroll
  for (int i = 0; i < 4; ++i) {
    int c = c0 + ty + i*8;
    t[ty + i*8][tx] = x[((size_t)b*Cin + c)*Lsp + l0 + tx];
  }
  __syncthreads();
  #pragma unroll
  for (int i = 0; i < 4; ++i) {
    int l = l0 + ty + i*8;
    featB[(size_t)(b*Lsp + l)*DM + c0 + tx] = f2bf(t[tx][ty + i*8]);
  }
}

// ---------- fill feat cols 512..1023 (y0 broadcast + bilinear upsample) ----------
__global__ __launch_bounds__(256) void feat_fill(const float* __restrict__ y0m,
    const float* __restrict__ pconv, short* __restrict__ featB) {
  int bl = blockIdx.x;             // b*256+l
  int b = bl >> 8, l = bl & 255;
  int h = l >> 4, w = l & 15;
  for (int cc = threadIdx.x; cc < 512; cc += 256) {
    float val;
    if (cc < 128) {
      val = y0m[b*DIM + cc];
    } else {
      int i = (cc - 128) >> 7;               // 0,1,2 -> s=5,9,13
      int d = (cc - 128) & 127;
      int s = (i==0) ? 5 : (i==1) ? 9 : 13;
      int off = (i==0) ? 0 : (i==1) ? 25 : 106;
      float scale = (float)s / 16.f;
      float sh = fmaxf((h + 0.5f)*scale - 0.5f, 0.f);
      int h0 = min((int)sh, s-1); float wh = sh - (float)h0; int h1 = min(h0+1, s-1);
      float sw = fmaxf((w + 0.5f)*scale - 0.5f, 0.f);
      int w0 = min((int)sw, s-1); float ww2 = sw - (float)w0; int w1 = min(w0+1, s-1);
      const float* pc = pconv + b*275*DIM;
      float v00 = pc[(off + h0*s + w0)*DIM + d];
      float v01 = pc[(off + h0*s + w1)*DIM + d];
      float v10 = pc[(off + h1*s + w0)*DIM + d];
      float v11 = pc[(off + h1*s + w1)*DIM + d];
      val = (1.f-wh)*((1.f-ww2)*v00 + ww2*v01) + wh*((1.f-ww2)*v10 + ww2*v11);
    }
    featB[(size_t)bl*DM + 512 + cc] = f2bf(val);
  }
}

// scan-direction spatial index map (l -> sp)
__device__ __forceinline__ int dir_map(int k, int l) {
  if (k == 0) return l;
  if (k == 1) return ((l & 15) << 4) | (l >> 4);
  if (k == 2) return 255 - l;
  int m = 255 - l; return ((m & 15) << 4) | (m >> 4);
}
// inverse map (sp -> scan l) per direction
__device__ __forceinline__ int inv_map(int k, int sp) {
  int t = ((sp & 15) << 4) | (sp >> 4);
  if (k == 0) return sp;
  if (k == 1) return t;
  if (k == 2) return 255 - sp;
  return 255 - t;
}

// ---------- bf16 MFMA GEMM: C[M][N] = A[M][K] * B[N][K]^T ----------
// MODE 0: f32 store.  MODE 1: bf16 store.
// MODE 4: delta (z-batched over k): dl=softplus(acc+bias); pack (du|dl) bf16 into u32
//         at scan-order row.  MODE 5: f32 store + bf16 copy (aux).
__device__ __forceinline__ void gload_lds16(const short* g, short* l) {
  __builtin_amdgcn_global_load_lds((const __attribute__((address_space(1))) void*)g,
                                   (__attribute__((address_space(3))) void*)l, 16, 0, 0);
}

template<int MODE>
__global__ __launch_bounds__(256) void gemm_bf(const short* __restrict__ Ag,
    const short* __restrict__ Bg, void* __restrict__ Cout, const float* __restrict__ bias,
    int M, int N, int K, int lda, int ldb,
    int azs, int bzs, unsigned czs, int ezs,
    const short* __restrict__ xcb, void* __restrict__ aux) {
  __shared__ short Als[128*64];
  __shared__ short Bls[128*64];
  int kdir = blockIdx.z;
  Ag += (size_t)kdir * azs;
  Bg += (size_t)kdir * bzs;
  size_t cz = (size_t)kdir * czs;
  if (bias) bias += (size_t)kdir * ezs;
  int tid = threadIdx.x;
  int w = tid >> 6, lane = tid & 63;
  int wm = w >> 1, wn = w & 1;
  int row0 = blockIdx.y * 128, col0 = blockIdx.x * 128;
  f32x4 acc[4][4];
  #pragma unroll
  for (int i = 0; i < 4; ++i)
    #pragma unroll
    for (int j = 0; j < 4; ++j)
      acc[i][j] = (f32x4){0.f, 0.f, 0.f, 0.f};

  for (int k0 = 0; k0 < K; k0 += 64) {
    #pragma unroll
    for (int i = 0; i < 4; ++i) {
      int slot = i*256 + w*64 + lane;
      int r = slot >> 3, pc = slot & 7;
      int c = pc ^ (r & 7);
      gload_lds16(Ag + (size_t)(row0 + r)*lda + k0 + c*8, &Als[(i*256 + w*64)*8]);
      gload_lds16(Bg + (size_t)(col0 + r)*ldb + k0 + c*8, &Bls[(i*256 + w*64)*8]);
    }
    __syncthreads();
    #pragma unroll
    for (int ks = 0; ks < 2; ++ks) {
      short8 af[4], bfr[4];
      int rsel = lane & 15, csel = ks*4 + (lane >> 4);
      #pragma unroll
      for (int mi = 0; mi < 4; ++mi) {
        int row = wm*64 + mi*16 + rsel;
        af[mi] = *(const short8*)&Als[row*64 + ((csel ^ (row & 7)) << 3)];
      }
      #pragma unroll
      for (int ni = 0; ni < 4; ++ni) {
        int row = wn*64 + ni*16 + rsel;
        bfr[ni] = *(const short8*)&Bls[row*64 + ((csel ^ (row & 7)) << 3)];
      }
      #pragma unroll
      for (int mi = 0; mi < 4; ++mi)
        #pragma unroll
        for (int ni = 0; ni < 4; ++ni)
          acc[mi][ni] = __builtin_amdgcn_mfma_f32_16x16x32_bf16(af[mi], bfr[ni], acc[mi][ni], 0, 0, 0);
    }
    __syncthreads();
  }
  // epilogue: D row = (lane>>4)*4 + j, col = lane&15
  #pragma unroll
  for (int mi = 0; mi < 4; ++mi) {
    int rbase = row0 + wm*64 + mi*16 + ((lane >> 4) << 2);
    #pragma unroll
    for (int ni = 0; ni < 4; ++ni) {
      int colg = col0 + wn*64 + ni*16 + (lane & 15);
      #pragma unroll
      for (int j = 0; j < 4; ++j) {
        if (MODE == 1) {
          ((short*)Cout)[(size_t)(rbase + j)*N + colg] = f2bf(acc[mi][ni][j]);
        } else if (MODE == 4) {
          int rowg = rbase + j;                 // b*256 + sp
          int b_ = rowg >> 8, sp_ = rowg & 255;
          int lsc = inv_map(kdir, sp_);
          float dl = acc[mi][ni][j] + bias[colg];
          dl = (dl > 20.f) ? dl : log1pf(__expf(dl));
          float ul = bf2f(xcb[(size_t)rowg*N + colg]);   // N == DI
          unsigned pv = ((unsigned)(unsigned short)f2bf(dl*ul) << 16)
                      |  (unsigned)(unsigned short)f2bf(dl);
          ((unsigned*)Cout)[cz + (size_t)(b_*Lsp + lsc)*N + colg] = pv;
        } else if (MODE == 5) {
          float vv = acc[mi][ni][j];
          ((float*)Cout)[(size_t)(rbase + j)*N + colg] = vv;
          ((short*)aux)[(size_t)(rbase + j)*N + colg] = f2bf(vv);
        } else {
          ((float*)Cout)[(size_t)(rbase + j)*N + colg] = acc[mi][ni][j];
        }
      }
    }
  }
}

// ---------- depthwise 3x3 conv + bias + silu -> xcB (bf16); 2 d's per thread ----------
__global__ __launch_bounds__(256) void dwconv_kernel(const short* __restrict__ xzB,
    const float* __restrict__ cw, const float* __restrict__ cb, short* __restrict__ xcB) {
  int bl = blockIdx.x;
  int b = bl >> 8, l = bl & 255;
  int h = l >> 4, w = l & 15;
  const short* xzb = xzB + (size_t)b*Lsp*(2*DI);
  #pragma unroll
  for (int it = 0; it < 4; ++it) {
    int d = (threadIdx.x + it*256)*2;
    float s0 = cb[d], s1 = cb[d+1];
    #pragma unroll
    for (int dh = -1; dh <= 1; ++dh) {
      int hh = h + dh; if (hh < 0 || hh > 15) continue;
      #pragma unroll
      for (int dw = -1; dw <= 1; ++dw) {
        int ww2 = w + dw; if (ww2 < 0 || ww2 > 15) continue;
        int t = (dh+1)*3 + (dw+1);
        short2 xv = *(const short2*)&xzb[(size_t)(hh*16 + ww2)*(2*DI) + d];
        s0 += bf2f(xv.x) * cw[d*9 + t];
        s1 += bf2f(xv.y) * cw[(d+1)*9 + t];
      }
    }
    float r0 = s0 / (1.f + __expf(-s0));
    float r1 = s1 / (1.f + __expf(-s1));
    short2 o; o.x = f2bf(r0); o.y = f2bf(r1);
    *(short2*)&xcB[((size_t)b*Lsp + l)*DI + d] = o;
  }
}

// ---------- pack B/C columns of P into scan order: PS[(k*4+b)][l][32] ----------
__global__ __launch_bounds__(256) void ps_build(const float* __restrict__ P,
    float* __restrict__ PS) {
  int slab = blockIdx.x;           // k*4 + b
  int k = slab >> 2, b = slab & 3;
  int l = threadIdx.x;
  int sp = dir_map(k, l);
  const float* src = P + (size_t)(b*Lsp + sp)*PW + k*96 + RR;   // 32 floats: B then C
  float* dst = PS + ((size_t)slab*Lsp + l)*32;
  #pragma unroll
  for (int n = 0; n < 32; n += 4)
    *(float4*)(dst + n) = *(const float4*)(src + n);
}

// ---------- scan pass 1: per-chunk local scan -> Pa, Hend; chunk 0 also emits y ----------
__global__ __launch_bounds__(256) void scan_pass1(const unsigned* __restrict__ pk,
    const float* __restrict__ PS, const float* __restrict__ A_logs,
    float* __restrict__ Pa, float* __restrict__ Hend, short* __restrict__ oyB) {
  int bk = blockIdx.x;             // b*4+k
  int b = bk >> 2, k = bk & 3;
  int slab = k*Bsz + b;
  int tid = threadIdx.x;
  int wv = tid >> 6, lane = tid & 63;
  int dloc = lane >> 2, ng = lane & 3;
  int d = blockIdx.y*64 + wv*16 + dloc;
  int c = blockIdx.z;
  int n0 = ng*4;
  float A[4], h[4] = {0.f,0.f,0.f,0.f};
  float sdl = 0.f;
  #pragma unroll
  for (int j = 0; j < 4; ++j)
    A[j] = -__expf(A_logs[((size_t)k*DI + d)*NST + n0 + j]);
  const unsigned* pkp = pk + (size_t)slab*Lsp*DI;
  const float* ps  = PS + (size_t)slab*Lsp*32;
  if (c == 0) {
    // chunk 0: Hstart is exactly 0 -> this IS the final scan; emit y too.
    short* oy = oyB + (size_t)bk*Lsp*DI;
    #pragma unroll 2
    for (int l = 0; l < CHUNK; ++l) {
      unsigned v = pkp[(size_t)l*DI + d];
      float dl = unpack_lo(v);
      float du = unpack_hi(v);
      sdl += dl;
      float4 Bv = *(const float4*)(ps + l*32 + n0);
      float4 Cv = *(const float4*)(ps + l*32 + 16 + n0);
      float y;
      float e0 = __expf(dl*A[0]); h[0] = h[0]*e0 + du*Bv.x; y  = h[0]*Cv.x;
      float e1 = __expf(dl*A[1]); h[1] = h[1]*e1 + du*Bv.y; y += h[1]*Cv.y;
      float e2 = __expf(dl*A[2]); h[2] = h[2]*e2 + du*Bv.z; y += h[2]*Cv.z;
      float e3 = __expf(dl*A[3]); h[3] = h[3]*e3 + du*Bv.w; y += h[3]*Cv.w;
      y += __shfl_xor(y, 1);
      y += __shfl_xor(y, 2);
      if (ng == 0) oy[(size_t)l*DI + d] = f2bf(y);
    }
  } else {
    #pragma unroll 2
    for (int l = c*CHUNK; l < (c+1)*CHUNK; ++l) {
      unsigned v = pkp[(size_t)l*DI + d];
      float dl = unpack_lo(v);
      float du = unpack_hi(v);
      sdl += dl;
      float4 Bv = *(const float4*)(ps + l*32 + n0);
      float e0 = __expf(dl*A[0]); h[0] = h[0]*e0 + du*Bv.x;
      float e1 = __expf(dl*A[1]); h[1] = h[1]*e1 + du*Bv.y;
      float e2 = __expf(dl*A[2]); h[2] = h[2]*e2 + du*Bv.z;
      float e3 = __expf(dl*A[3]); h[3] = h[3]*e3 + du*Bv.w;
    }
  }
  size_t base = ((size_t)(c*16 + bk)*DI + d)*NST + n0;
  #pragma unroll
  for (int j = 0; j < 4; ++j) {
    Pa[base + j] = __expf(A[j]*sdl);   // product of per-step decays == exp of summed dl
    Hend[base + j] = h[j];
  }
}

// ---------- combine chunk boundaries ----------
__global__ __launch_bounds__(256) void scan_combine(const float* __restrict__ Pa,
    const float* __restrict__ Hend, float* __restrict__ Hstart) {
  int idx = blockIdx.x*256 + threadIdx.x;    // (bk*DI + d)*16 + n
  const int stride = 16*DI*NST;              // 524288
  float h = 0.f;
  #pragma unroll
  for (int c = 0; c < NCH; ++c) {
    Hstart[c*stride + idx] = h;
    h = Pa[c*stride + idx]*h + Hend[c*stride + idx];
  }
}

// ---------- scan pass 2: rescan chunks 1..3 with correct Hstart, emit y (bf16) ----------
__global__ __launch_bounds__(256) void scan_pass2(const unsigned* __restrict__ pk,
    const float* __restrict__ PS, const float* __restrict__ A_logs,
    const float* __restrict__ Hstart, short* __restrict__ oyB) {
  int bk = blockIdx.x;             // b*4+k
  int b = bk >> 2, k = bk & 3;
  int slab = k*Bsz + b;
  int tid = threadIdx.x;
  int wv = tid >> 6, lane = tid & 63;
  int dloc = lane >> 2, ng = lane & 3;
  int d = blockIdx.y*64 + wv*16 + dloc;
  int c = blockIdx.z + 1;          // chunks 1..3 (chunk 0 emitted by pass1)
  int n0 = ng*4;
  float A[4], h[4];
  #pragma unroll
  for (int j = 0; j < 4; ++j)
    A[j] = -__expf(A_logs[((size_t)k*DI + d)*NST + n0 + j]);
  size_t hbase = ((size_t)(c*16 + bk)*DI + d)*NST + n0;
  #pragma unroll
  for (int j = 0; j < 4; ++j) h[j] = Hstart[hbase + j];
  const unsigned* pkp = pk + (size_t)slab*Lsp*DI;
  const float* ps  = PS + (size_t)slab*Lsp*32;
  short* oy = oyB + (size_t)bk*Lsp*DI;
  #pragma unroll 2
  for (int l = c*CHUNK; l < (c+1)*CHUNK; ++l) {
    unsigned v = pkp[(size_t)l*DI + d];
    float dl = unpack_lo(v);
    float du = unpack_hi(v);
    float4 Bv = *(const float4*)(ps + l*32 + n0);
    float4 Cv = *(const float4*)(ps + l*32 + 16 + n0);
    float y;
    float e0 = __expf(dl*A[0]); h[0] = h[0]*e0 + du*Bv.x; y  = h[0]*Cv.x;
    float e1 = __expf(dl*A[1]); h[1] = h[1]*e1 + du*Bv.y; y += h[1]*Cv.y;
    float e2 = __expf(dl*A[2]); h[2] = h[2]*e2 + du*Bv.z; y += h[2]*Cv.z;
    float e3 = __expf(dl*A[3]); h[3] = h[3]*e3 + du*Bv.w; y += h[3]*Cv.w;
    y += __shfl_xor(y, 1);
    y += __shfl_xor(y, 2);
    if (ng == 0) oy[(size_t)l*DI + d] = f2bf(y);
  }
}

// ---------- combine 4 directions + D*u + LayerNorm + gate with silu(z) -> bf16 ----------
__global__ __launch_bounds__(256) void combine_ln_kernel(const short* __restrict__ oyB,
    const short* __restrict__ xzB, const short* __restrict__ xcB,
    const float* __restrict__ Ds, const float* __restrict__ lng,
    const float* __restrict__ lnb, short* __restrict__ ygB) {
  int bl = blockIdx.x;
  int b = bl >> 8, l = bl & 255;
  int h = l >> 4, w = l & 15;
  int lT = (w << 4) | h;
  const short* oy = oyB + (size_t)b*KK*Lsp*DI;
  float vals[8];
  float sum = 0.f, sumsq = 0.f;
  #pragma unroll
  for (int i = 0; i < 8; ++i) {
    int d = threadIdx.x + i*256;
    float dsum = Ds[d] + Ds[DI + d] + Ds[2*DI + d] + Ds[3*DI + d];
    float yv = bf2f(oy[(size_t)(0*Lsp + l       )*DI + d])
             + bf2f(oy[(size_t)(2*Lsp + (255-l ))*DI + d])
             + bf2f(oy[(size_t)(1*Lsp + lT      )*DI + d])
             + bf2f(oy[(size_t)(3*Lsp + (255-lT))*DI + d])
             + bf2f(xcB[(size_t)bl*DI + d]) * dsum;
    vals[i] = yv; sum += yv; sumsq += yv*yv;
  }
  __shared__ float r1[256], r2[256];
  r1[threadIdx.x] = sum; r2[threadIdx.x] = sumsq; __syncthreads();
  for (int off = 128; off > 0; off >>= 1) {
    if (threadIdx.x < off) { r1[threadIdx.x] += r1[threadIdx.x+off]; r2[threadIdx.x] += r2[threadIdx.x+off]; }
    __syncthreads();
  }
  float mu = r1[0] * (1.f/2048.f);
  float var = r2[0] * (1.f/2048.f) - mu*mu;
  float rstd = rsqrtf(var + 1e-5f);
  const short* zrow = xzB + (size_t)bl*(2*DI) + DI;
  #pragma unroll
  for (int i = 0; i < 8; ++i) {
    int d = threadIdx.x + i*256;
    float z = bf2f(zrow[d]);
    float sz = z / (1.f + __expf(-z));
    ygB[(size_t)bl*DI + d] = f2bf(((vals[i]-mu)*rstd*lng[d] + lnb[d]) * sz);
  }
}

// ---------- cbr epilogue: bias + BN + exact GELU, write NCHW ----------
__global__ void cbr_epilogue(const float* __restrict__ o2, const float* __restrict__ cb,
    const float* __restrict__ g, const float* __restrict__ beta, const float* __restrict__ m_,
    const float* __restrict__ v_, float* __restrict__ out) {
  int idx = blockIdx.x*256 + threadIdx.x;   // (b*128+dd)*256 + l
  int l = idx & 255;
  int rest = idx >> 8;
  int dd = rest & 127;
  int b = rest >> 7;
  float s = o2[((size_t)b*Lsp + l)*DIM + dd] + cb[dd];
  float inv = g[dd] * rsqrtf(v_[dd] + 1e-5f);
  s = s*inv + (beta[dd] - m_[dd]*inv);
  out[idx] = s * 0.5f * (1.f + erff(s * 0.70710678118f));
}

extern "C" void kernel_launch(void* const* d_in, const int* in_sizes, int n_in,
                              void* d_out, int out_size, void* d_ws, size_t ws_size,
                              hipStream_t stream) {
  const float* x        = (const float*)d_in[0];
  const float* pool_w   = (const float*)d_in[1];
  const float* pool_b   = (const float*)d_in[2];
  const float* bn_g     = (const float*)d_in[3];
  const float* bn_b     = (const float*)d_in[4];
  const float* bn_m     = (const float*)d_in[5];
  const float* bn_v     = (const float*)d_in[6];
  const float* in_proj_w= (const float*)d_in[7];
  const float* conv_w   = (const float*)d_in[8];
  const float* conv_b   = (const float*)d_in[9];
  const float* x_proj_w = (const float*)d_in[10];
  const float* dt_w     = (const float*)d_in[11];
  const float* dt_b     = (const float*)d_in[12];
  const float* A_logs   = (const float*)d_in[13];
  const float* Ds       = (const float*)d_in[14];
  const float* ln_g     = (const float*)d_in[15];
  const float* ln_b     = (const float*)d_in[16];
  const float* out_proj_w=(const float*)d_in[17];
  const float* cbr_w    = (const float*)d_in[18];
  const float* cbr_b    = (const float*)d_in[19];
  const float* cbr_g    = (const float*)d_in[20];
  const float* cbr_beta = (const float*)d_in[21];
  const float* cbr_m    = (const float*)d_in[22];
  const float* cbr_v    = (const float*)d_in[23];
  float* out = (float*)d_out;

  if (ws_size < (size_t)WS_FLOATS * sizeof(float)) return;
  float* ws = (float*)d_ws;
  float* pooled   = ws + OFF_POOLED;
  float* pconv    = ws + OFF_PCONV;
  float* y0m      = ws + OFF_Y0M;
  float* P        = ws + OFF_XDBL;
  unsigned* pk    = (unsigned*)(ws + OFF_DELTA);       // packed (du|dl) bf16, scan order
  float* o2       = ws + OFF_O2;

  // overlays (lifetimes audited):
  short* featB = (short*)(ws + OFF_POOLED);            // written xT/feat_fill AFTER pconv, read B
  float* PS    = ws + OFF_POOLED;                      // written after D (featB dead), read F
  short* xzB   = (short*)(ws + OFF_XZ);                // written B (bf16), read C & G
  short* wInB  = (short*)(ws + OFF_DELTA);             // read B; pk written E
  short* wXB   = (short*)(ws + OFF_DELTA + 2097152);   // read D; pk written E
  short* wOB   = (short*)(ws + OFF_FEAT);              // read H
  short* wCB   = (short*)(ws + OFF_PCONV);             // written cvt after feat_fill, read I
  short* xcB   = (short*)(ws + OFF_O1);                // written C, read D/E & G; o1B after
  short* oyB   = (short*)(ws + OFF_OUTY);              // written pass1(c0)/pass2, read G
  float* Pa    = ws + OFF_OUTY + 4194304;              // written pass1, read combine
  float* Hend  = ws + OFF_OUTY + 4194304 + 2097152;    // written pass1, read combine
  short* dtwB  = (short*)(ws + OFF_OUTY + 4194304);    // read E; Pa written pass1 (after E)
  short* PB    = (short*)(ws + OFF_OUTY + 4194304 + 262144); // written D (MODE5), read E
  float* Hstart= ws + OFF_YG;                          // written combine, read pass2
  short* ygB   = (short*)(ws + OFF_DELTA);             // written G (pk dead), read H
  short* o1B   = (short*)(ws + OFF_O1);                // written H, read I
  // NOTE: pass1 chunk-0 writes oyB rows 0..63; Pa/Hend live at OFF_OUTY+16MB — disjoint
  // (oyB bf16 uses first 16MB of the 32MB OUTY region).

  // stage A: pyramid pooling (xT AFTER pconv: featB overlays pooled)
  pool0_kernel<<<Bsz*DIM, 256, 0, stream>>>(x, pool_w, pool_b, bn_g, bn_b, bn_m, bn_v, y0m);
  pool_avg_kernel<<<Bsz*Cin, 288, 0, stream>>>(x, pooled);
  pconv_kernel<<<Bsz*275, 128, 0, stream>>>(pooled, pool_w, pool_b, bn_g, bn_b, bn_m, bn_v, pconv);
  xT_kernel<<<dim3(16, 8, Bsz), 256, 0, stream>>>(x, featB);
  feat_fill<<<Bsz*Lsp, 256, 0, stream>>>(y0m, pconv, featB);

  // weight conversions: one fused launch (enqueued after feat_fill -> pconv dead)
  f2bf5_kernel<<<3776, 256, 0, stream>>>(in_proj_w, wInB, x_proj_w, wXB,
      out_proj_w, wOB, cbr_w, wCB, dt_w, dtwB);

  // stage B: in_proj GEMM (M=1024, N=4096, K=1024), bf16 out
  gemm_bf<1><<<dim3(32, 8, 1), 256, 0, stream>>>(featB, wInB, xzB, nullptr,
      1024, 4096, 1024, 1024, 1024, 0, 0, 0, 0, nullptr, nullptr);

  // stage C: depthwise conv + silu -> bf16
  dwconv_kernel<<<Bsz*Lsp, 256, 0, stream>>>(xzB, conv_w, conv_b, xcB);

  // stage D: x_proj GEMM -> P (f32) + PB (bf16) in one epilogue; then PS pack
  gemm_bf<5><<<dim3(3, 8, 1), 256, 0, stream>>>(xcB, wXB, P, nullptr,
      1024, PW, 2048, 2048, 2048, 0, 0, 0, 0, nullptr, PB);
  ps_build<<<16, 256, 0, stream>>>(P, PS);

  // stage E: delta as ONE z-batched GEMM (z=k): (M=1024, N=2048, K=64),
  // softplus epilogue packs (du|dl) bf16 into pk at scan-order rows
  gemm_bf<4><<<dim3(16, 8, KK), 256, 0, stream>>>(PB, dtwB, pk, dt_b,
      1024, DI, 64, PW, RR, 96, DI*RR, (unsigned)(Bsz*Lsp*DI), DI, xcB, nullptr);

  // stage F: chunked two-pass selective scan; pass1 emits chunk-0 y directly
  scan_pass1<<<dim3(Bsz*KK, DI/64, NCH), 256, 0, stream>>>(pk, PS, A_logs, Pa, Hend, oyB);
  scan_combine<<<(16*DI*NST)/256, 256, 0, stream>>>(Pa, Hend, Hstart);
  scan_pass2<<<dim3(Bsz*KK, DI/64, NCH-1), 256, 0, stream>>>(pk, PS, A_logs, Hstart, oyB);

  // stage G: combine + D*u + LN + gate -> bf16 (pk dead; ygB overlays it)
  combine_ln_kernel<<<Bsz*Lsp, 256, 0, stream>>>(oyB, xzB, xcB, Ds, ln_g, ln_b, ygB);

  // stage H: out_proj GEMM (M=1024, N=1024, K=2048), bf16 out
  gemm_bf<1><<<dim3(8, 8, 1), 256, 0, stream>>>(ygB, wOB, o1B, nullptr,
      1024, 1024, 2048, 2048, 2048, 0, 0, 0, 0, nullptr, nullptr);

  // stage I: cbr GEMM (M=1024, N=128, K=1024), f32 out + epilogue
  gemm_bf<0><<<dim3(1, 8, 1), 256, 0, stream>>>(o1B, wCB, o2, nullptr,
      1024, DIM, 1024, 1024, 1024, 0, 0, 0, 0, nullptr, nullptr);
  cbr_epilogue<<<(Bsz*DIM*Lsp)/256, 256, 0, stream>>>(o2, cbr_b, cbr_g, cbr_beta, cbr_m, cbr_v, out);
}

// Round 12
// 319.123 us; speedup vs baseline: 1.5210x; 1.0884x over previous
//
#include <hip/hip_runtime.h>
#include <hip/hip_bf16.h>
#include <math.h>

// ---------- constants ----------
#define Bsz 4
#define Cin 512
#define Hh 16
#define Ww 16
#define Lsp 256
#define DIM 128
#define DM 1024      // dim*4 + 512
#define DI 2048
#define KK 4
#define NST 16
#define RR 64
#define PW 384       // K*96 projection rows
#define NCH 4
#define CHUNK 64     // Lsp / NCH

// ---------- ws layout (floats) — round-4 proven layout ----------
#define OFF_FEAT    0u
#define SZ_FEAT     (Bsz*Lsp*DM)                 // 1048576
#define OFF_POOLED  (OFF_FEAT + SZ_FEAT)
#define SZ_POOLED   (Bsz*Cin*275)                // 563200
#define OFF_PCONV   (OFF_POOLED + SZ_POOLED)
#define SZ_PCONV    (Bsz*275*DIM)                // 140800
#define OFF_Y0M     (OFF_PCONV + SZ_PCONV)
#define SZ_Y0M      (Bsz*DIM)                    // 512
#define OFF_XZ      (OFF_Y0M + SZ_Y0M)
#define SZ_XZ       (Bsz*Lsp*2*DI)               // 4194304
#define OFF_XCT     (OFF_XZ + SZ_XZ)
#define SZ_XCT      (Bsz*Lsp*DI)                 // 2097152
#define OFF_XDBL    (OFF_XCT + SZ_XCT)
#define SZ_XDBL     (Bsz*Lsp*PW)                 // 393216  (P matrix f32)
#define OFF_DELTA   (OFF_XDBL + SZ_XDBL)
#define SZ_DELTA    (Bsz*KK*Lsp*DI)              // 8388608 (pk u32: du|dl packed bf16)
#define OFF_OUTY    (OFF_DELTA + SZ_DELTA)
#define SZ_OUTY     (Bsz*KK*Lsp*DI)              // 8388608 (oyB bf16 + Pa + Hend)
#define OFF_YG      (OFF_OUTY + SZ_OUTY)
#define SZ_YG       (Bsz*Lsp*DI)                 // 2097152 (Hstart)
#define OFF_O1      (OFF_YG + SZ_YG)
#define SZ_O1       (Bsz*Lsp*DM)                 // 1048576 (xcB then o1B)
#define OFF_O2      (OFF_O1 + SZ_O1)
#define SZ_O2       (Bsz*Lsp*DIM)                // 131072
#define WS_FLOATS   (OFF_O2 + SZ_O2)

typedef __attribute__((ext_vector_type(8))) short short8;
typedef __attribute__((ext_vector_type(4))) float f32x4;

__device__ __forceinline__ short f2bf(float x) {
  __hip_bfloat16 h = __float2bfloat16(x);
  short s;
  __builtin_memcpy(&s, &h, 2);
  return s;
}
__device__ __forceinline__ float bf2f(short s) {
  unsigned u = ((unsigned)(unsigned short)s) << 16;
  float f;
  __builtin_memcpy(&f, &u, 4);
  return f;
}
// unpack packed (du|dl): dl = low16<<16, du = high16 in place
__device__ __forceinline__ float unpack_lo(unsigned v) {
  unsigned u = v << 16; float f; __builtin_memcpy(&f, &u, 4); return f;
}
__device__ __forceinline__ float unpack_hi(unsigned v) {
  unsigned u = v & 0xffff0000u; float f; __builtin_memcpy(&f, &u, 4); return f;
}

// ---------- fused f32 -> bf16 convert of the 5 weight tensors ----------
__global__ __launch_bounds__(256) void f2bf5_kernel(
    const float* __restrict__ s0, short* __restrict__ d0,    // 4194304
    const float* __restrict__ s1, short* __restrict__ d1,    // 786432
    const float* __restrict__ s2, short* __restrict__ d2,    // 2097152
    const float* __restrict__ s3, short* __restrict__ d3,    // 131072
    const float* __restrict__ s4, short* __restrict__ d4) {  // 524288
  int blk = blockIdx.x;
  const float* src; short* dst; int base;
  if (blk < 2048)      { src = s0; dst = d0; base = blk; }
  else if (blk < 2432) { src = s1; dst = d1; base = blk - 2048; }
  else if (blk < 3456) { src = s2; dst = d2; base = blk - 2432; }
  else if (blk < 3520) { src = s3; dst = d3; base = blk - 3456; }
  else                 { src = s4; dst = d4; base = blk - 3520; }
  int i = (base*256 + threadIdx.x)*8;
  float4 a = *(const float4*)(src + i);
  float4 b = *(const float4*)(src + i + 4);
  short8 o;
  o[0]=f2bf(a.x); o[1]=f2bf(a.y); o[2]=f2bf(a.z); o[3]=f2bf(a.w);
  o[4]=f2bf(b.x); o[5]=f2bf(b.y); o[6]=f2bf(b.z); o[7]=f2bf(b.w);
  *(short8*)(dst + i) = o;
}

// ---------- pool layer 0: conv1x1+BN+ReLU then global mean (ILP version) ----------
__global__ __launch_bounds__(256) void pool0_kernel(
    const float* __restrict__ x, const float* __restrict__ pw, const float* __restrict__ pb,
    const float* __restrict__ g, const float* __restrict__ bb,
    const float* __restrict__ m, const float* __restrict__ v, float* __restrict__ y0m) {
  int bd = blockIdx.x;             // b*128+d
  int b = bd >> 7, d = bd & 127;
  int l = threadIdx.x;
  const float* xb = x + (b*Cin)*Lsp + l;
  const float* w = pw + d*Cin;
  float a0 = 0.f, a1 = 0.f, a2 = 0.f, a3 = 0.f;
  #pragma unroll 4
  for (int c = 0; c < Cin; c += 4) {
    float4 wv = *(const float4*)(w + c);
    a0 += xb[(c+0)*Lsp] * wv.x;
    a1 += xb[(c+1)*Lsp] * wv.y;
    a2 += xb[(c+2)*Lsp] * wv.z;
    a3 += xb[(c+3)*Lsp] * wv.w;
  }
  float s = (a0 + a1) + (a2 + a3) + pb[d];
  float inv = g[d] * rsqrtf(v[d] + 1e-5f);
  s = s*inv + (bb[d] - m[d]*inv);
  s = fmaxf(s, 0.f);
  __shared__ float red[256];
  red[l] = s; __syncthreads();
  for (int off = 128; off > 0; off >>= 1) {
    if (l < off) red[l] += red[l+off];
    __syncthreads();
  }
  if (l == 0) y0m[bd] = red[0] * (1.f/256.f);
}

// ---------- adaptive avg pool of x to 5x5,9x9,13x13 (concatenated 275 positions) ----------
__device__ __forceinline__ void decode_pos(int pos, int& s, int& pp, int& qq, int& layer) {
  if (pos < 25)       { s = 5;  layer = 1; int t = pos;       pp = t/5;  qq = t%5;  }
  else if (pos < 106) { s = 9;  layer = 2; int t = pos - 25;  pp = t/9;  qq = t%9;  }
  else                { s = 13; layer = 3; int t = pos - 106; pp = t/13; qq = t%13; }
}

__global__ void pool_avg_kernel(const float* __restrict__ x, float* __restrict__ pooled) {
  int bc = blockIdx.x;             // b*512+c
  int pos = threadIdx.x;
  if (pos >= 275) return;
  int s, pp, qq, layer;
  decode_pos(pos, s, pp, qq, layer);
  int hs = (pp*Hh)/s, he = ((pp+1)*Hh + s-1)/s;
  int ws = (qq*Ww)/s, we = ((qq+1)*Ww + s-1)/s;
  const float* xb = x + (size_t)bc*Lsp;
  float acc = 0.f;
  for (int hh = hs; hh < he; ++hh)
    for (int ww2 = ws; ww2 < we; ++ww2)
      acc += xb[hh*Ww + ww2];
  pooled[(size_t)bc*275 + pos] = acc / (float)((he-hs)*(we-ws));
}

// ---------- conv1x1 + BN + ReLU on pooled features (ILP version) ----------
__global__ void pconv_kernel(const float* __restrict__ pooled, const float* __restrict__ pw,
    const float* __restrict__ pb, const float* __restrict__ g, const float* __restrict__ bb,
    const float* __restrict__ m, const float* __restrict__ v, float* __restrict__ pconv) {
  int bp = blockIdx.x;             // b*275+pos
  int b = bp / 275, pos = bp % 275;
  int d = threadIdx.x;             // 0..127
  int s, pp, qq, layer;
  decode_pos(pos, s, pp, qq, layer);
  const float* pc = pooled + b*Cin*275 + pos;
  const float* w = pw + (layer*DIM + d)*Cin;
  float a0 = 0.f, a1 = 0.f, a2 = 0.f, a3 = 0.f;
  #pragma unroll 4
  for (int c = 0; c < Cin; c += 4) {
    float4 wv = *(const float4*)(w + c);
    a0 += pc[(c+0)*275] * wv.x;
    a1 += pc[(c+1)*275] * wv.y;
    a2 += pc[(c+2)*275] * wv.z;
    a3 += pc[(c+3)*275] * wv.w;
  }
  float acc = (a0 + a1) + (a2 + a3) + pb[layer*DIM + d];
  int ld = layer*DIM + d;
  float inv = g[ld] * rsqrtf(v[ld] + 1e-5f);
  acc = acc*inv + (bb[ld] - m[ld]*inv);
  pconv[bp*DIM + d] = fmaxf(acc, 0.f);
}

// ---------- transpose x (b,c,l) f32 -> featB cols 0..511 bf16 (coalesced reads) ----------
// NOTE: featB overlays pooled — must launch AFTER pconv_kernel.
__global__ __launch_bounds__(256) void xT_kernel(const float* __restrict__ x,
    short* __restrict__ featB) {
  int b = blockIdx.z;
  int c0 = blockIdx.x*32, l0 = blockIdx.y*32;
  __shared__ float t[32][33];
  int tx = threadIdx.x & 31, ty = threadIdx.x >> 5;   // 32 x 8
  #pragma unroll
  for (int i = 0; i < 4; ++i) {
    int c = c0 + ty + i*8;
    t[ty + i*8][tx] = x[((size_t)b*Cin + c)*Lsp + l0 + tx];
  }
  __syncthreads();
  #pragma unroll
  for (int i = 0; i < 4; ++i) {
    int l = l0 + ty + i*8;
    featB[(size_t)(b*Lsp + l)*DM + c0 + tx] = f2bf(t[tx][ty + i*8]);
  }
}

// ---------- fill feat cols 512..1023 (y0 broadcast + bilinear upsample) ----------
__global__ __launch_bounds__(256) void feat_fill(const float* __restrict__ y0m,
    const float* __restrict__ pconv, short* __restrict__ featB) {
  int bl = blockIdx.x;             // b*256+l
  int b = bl >> 8, l = bl & 255;
  int h = l >> 4, w = l & 15;
  for (int cc = threadIdx.x; cc < 512; cc += 256) {
    float val;
    if (cc < 128) {
      val = y0m[b*DIM + cc];
    } else {
      int i = (cc - 128) >> 7;               // 0,1,2 -> s=5,9,13
      int d = (cc - 128) & 127;
      int s = (i==0) ? 5 : (i==1) ? 9 : 13;
      int off = (i==0) ? 0 : (i==1) ? 25 : 106;
      float scale = (float)s / 16.f;
      float sh = fmaxf((h + 0.5f)*scale - 0.5f, 0.f);
      int h0 = min((int)sh, s-1); float wh = sh - (float)h0; int h1 = min(h0+1, s-1);
      float sw = fmaxf((w + 0.5f)*scale - 0.5f, 0.f);
      int w0 = min((int)sw, s-1); float ww2 = sw - (float)w0; int w1 = min(w0+1, s-1);
      const float* pc = pconv + b*275*DIM;
      float v00 = pc[(off + h0*s + w0)*DIM + d];
      float v01 = pc[(off + h0*s + w1)*DIM + d];
      float v10 = pc[(off + h1*s + w0)*DIM + d];
      float v11 = pc[(off + h1*s + w1)*DIM + d];
      val = (1.f-wh)*((1.f-ww2)*v00 + ww2*v01) + wh*((1.f-ww2)*v10 + ww2*v11);
    }
    featB[(size_t)bl*DM + 512 + cc] = f2bf(val);
  }
}

// scan-direction spatial index map (l -> sp)
__device__ __forceinline__ int dir_map(int k, int l) {
  if (k == 0) return l;
  if (k == 1) return ((l & 15) << 4) | (l >> 4);
  if (k == 2) return 255 - l;
  int m = 255 - l; return ((m & 15) << 4) | (m >> 4);
}
// inverse map (sp -> scan l) per direction
__device__ __forceinline__ int inv_map(int k, int sp) {
  int t = ((sp & 15) << 4) | (sp >> 4);
  if (k == 0) return sp;
  if (k == 1) return t;
  if (k == 2) return 255 - sp;
  return 255 - t;
}

// ---------- bf16 MFMA GEMM: C[M][N] = A[M][K] * B[N][K]^T ----------
// MODE 0: f32 store.  MODE 1: bf16 store.
// MODE 4: delta (z-batched over k): dl=softplus(acc+bias); pack (du|dl) bf16 into u32
//         at scan-order row.  MODE 5: f32 store + bf16 copy (aux).
__device__ __forceinline__ void gload_lds16(const short* g, short* l) {
  __builtin_amdgcn_global_load_lds((const __attribute__((address_space(1))) void*)g,
                                   (__attribute__((address_space(3))) void*)l, 16, 0, 0);
}

template<int MODE>
__global__ __launch_bounds__(256) void gemm_bf(const short* __restrict__ Ag,
    const short* __restrict__ Bg, void* __restrict__ Cout, const float* __restrict__ bias,
    int M, int N, int K, int lda, int ldb,
    int azs, int bzs, unsigned czs, int ezs,
    const short* __restrict__ xcb, void* __restrict__ aux) {
  __shared__ short Als[128*64];
  __shared__ short Bls[128*64];
  int kdir = blockIdx.z;
  Ag += (size_t)kdir * azs;
  Bg += (size_t)kdir * bzs;
  size_t cz = (size_t)kdir * czs;
  if (bias) bias += (size_t)kdir * ezs;
  int tid = threadIdx.x;
  int w = tid >> 6, lane = tid & 63;
  int wm = w >> 1, wn = w & 1;
  int row0 = blockIdx.y * 128, col0 = blockIdx.x * 128;
  f32x4 acc[4][4];
  #pragma unroll
  for (int i = 0; i < 4; ++i)
    #pragma unroll
    for (int j = 0; j < 4; ++j)
      acc[i][j] = (f32x4){0.f, 0.f, 0.f, 0.f};

  for (int k0 = 0; k0 < K; k0 += 64) {
    #pragma unroll
    for (int i = 0; i < 4; ++i) {
      int slot = i*256 + w*64 + lane;
      int r = slot >> 3, pc = slot & 7;
      int c = pc ^ (r & 7);
      gload_lds16(Ag + (size_t)(row0 + r)*lda + k0 + c*8, &Als[(i*256 + w*64)*8]);
      gload_lds16(Bg + (size_t)(col0 + r)*ldb + k0 + c*8, &Bls[(i*256 + w*64)*8]);
    }
    __syncthreads();
    #pragma unroll
    for (int ks = 0; ks < 2; ++ks) {
      short8 af[4], bfr[4];
      int rsel = lane & 15, csel = ks*4 + (lane >> 4);
      #pragma unroll
      for (int mi = 0; mi < 4; ++mi) {
        int row = wm*64 + mi*16 + rsel;
        af[mi] = *(const short8*)&Als[row*64 + ((csel ^ (row & 7)) << 3)];
      }
      #pragma unroll
      for (int ni = 0; ni < 4; ++ni) {
        int row = wn*64 + ni*16 + rsel;
        bfr[ni] = *(const short8*)&Bls[row*64 + ((csel ^ (row & 7)) << 3)];
      }
      #pragma unroll
      for (int mi = 0; mi < 4; ++mi)
        #pragma unroll
        for (int ni = 0; ni < 4; ++ni)
          acc[mi][ni] = __builtin_amdgcn_mfma_f32_16x16x32_bf16(af[mi], bfr[ni], acc[mi][ni], 0, 0, 0);
    }
    __syncthreads();
  }
  // epilogue: D row = (lane>>4)*4 + j, col = lane&15
  #pragma unroll
  for (int mi = 0; mi < 4; ++mi) {
    int rbase = row0 + wm*64 + mi*16 + ((lane >> 4) << 2);
    #pragma unroll
    for (int ni = 0; ni < 4; ++ni) {
      int colg = col0 + wn*64 + ni*16 + (lane & 15);
      #pragma unroll
      for (int j = 0; j < 4; ++j) {
        if (MODE == 1) {
          ((short*)Cout)[(size_t)(rbase + j)*N + colg] = f2bf(acc[mi][ni][j]);
        } else if (MODE == 4) {
          int rowg = rbase + j;                 // b*256 + sp
          int b_ = rowg >> 8, sp_ = rowg & 255;
          int lsc = inv_map(kdir, sp_);
          float dl = acc[mi][ni][j] + bias[colg];
          // native softplus: v_exp + v_log (bf16-rounded downstream, 1-ulp f32 is plenty)
          dl = (dl > 20.f) ? dl : __logf(1.f + __expf(dl));
          float ul = bf2f(xcb[(size_t)rowg*N + colg]);   // N == DI
          unsigned pv = ((unsigned)(unsigned short)f2bf(dl*ul) << 16)
                      |  (unsigned)(unsigned short)f2bf(dl);
          ((unsigned*)Cout)[cz + (size_t)(b_*Lsp + lsc)*N + colg] = pv;
        } else if (MODE == 5) {
          float vv = acc[mi][ni][j];
          ((float*)Cout)[(size_t)(rbase + j)*N + colg] = vv;
          ((short*)aux)[(size_t)(rbase + j)*N + colg] = f2bf(vv);
        } else {
          ((float*)Cout)[(size_t)(rbase + j)*N + colg] = acc[mi][ni][j];
        }
      }
    }
  }
}

// ---------- depthwise 3x3 conv + bias + silu -> xcB (bf16); 2 d's per thread ----------
__global__ __launch_bounds__(256) void dwconv_kernel(const short* __restrict__ xzB,
    const float* __restrict__ cw, const float* __restrict__ cb, short* __restrict__ xcB) {
  int bl = blockIdx.x;
  int b = bl >> 8, l = bl & 255;
  int h = l >> 4, w = l & 15;
  const short* xzb = xzB + (size_t)b*Lsp*(2*DI);
  #pragma unroll
  for (int it = 0; it < 4; ++it) {
    int d = (threadIdx.x + it*256)*2;
    float s0 = cb[d], s1 = cb[d+1];
    #pragma unroll
    for (int dh = -1; dh <= 1; ++dh) {
      int hh = h + dh; if (hh < 0 || hh > 15) continue;
      #pragma unroll
      for (int dw = -1; dw <= 1; ++dw) {
        int ww2 = w + dw; if (ww2 < 0 || ww2 > 15) continue;
        int t = (dh+1)*3 + (dw+1);
        short2 xv = *(const short2*)&xzb[(size_t)(hh*16 + ww2)*(2*DI) + d];
        s0 += bf2f(xv.x) * cw[d*9 + t];
        s1 += bf2f(xv.y) * cw[(d+1)*9 + t];
      }
    }
    float r0 = s0 / (1.f + __expf(-s0));
    float r1 = s1 / (1.f + __expf(-s1));
    short2 o; o.x = f2bf(r0); o.y = f2bf(r1);
    *(short2*)&xcB[((size_t)b*Lsp + l)*DI + d] = o;
  }
}

// ---------- pack B/C columns of P into scan order: PS[(k*4+b)][l][32] ----------
__global__ __launch_bounds__(256) void ps_build(const float* __restrict__ P,
    float* __restrict__ PS) {
  int slab = blockIdx.x;           // k*4 + b
  int k = slab >> 2, b = slab & 3;
  int l = threadIdx.x;
  int sp = dir_map(k, l);
  const float* src = P + (size_t)(b*Lsp + sp)*PW + k*96 + RR;   // 32 floats: B then C
  float* dst = PS + ((size_t)slab*Lsp + l)*32;
  #pragma unroll
  for (int n = 0; n < 32; n += 4)
    *(float4*)(dst + n) = *(const float4*)(src + n);
}

// ---------- scan pass 1: chunks 0..2 only (chunk 3's state is never consumed).
// chunk 0 emits y directly (Hstart==0) and skips Pa; chunks 1,2 write Pa+Hend. ----------
__global__ __launch_bounds__(256) void scan_pass1(const unsigned* __restrict__ pk,
    const float* __restrict__ PS, const float* __restrict__ A_logs,
    float* __restrict__ Pa, float* __restrict__ Hend, short* __restrict__ oyB) {
  int bk = blockIdx.x;             // b*4+k
  int b = bk >> 2, k = bk & 3;
  int slab = k*Bsz + b;
  int tid = threadIdx.x;
  int wv = tid >> 6, lane = tid & 63;
  int dloc = lane >> 2, ng = lane & 3;
  int d = blockIdx.y*64 + wv*16 + dloc;
  int c = blockIdx.z;              // 0..2
  int n0 = ng*4;
  float A[4], h[4] = {0.f,0.f,0.f,0.f};
  #pragma unroll
  for (int j = 0; j < 4; ++j)
    A[j] = -__expf(A_logs[((size_t)k*DI + d)*NST + n0 + j]);
  const unsigned* pkp = pk + (size_t)slab*Lsp*DI;
  const float* ps  = PS + (size_t)slab*Lsp*32;
  size_t base = ((size_t)(c*16 + bk)*DI + d)*NST + n0;
  if (c == 0) {
    // chunk 0: Hstart is exactly 0 -> this IS the final scan; emit y too.
    short* oy = oyB + (size_t)bk*Lsp*DI;
    #pragma unroll 2
    for (int l = 0; l < CHUNK; ++l) {
      unsigned v = pkp[(size_t)l*DI + d];
      float dl = unpack_lo(v);
      float du = unpack_hi(v);
      float4 Bv = *(const float4*)(ps + l*32 + n0);
      float4 Cv = *(const float4*)(ps + l*32 + 16 + n0);
      float y;
      float e0 = __expf(dl*A[0]); h[0] = h[0]*e0 + du*Bv.x; y  = h[0]*Cv.x;
      float e1 = __expf(dl*A[1]); h[1] = h[1]*e1 + du*Bv.y; y += h[1]*Cv.y;
      float e2 = __expf(dl*A[2]); h[2] = h[2]*e2 + du*Bv.z; y += h[2]*Cv.z;
      float e3 = __expf(dl*A[3]); h[3] = h[3]*e3 + du*Bv.w; y += h[3]*Cv.w;
      y += __shfl_xor(y, 1);
      y += __shfl_xor(y, 2);
      if (ng == 0) oy[(size_t)l*DI + d] = f2bf(y);
    }
    #pragma unroll
    for (int j = 0; j < 4; ++j) Hend[base + j] = h[j];
  } else {
    float sdl = 0.f;
    #pragma unroll 2
    for (int l = c*CHUNK; l < (c+1)*CHUNK; ++l) {
      unsigned v = pkp[(size_t)l*DI + d];
      float dl = unpack_lo(v);
      float du = unpack_hi(v);
      sdl += dl;
      float4 Bv = *(const float4*)(ps + l*32 + n0);
      float e0 = __expf(dl*A[0]); h[0] = h[0]*e0 + du*Bv.x;
      float e1 = __expf(dl*A[1]); h[1] = h[1]*e1 + du*Bv.y;
      float e2 = __expf(dl*A[2]); h[2] = h[2]*e2 + du*Bv.z;
      float e3 = __expf(dl*A[3]); h[3] = h[3]*e3 + du*Bv.w;
    }
    #pragma unroll
    for (int j = 0; j < 4; ++j) {
      Pa[base + j] = __expf(A[j]*sdl);   // product of decays == exp of summed dl
      Hend[base + j] = h[j];
    }
  }
}

// ---------- combine chunk boundaries: fold chunks 0..2 -> Hstart[1..3] ----------
__global__ __launch_bounds__(256) void scan_combine(const float* __restrict__ Pa,
    const float* __restrict__ Hend, float* __restrict__ Hstart) {
  int idx = blockIdx.x*256 + threadIdx.x;    // (bk*DI + d)*16 + n
  const int stride = 16*DI*NST;              // 524288
  float h = Hend[idx];                       // after chunk 0 (Pa[0] == anything, unused)
  Hstart[stride + idx] = h;
  h = Pa[stride + idx]*h + Hend[stride + idx];
  Hstart[2*stride + idx] = h;
  h = Pa[2*stride + idx]*h + Hend[2*stride + idx];
  Hstart[3*stride + idx] = h;
}

// ---------- scan pass 2: rescan chunks 1..3 with correct Hstart, emit y (bf16) ----------
__global__ __launch_bounds__(256) void scan_pass2(const unsigned* __restrict__ pk,
    const float* __restrict__ PS, const float* __restrict__ A_logs,
    const float* __restrict__ Hstart, short* __restrict__ oyB) {
  int bk = blockIdx.x;             // b*4+k
  int b = bk >> 2, k = bk & 3;
  int slab = k*Bsz + b;
  int tid = threadIdx.x;
  int wv = tid >> 6, lane = tid & 63;
  int dloc = lane >> 2, ng = lane & 3;
  int d = blockIdx.y*64 + wv*16 + dloc;
  int c = blockIdx.z + 1;          // chunks 1..3 (chunk 0 emitted by pass1)
  int n0 = ng*4;
  float A[4], h[4];
  #pragma unroll
  for (int j = 0; j < 4; ++j)
    A[j] = -__expf(A_logs[((size_t)k*DI + d)*NST + n0 + j]);
  size_t hbase = ((size_t)(c*16 + bk)*DI + d)*NST + n0;
  #pragma unroll
  for (int j = 0; j < 4; ++j) h[j] = Hstart[hbase + j];
  const unsigned* pkp = pk + (size_t)slab*Lsp*DI;
  const float* ps  = PS + (size_t)slab*Lsp*32;
  short* oy = oyB + (size_t)bk*Lsp*DI;
  #pragma unroll 2
  for (int l = c*CHUNK; l < (c+1)*CHUNK; ++l) {
    unsigned v = pkp[(size_t)l*DI + d];
    float dl = unpack_lo(v);
    float du = unpack_hi(v);
    float4 Bv = *(const float4*)(ps + l*32 + n0);
    float4 Cv = *(const float4*)(ps + l*32 + 16 + n0);
    float y;
    float e0 = __expf(dl*A[0]); h[0] = h[0]*e0 + du*Bv.x; y  = h[0]*Cv.x;
    float e1 = __expf(dl*A[1]); h[1] = h[1]*e1 + du*Bv.y; y += h[1]*Cv.y;
    float e2 = __expf(dl*A[2]); h[2] = h[2]*e2 + du*Bv.z; y += h[2]*Cv.z;
    float e3 = __expf(dl*A[3]); h[3] = h[3]*e3 + du*Bv.w; y += h[3]*Cv.w;
    y += __shfl_xor(y, 1);
    y += __shfl_xor(y, 2);
    if (ng == 0) oy[(size_t)l*DI + d] = f2bf(y);
  }
}

// ---------- combine 4 directions + D*u + LayerNorm + gate with silu(z) -> bf16 ----------
__global__ __launch_bounds__(256) void combine_ln_kernel(const short* __restrict__ oyB,
    const short* __restrict__ xzB, const short* __restrict__ xcB,
    const float* __restrict__ Ds, const float* __restrict__ lng,
    const float* __restrict__ lnb, short* __restrict__ ygB) {
  int bl = blockIdx.x;
  int b = bl >> 8, l = bl & 255;
  int h = l >> 4, w = l & 15;
  int lT = (w << 4) | h;
  const short* oy = oyB + (size_t)b*KK*Lsp*DI;
  float vals[8];
  float sum = 0.f, sumsq = 0.f;
  #pragma unroll
  for (int i = 0; i < 8; ++i) {
    int d = threadIdx.x + i*256;
    float dsum = Ds[d] + Ds[DI + d] + Ds[2*DI + d] + Ds[3*DI + d];
    float yv = bf2f(oy[(size_t)(0*Lsp + l       )*DI + d])
             + bf2f(oy[(size_t)(2*Lsp + (255-l ))*DI + d])
             + bf2f(oy[(size_t)(1*Lsp + lT      )*DI + d])
             + bf2f(oy[(size_t)(3*Lsp + (255-lT))*DI + d])
             + bf2f(xcB[(size_t)bl*DI + d]) * dsum;
    vals[i] = yv; sum += yv; sumsq += yv*yv;
  }
  __shared__ float r1[256], r2[256];
  r1[threadIdx.x] = sum; r2[threadIdx.x] = sumsq; __syncthreads();
  for (int off = 128; off > 0; off >>= 1) {
    if (threadIdx.x < off) { r1[threadIdx.x] += r1[threadIdx.x+off]; r2[threadIdx.x] += r2[threadIdx.x+off]; }
    __syncthreads();
  }
  float mu = r1[0] * (1.f/2048.f);
  float var = r2[0] * (1.f/2048.f) - mu*mu;
  float rstd = rsqrtf(var + 1e-5f);
  const short* zrow = xzB + (size_t)bl*(2*DI) + DI;
  #pragma unroll
  for (int i = 0; i < 8; ++i) {
    int d = threadIdx.x + i*256;
    float z = bf2f(zrow[d]);
    float sz = z / (1.f + __expf(-z));
    ygB[(size_t)bl*DI + d] = f2bf(((vals[i]-mu)*rstd*lng[d] + lnb[d]) * sz);
  }
}

// ---------- cbr epilogue: bias + BN + exact GELU, write NCHW ----------
__global__ void cbr_epilogue(const float* __restrict__ o2, const float* __restrict__ cb,
    const float* __restrict__ g, const float* __restrict__ beta, const float* __restrict__ m_,
    const float* __restrict__ v_, float* __restrict__ out) {
  int idx = blockIdx.x*256 + threadIdx.x;   // (b*128+dd)*256 + l
  int l = idx & 255;
  int rest = idx >> 8;
  int dd = rest & 127;
  int b = rest >> 7;
  float s = o2[((size_t)b*Lsp + l)*DIM + dd] + cb[dd];
  float inv = g[dd] * rsqrtf(v_[dd] + 1e-5f);
  s = s*inv + (beta[dd] - m_[dd]*inv);
  out[idx] = s * 0.5f * (1.f + erff(s * 0.70710678118f));
}

extern "C" void kernel_launch(void* const* d_in, const int* in_sizes, int n_in,
                              void* d_out, int out_size, void* d_ws, size_t ws_size,
                              hipStream_t stream) {
  const float* x        = (const float*)d_in[0];
  const float* pool_w   = (const float*)d_in[1];
  const float* pool_b   = (const float*)d_in[2];
  const float* bn_g     = (const float*)d_in[3];
  const float* bn_b     = (const float*)d_in[4];
  const float* bn_m     = (const float*)d_in[5];
  const float* bn_v     = (const float*)d_in[6];
  const float* in_proj_w= (const float*)d_in[7];
  const float* conv_w   = (const float*)d_in[8];
  const float* conv_b   = (const float*)d_in[9];
  const float* x_proj_w = (const float*)d_in[10];
  const float* dt_w     = (const float*)d_in[11];
  const float* dt_b     = (const float*)d_in[12];
  const float* A_logs   = (const float*)d_in[13];
  const float* Ds       = (const float*)d_in[14];
  const float* ln_g     = (const float*)d_in[15];
  const float* ln_b     = (const float*)d_in[16];
  const float* out_proj_w=(const float*)d_in[17];
  const float* cbr_w    = (const float*)d_in[18];
  const float* cbr_b    = (const float*)d_in[19];
  const float* cbr_g    = (const float*)d_in[20];
  const float* cbr_beta = (const float*)d_in[21];
  const float* cbr_m    = (const float*)d_in[22];
  const float* cbr_v    = (const float*)d_in[23];
  float* out = (float*)d_out;

  if (ws_size < (size_t)WS_FLOATS * sizeof(float)) return;
  float* ws = (float*)d_ws;
  float* pooled   = ws + OFF_POOLED;
  float* pconv    = ws + OFF_PCONV;
  float* y0m      = ws + OFF_Y0M;
  float* P        = ws + OFF_XDBL;
  unsigned* pk    = (unsigned*)(ws + OFF_DELTA);       // packed (du|dl) bf16, scan order
  float* o2       = ws + OFF_O2;

  // overlays (lifetimes audited):
  short* featB = (short*)(ws + OFF_POOLED);            // written xT/feat_fill AFTER pconv, read B
  float* PS    = ws + OFF_POOLED;                      // written after D (featB dead), read F
  short* xzB   = (short*)(ws + OFF_XZ);                // written B (bf16), read C & G
  short* wInB  = (short*)(ws + OFF_DELTA);             // read B; pk written E
  short* wXB   = (short*)(ws + OFF_DELTA + 2097152);   // read D; pk written E
  short* wOB   = (short*)(ws + OFF_FEAT);              // read H
  short* wCB   = (short*)(ws + OFF_PCONV);             // written cvt after feat_fill, read I
  short* xcB   = (short*)(ws + OFF_O1);                // written C, read D/E & G; o1B after
  short* oyB   = (short*)(ws + OFF_OUTY);              // written pass1(c0)/pass2, read G
  float* Pa    = ws + OFF_OUTY + 4194304;              // written pass1, read combine
  float* Hend  = ws + OFF_OUTY + 4194304 + 2097152;    // written pass1, read combine
  short* dtwB  = (short*)(ws + OFF_OUTY + 4194304);    // read E; Pa written pass1 (after E)
  short* PB    = (short*)(ws + OFF_OUTY + 4194304 + 262144); // written D (MODE5), read E
  float* Hstart= ws + OFF_YG;                          // written combine, read pass2
  short* ygB   = (short*)(ws + OFF_DELTA);             // written G (pk dead), read H
  short* o1B   = (short*)(ws + OFF_O1);                // written H, read I

  // stage A: pyramid pooling (xT AFTER pconv: featB overlays pooled)
  pool0_kernel<<<Bsz*DIM, 256, 0, stream>>>(x, pool_w, pool_b, bn_g, bn_b, bn_m, bn_v, y0m);
  pool_avg_kernel<<<Bsz*Cin, 288, 0, stream>>>(x, pooled);
  pconv_kernel<<<Bsz*275, 128, 0, stream>>>(pooled, pool_w, pool_b, bn_g, bn_b, bn_m, bn_v, pconv);
  xT_kernel<<<dim3(16, 8, Bsz), 256, 0, stream>>>(x, featB);
  feat_fill<<<Bsz*Lsp, 256, 0, stream>>>(y0m, pconv, featB);

  // weight conversions: one fused launch (enqueued after feat_fill -> pconv dead)
  f2bf5_kernel<<<3776, 256, 0, stream>>>(in_proj_w, wInB, x_proj_w, wXB,
      out_proj_w, wOB, cbr_w, wCB, dt_w, dtwB);

  // stage B: in_proj GEMM (M=1024, N=4096, K=1024), bf16 out
  gemm_bf<1><<<dim3(32, 8, 1), 256, 0, stream>>>(featB, wInB, xzB, nullptr,
      1024, 4096, 1024, 1024, 1024, 0, 0, 0, 0, nullptr, nullptr);

  // stage C: depthwise conv + silu -> bf16
  dwconv_kernel<<<Bsz*Lsp, 256, 0, stream>>>(xzB, conv_w, conv_b, xcB);

  // stage D: x_proj GEMM -> P (f32) + PB (bf16) in one epilogue; then PS pack
  gemm_bf<5><<<dim3(3, 8, 1), 256, 0, stream>>>(xcB, wXB, P, nullptr,
      1024, PW, 2048, 2048, 2048, 0, 0, 0, 0, nullptr, PB);
  ps_build<<<16, 256, 0, stream>>>(P, PS);

  // stage E: delta as ONE z-batched GEMM (z=k): (M=1024, N=2048, K=64),
  // native-softplus epilogue packs (du|dl) bf16 into pk at scan-order rows
  gemm_bf<4><<<dim3(16, 8, KK), 256, 0, stream>>>(PB, dtwB, pk, dt_b,
      1024, DI, 64, PW, RR, 96, DI*RR, (unsigned)(Bsz*Lsp*DI), DI, xcB, nullptr);

  // stage F: chunked two-pass selective scan; pass1 runs chunks 0-2 (chunk-3 state unused),
  // chunk-0 emits y directly
  scan_pass1<<<dim3(Bsz*KK, DI/64, NCH-1), 256, 0, stream>>>(pk, PS, A_logs, Pa, Hend, oyB);
  scan_combine<<<(16*DI*NST)/256, 256, 0, stream>>>(Pa, Hend, Hstart);
  scan_pass2<<<dim3(Bsz*KK, DI/64, NCH-1), 256, 0, stream>>>(pk, PS, A_logs, Hstart, oyB);

  // stage G: combine + D*u + LN + gate -> bf16 (pk dead; ygB overlays it)
  combine_ln_kernel<<<Bsz*Lsp, 256, 0, stream>>>(oyB, xzB, xcB, Ds, ln_g, ln_b, ygB);

  // stage H: out_proj GEMM (M=1024, N=1024, K=2048), bf16 out
  gemm_bf<1><<<dim3(8, 8, 1), 256, 0, stream>>>(ygB, wOB, o1B, nullptr,
      1024, 1024, 2048, 2048, 2048, 0, 0, 0, 0, nullptr, nullptr);

  // stage I: cbr GEMM (M=1024, N=128, K=1024), f32 out + epilogue
  gemm_bf<0><<<dim3(1, 8, 1), 256, 0, stream>>>(o1B, wCB, o2, nullptr,
      1024, DIM, 1024, 1024, 1024, 0, 0, 0, 0, nullptr, nullptr);
  cbr_epilogue<<<(Bsz*DIM*Lsp)/256, 256, 0, stream>>>(o2, cbr_b, cbr_g, cbr_beta, cbr_m, cbr_v, out);
}

// Round 13
// 317.273 us; speedup vs baseline: 1.5299x; 1.0058x over previous
//
#include <hip/hip_runtime.h>
#include <hip/hip_bf16.h>
#include <math.h>

// ---------- constants ----------
#define Bsz 4
#define Cin 512
#define Hh 16
#define Ww 16
#define Lsp 256
#define DIM 128
#define DM 1024      // dim*4 + 512
#define DI 2048
#define KK 4
#define NST 16
#define RR 64
#define PW 384       // K*96 projection rows
#define NCH 4
#define CHUNK 64     // Lsp / NCH

// ---------- ws layout (floats) — round-4 proven layout ----------
#define OFF_FEAT    0u
#define SZ_FEAT     (Bsz*Lsp*DM)                 // 1048576
#define OFF_POOLED  (OFF_FEAT + SZ_FEAT)
#define SZ_POOLED   (Bsz*Cin*275)                // 563200
#define OFF_PCONV   (OFF_POOLED + SZ_POOLED)
#define SZ_PCONV    (Bsz*275*DIM)                // 140800
#define OFF_Y0M     (OFF_PCONV + SZ_PCONV)
#define SZ_Y0M      (Bsz*DIM)                    // 512
#define OFF_XZ      (OFF_Y0M + SZ_Y0M)
#define SZ_XZ       (Bsz*Lsp*2*DI)               // 4194304
#define OFF_XCT     (OFF_XZ + SZ_XZ)
#define SZ_XCT      (Bsz*Lsp*DI)                 // 2097152
#define OFF_XDBL    (OFF_XCT + SZ_XCT)
#define SZ_XDBL     (Bsz*Lsp*PW)                 // 393216  (P matrix f32)
#define OFF_DELTA   (OFF_XDBL + SZ_XDBL)
#define SZ_DELTA    (Bsz*KK*Lsp*DI)              // 8388608 (pk u32: du|dl packed bf16)
#define OFF_OUTY    (OFF_DELTA + SZ_DELTA)
#define SZ_OUTY     (Bsz*KK*Lsp*DI)              // 8388608 (oyB bf16 + dtwB/PB region)
#define OFF_YG      (OFF_OUTY + SZ_OUTY)
#define SZ_YG       (Bsz*Lsp*DI)                 // 2097152 (unused now)
#define OFF_O1      (OFF_YG + SZ_YG)
#define SZ_O1       (Bsz*Lsp*DM)                 // 1048576 (xcB then o1B)
#define OFF_O2      (OFF_O1 + SZ_O1)
#define SZ_O2       (Bsz*Lsp*DIM)                // 131072
#define WS_FLOATS   (OFF_O2 + SZ_O2)

typedef __attribute__((ext_vector_type(8))) short short8;
typedef __attribute__((ext_vector_type(4))) float f32x4;

__device__ __forceinline__ short f2bf(float x) {
  __hip_bfloat16 h = __float2bfloat16(x);
  short s;
  __builtin_memcpy(&s, &h, 2);
  return s;
}
__device__ __forceinline__ float bf2f(short s) {
  unsigned u = ((unsigned)(unsigned short)s) << 16;
  float f;
  __builtin_memcpy(&f, &u, 4);
  return f;
}
// unpack packed (du|dl): dl = low16<<16, du = high16 in place
__device__ __forceinline__ float unpack_lo(unsigned v) {
  unsigned u = v << 16; float f; __builtin_memcpy(&f, &u, 4); return f;
}
__device__ __forceinline__ float unpack_hi(unsigned v) {
  unsigned u = v & 0xffff0000u; float f; __builtin_memcpy(&f, &u, 4); return f;
}

// ---------- fused f32 -> bf16 convert of the 5 weight tensors ----------
__global__ __launch_bounds__(256) void f2bf5_kernel(
    const float* __restrict__ s0, short* __restrict__ d0,    // 4194304
    const float* __restrict__ s1, short* __restrict__ d1,    // 786432
    const float* __restrict__ s2, short* __restrict__ d2,    // 2097152
    const float* __restrict__ s3, short* __restrict__ d3,    // 131072
    const float* __restrict__ s4, short* __restrict__ d4) {  // 524288
  int blk = blockIdx.x;
  const float* src; short* dst; int base;
  if (blk < 2048)      { src = s0; dst = d0; base = blk; }
  else if (blk < 2432) { src = s1; dst = d1; base = blk - 2048; }
  else if (blk < 3456) { src = s2; dst = d2; base = blk - 2432; }
  else if (blk < 3520) { src = s3; dst = d3; base = blk - 3456; }
  else                 { src = s4; dst = d4; base = blk - 3520; }
  int i = (base*256 + threadIdx.x)*8;
  float4 a = *(const float4*)(src + i);
  float4 b = *(const float4*)(src + i + 4);
  short8 o;
  o[0]=f2bf(a.x); o[1]=f2bf(a.y); o[2]=f2bf(a.z); o[3]=f2bf(a.w);
  o[4]=f2bf(b.x); o[5]=f2bf(b.y); o[6]=f2bf(b.z); o[7]=f2bf(b.w);
  *(short8*)(dst + i) = o;
}

// ---------- pool layer 0: conv1x1+BN+ReLU then global mean (ILP version) ----------
__global__ __launch_bounds__(256) void pool0_kernel(
    const float* __restrict__ x, const float* __restrict__ pw, const float* __restrict__ pb,
    const float* __restrict__ g, const float* __restrict__ bb,
    const float* __restrict__ m, const float* __restrict__ v, float* __restrict__ y0m) {
  int bd = blockIdx.x;             // b*128+d
  int b = bd >> 7, d = bd & 127;
  int l = threadIdx.x;
  const float* xb = x + (b*Cin)*Lsp + l;
  const float* w = pw + d*Cin;
  float a0 = 0.f, a1 = 0.f, a2 = 0.f, a3 = 0.f;
  #pragma unroll 4
  for (int c = 0; c < Cin; c += 4) {
    float4 wv = *(const float4*)(w + c);
    a0 += xb[(c+0)*Lsp] * wv.x;
    a1 += xb[(c+1)*Lsp] * wv.y;
    a2 += xb[(c+2)*Lsp] * wv.z;
    a3 += xb[(c+3)*Lsp] * wv.w;
  }
  float s = (a0 + a1) + (a2 + a3) + pb[d];
  float inv = g[d] * rsqrtf(v[d] + 1e-5f);
  s = s*inv + (bb[d] - m[d]*inv);
  s = fmaxf(s, 0.f);
  __shared__ float red[256];
  red[l] = s; __syncthreads();
  for (int off = 128; off > 0; off >>= 1) {
    if (l < off) red[l] += red[l+off];
    __syncthreads();
  }
  if (l == 0) y0m[bd] = red[0] * (1.f/256.f);
}

// ---------- adaptive avg pool of x to 5x5,9x9,13x13 (concatenated 275 positions) ----------
__device__ __forceinline__ void decode_pos(int pos, int& s, int& pp, int& qq, int& layer) {
  if (pos < 25)       { s = 5;  layer = 1; int t = pos;       pp = t/5;  qq = t%5;  }
  else if (pos < 106) { s = 9;  layer = 2; int t = pos - 25;  pp = t/9;  qq = t%9;  }
  else                { s = 13; layer = 3; int t = pos - 106; pp = t/13; qq = t%13; }
}

__global__ void pool_avg_kernel(const float* __restrict__ x, float* __restrict__ pooled) {
  int bc = blockIdx.x;             // b*512+c
  int pos = threadIdx.x;
  if (pos >= 275) return;
  int s, pp, qq, layer;
  decode_pos(pos, s, pp, qq, layer);
  int hs = (pp*Hh)/s, he = ((pp+1)*Hh + s-1)/s;
  int ws = (qq*Ww)/s, we = ((qq+1)*Ww + s-1)/s;
  const float* xb = x + (size_t)bc*Lsp;
  float acc = 0.f;
  for (int hh = hs; hh < he; ++hh)
    for (int ww2 = ws; ww2 < we; ++ww2)
      acc += xb[hh*Ww + ww2];
  pooled[(size_t)bc*275 + pos] = acc / (float)((he-hs)*(we-ws));
}

// ---------- conv1x1 + BN + ReLU on pooled features (ILP version) ----------
__global__ void pconv_kernel(const float* __restrict__ pooled, const float* __restrict__ pw,
    const float* __restrict__ pb, const float* __restrict__ g, const float* __restrict__ bb,
    const float* __restrict__ m, const float* __restrict__ v, float* __restrict__ pconv) {
  int bp = blockIdx.x;             // b*275+pos
  int b = bp / 275, pos = bp % 275;
  int d = threadIdx.x;             // 0..127
  int s, pp, qq, layer;
  decode_pos(pos, s, pp, qq, layer);
  const float* pc = pooled + b*Cin*275 + pos;
  const float* w = pw + (layer*DIM + d)*Cin;
  float a0 = 0.f, a1 = 0.f, a2 = 0.f, a3 = 0.f;
  #pragma unroll 4
  for (int c = 0; c < Cin; c += 4) {
    float4 wv = *(const float4*)(w + c);
    a0 += pc[(c+0)*275] * wv.x;
    a1 += pc[(c+1)*275] * wv.y;
    a2 += pc[(c+2)*275] * wv.z;
    a3 += pc[(c+3)*275] * wv.w;
  }
  float acc = (a0 + a1) + (a2 + a3) + pb[layer*DIM + d];
  int ld = layer*DIM + d;
  float inv = g[ld] * rsqrtf(v[ld] + 1e-5f);
  acc = acc*inv + (bb[ld] - m[ld]*inv);
  pconv[bp*DIM + d] = fmaxf(acc, 0.f);
}

// ---------- transpose x (b,c,l) f32 -> featB cols 0..511 bf16 (coalesced reads) ----------
// NOTE: featB overlays pooled — must launch AFTER pconv_kernel.
__global__ __launch_bounds__(256) void xT_kernel(const float* __restrict__ x,
    short* __restrict__ featB) {
  int b = blockIdx.z;
  int c0 = blockIdx.x*32, l0 = blockIdx.y*32;
  __shared__ float t[32][33];
  int tx = threadIdx.x & 31, ty = threadIdx.x >> 5;   // 32 x 8
  #pragma unroll
  for (int i = 0; i < 4; ++i) {
    int c = c0 + ty + i*8;
    t[ty + i*8][tx] = x[((size_t)b*Cin + c)*Lsp + l0 + tx];
  }
  __syncthreads();
  #pragma unroll
  for (int i = 0; i < 4; ++i) {
    int l = l0 + ty + i*8;
    featB[(size_t)(b*Lsp + l)*DM + c0 + tx] = f2bf(t[tx][ty + i*8]);
  }
}

// ---------- fill feat cols 512..1023 (y0 broadcast + bilinear upsample) ----------
__global__ __launch_bounds__(256) void feat_fill(const float* __restrict__ y0m,
    const float* __restrict__ pconv, short* __restrict__ featB) {
  int bl = blockIdx.x;             // b*256+l
  int b = bl >> 8, l = bl & 255;
  int h = l >> 4, w = l & 15;
  for (int cc = threadIdx.x; cc < 512; cc += 256) {
    float val;
    if (cc < 128) {
      val = y0m[b*DIM + cc];
    } else {
      int i = (cc - 128) >> 7;               // 0,1,2 -> s=5,9,13
      int d = (cc - 128) & 127;
      int s = (i==0) ? 5 : (i==1) ? 9 : 13;
      int off = (i==0) ? 0 : (i==1) ? 25 : 106;
      float scale = (float)s / 16.f;
      float sh = fmaxf((h + 0.5f)*scale - 0.5f, 0.f);
      int h0 = min((int)sh, s-1); float wh = sh - (float)h0; int h1 = min(h0+1, s-1);
      float sw = fmaxf((w + 0.5f)*scale - 0.5f, 0.f);
      int w0 = min((int)sw, s-1); float ww2 = sw - (float)w0; int w1 = min(w0+1, s-1);
      const float* pc = pconv + b*275*DIM;
      float v00 = pc[(off + h0*s + w0)*DIM + d];
      float v01 = pc[(off + h0*s + w1)*DIM + d];
      float v10 = pc[(off + h1*s + w0)*DIM + d];
      float v11 = pc[(off + h1*s + w1)*DIM + d];
      val = (1.f-wh)*((1.f-ww2)*v00 + ww2*v01) + wh*((1.f-ww2)*v10 + ww2*v11);
    }
    featB[(size_t)bl*DM + 512 + cc] = f2bf(val);
  }
}

// scan-direction spatial index map (l -> sp)
__device__ __forceinline__ int dir_map(int k, int l) {
  if (k == 0) return l;
  if (k == 1) return ((l & 15) << 4) | (l >> 4);
  if (k == 2) return 255 - l;
  int m = 255 - l; return ((m & 15) << 4) | (m >> 4);
}
// inverse map (sp -> scan l) per direction
__device__ __forceinline__ int inv_map(int k, int sp) {
  int t = ((sp & 15) << 4) | (sp >> 4);
  if (k == 0) return sp;
  if (k == 1) return t;
  if (k == 2) return 255 - sp;
  return 255 - t;
}

// ---------- bf16 MFMA GEMM: C[M][N] = A[M][K] * B[N][K]^T ----------
// MODE 0: f32 store.  MODE 1: bf16 store.
// MODE 4: delta (z-batched over k): dl=softplus(acc+bias); pack (du|dl) bf16 into u32
//         at scan-order row.  MODE 5: f32 store + bf16 copy (aux).
__device__ __forceinline__ void gload_lds16(const short* g, short* l) {
  __builtin_amdgcn_global_load_lds((const __attribute__((address_space(1))) void*)g,
                                   (__attribute__((address_space(3))) void*)l, 16, 0, 0);
}

template<int MODE>
__global__ __launch_bounds__(256) void gemm_bf(const short* __restrict__ Ag,
    const short* __restrict__ Bg, void* __restrict__ Cout, const float* __restrict__ bias,
    int M, int N, int K, int lda, int ldb,
    int azs, int bzs, unsigned czs, int ezs,
    const short* __restrict__ xcb, void* __restrict__ aux) {
  __shared__ short Als[128*64];
  __shared__ short Bls[128*64];
  int kdir = blockIdx.z;
  Ag += (size_t)kdir * azs;
  Bg += (size_t)kdir * bzs;
  size_t cz = (size_t)kdir * czs;
  if (bias) bias += (size_t)kdir * ezs;
  int tid = threadIdx.x;
  int w = tid >> 6, lane = tid & 63;
  int wm = w >> 1, wn = w & 1;
  int row0 = blockIdx.y * 128, col0 = blockIdx.x * 128;
  f32x4 acc[4][4];
  #pragma unroll
  for (int i = 0; i < 4; ++i)
    #pragma unroll
    for (int j = 0; j < 4; ++j)
      acc[i][j] = (f32x4){0.f, 0.f, 0.f, 0.f};

  for (int k0 = 0; k0 < K; k0 += 64) {
    #pragma unroll
    for (int i = 0; i < 4; ++i) {
      int slot = i*256 + w*64 + lane;
      int r = slot >> 3, pc = slot & 7;
      int c = pc ^ (r & 7);
      gload_lds16(Ag + (size_t)(row0 + r)*lda + k0 + c*8, &Als[(i*256 + w*64)*8]);
      gload_lds16(Bg + (size_t)(col0 + r)*ldb + k0 + c*8, &Bls[(i*256 + w*64)*8]);
    }
    __syncthreads();
    #pragma unroll
    for (int ks = 0; ks < 2; ++ks) {
      short8 af[4], bfr[4];
      int rsel = lane & 15, csel = ks*4 + (lane >> 4);
      #pragma unroll
      for (int mi = 0; mi < 4; ++mi) {
        int row = wm*64 + mi*16 + rsel;
        af[mi] = *(const short8*)&Als[row*64 + ((csel ^ (row & 7)) << 3)];
      }
      #pragma unroll
      for (int ni = 0; ni < 4; ++ni) {
        int row = wn*64 + ni*16 + rsel;
        bfr[ni] = *(const short8*)&Bls[row*64 + ((csel ^ (row & 7)) << 3)];
      }
      #pragma unroll
      for (int mi = 0; mi < 4; ++mi)
        #pragma unroll
        for (int ni = 0; ni < 4; ++ni)
          acc[mi][ni] = __builtin_amdgcn_mfma_f32_16x16x32_bf16(af[mi], bfr[ni], acc[mi][ni], 0, 0, 0);
    }
    __syncthreads();
  }
  // epilogue: D row = (lane>>4)*4 + j, col = lane&15
  #pragma unroll
  for (int mi = 0; mi < 4; ++mi) {
    int rbase = row0 + wm*64 + mi*16 + ((lane >> 4) << 2);
    #pragma unroll
    for (int ni = 0; ni < 4; ++ni) {
      int colg = col0 + wn*64 + ni*16 + (lane & 15);
      #pragma unroll
      for (int j = 0; j < 4; ++j) {
        if (MODE == 1) {
          ((short*)Cout)[(size_t)(rbase + j)*N + colg] = f2bf(acc[mi][ni][j]);
        } else if (MODE == 4) {
          int rowg = rbase + j;                 // b*256 + sp
          int b_ = rowg >> 8, sp_ = rowg & 255;
          int lsc = inv_map(kdir, sp_);
          float dl = acc[mi][ni][j] + bias[colg];
          // native softplus: v_exp + v_log (bf16-rounded downstream)
          dl = (dl > 20.f) ? dl : __logf(1.f + __expf(dl));
          float ul = bf2f(xcb[(size_t)rowg*N + colg]);   // N == DI
          unsigned pv = ((unsigned)(unsigned short)f2bf(dl*ul) << 16)
                      |  (unsigned)(unsigned short)f2bf(dl);
          ((unsigned*)Cout)[cz + (size_t)(b_*Lsp + lsc)*N + colg] = pv;
        } else if (MODE == 5) {
          float vv = acc[mi][ni][j];
          ((float*)Cout)[(size_t)(rbase + j)*N + colg] = vv;
          ((short*)aux)[(size_t)(rbase + j)*N + colg] = f2bf(vv);
        } else {
          ((float*)Cout)[(size_t)(rbase + j)*N + colg] = acc[mi][ni][j];
        }
      }
    }
  }
}

// ---------- depthwise 3x3 conv + bias + silu -> xcB (bf16); 2 d's per thread ----------
__global__ __launch_bounds__(256) void dwconv_kernel(const short* __restrict__ xzB,
    const float* __restrict__ cw, const float* __restrict__ cb, short* __restrict__ xcB) {
  int bl = blockIdx.x;
  int b = bl >> 8, l = bl & 255;
  int h = l >> 4, w = l & 15;
  const short* xzb = xzB + (size_t)b*Lsp*(2*DI);
  #pragma unroll
  for (int it = 0; it < 4; ++it) {
    int d = (threadIdx.x + it*256)*2;
    float s0 = cb[d], s1 = cb[d+1];
    #pragma unroll
    for (int dh = -1; dh <= 1; ++dh) {
      int hh = h + dh; if (hh < 0 || hh > 15) continue;
      #pragma unroll
      for (int dw = -1; dw <= 1; ++dw) {
        int ww2 = w + dw; if (ww2 < 0 || ww2 > 15) continue;
        int t = (dh+1)*3 + (dw+1);
        short2 xv = *(const short2*)&xzb[(size_t)(hh*16 + ww2)*(2*DI) + d];
        s0 += bf2f(xv.x) * cw[d*9 + t];
        s1 += bf2f(xv.y) * cw[(d+1)*9 + t];
      }
    }
    float r0 = s0 / (1.f + __expf(-s0));
    float r1 = s1 / (1.f + __expf(-s1));
    short2 o; o.x = f2bf(r0); o.y = f2bf(r1);
    *(short2*)&xcB[((size_t)b*Lsp + l)*DI + d] = o;
  }
}

// ---------- pack B/C columns of P into scan order: PS[(k*4+b)][l][32] ----------
__global__ __launch_bounds__(256) void ps_build(const float* __restrict__ P,
    float* __restrict__ PS) {
  int slab = blockIdx.x;           // k*4 + b
  int k = slab >> 2, b = slab & 3;
  int l = threadIdx.x;
  int sp = dir_map(k, l);
  const float* src = P + (size_t)(b*Lsp + sp)*PW + k*96 + RR;   // 32 floats: B then C
  float* dst = PS + ((size_t)slab*Lsp + l)*32;
  #pragma unroll
  for (int n = 0; n < 32; n += 4)
    *(float4*)(dst + n) = *(const float4*)(src + n);
}

// ---------- fused chunked scan: phase1 (local scans + chunk0 y) -> LDS -> phase2 ----------
// grid (Bsz*KK, DI/16); block 256 = 4 waves; wave c owns chunk c of a 16-d slice.
__global__ __launch_bounds__(256) void scan_fused(const unsigned* __restrict__ pk,
    const float* __restrict__ PS, const float* __restrict__ A_logs,
    short* __restrict__ oyB) {
  int bk = blockIdx.x;             // b*4+k
  int b = bk >> 2, k = bk & 3;
  int slab = k*Bsz + b;
  int tid = threadIdx.x;
  int wv = tid >> 6, lane = tid & 63;   // wave == chunk
  int dloc = lane >> 2, ng = lane & 3;
  int d = blockIdx.y*16 + dloc;
  int n0 = ng*4;
  __shared__ float sHend[3][16][16];    // chunks 0..2: [dloc][n]
  __shared__ float sPa[2][16][16];      // chunks 1..2
  float A[4];
  #pragma unroll
  for (int j = 0; j < 4; ++j)
    A[j] = -__expf(A_logs[((size_t)k*DI + d)*NST + n0 + j]);
  const unsigned* pkp = pk + (size_t)slab*Lsp*DI;
  const float* ps  = PS + (size_t)slab*Lsp*32;
  short* oy = oyB + (size_t)bk*Lsp*DI;
  float h[4] = {0.f,0.f,0.f,0.f};

  if (wv == 0) {
    // chunk 0: Hstart == 0 -> final scan; emit y. Save Hend to LDS.
    #pragma unroll 2
    for (int l = 0; l < CHUNK; ++l) {
      unsigned v = pkp[(size_t)l*DI + d];
      float dl = unpack_lo(v);
      float du = unpack_hi(v);
      float4 Bv = *(const float4*)(ps + l*32 + n0);
      float4 Cv = *(const float4*)(ps + l*32 + 16 + n0);
      float y;
      float e0 = __expf(dl*A[0]); h[0] = h[0]*e0 + du*Bv.x; y  = h[0]*Cv.x;
      float e1 = __expf(dl*A[1]); h[1] = h[1]*e1 + du*Bv.y; y += h[1]*Cv.y;
      float e2 = __expf(dl*A[2]); h[2] = h[2]*e2 + du*Bv.z; y += h[2]*Cv.z;
      float e3 = __expf(dl*A[3]); h[3] = h[3]*e3 + du*Bv.w; y += h[3]*Cv.w;
      y += __shfl_xor(y, 1);
      y += __shfl_xor(y, 2);
      if (ng == 0) oy[(size_t)l*DI + d] = f2bf(y);
    }
    #pragma unroll
    for (int j = 0; j < 4; ++j) sHend[0][dloc][n0+j] = h[j];
  } else if (wv <= 2) {
    // chunks 1,2: local scan (no y); save Pa (exp of summed dl) + Hend.
    int c = wv;
    float sdl = 0.f;
    #pragma unroll 2
    for (int l = c*CHUNK; l < (c+1)*CHUNK; ++l) {
      unsigned v = pkp[(size_t)l*DI + d];
      float dl = unpack_lo(v);
      float du = unpack_hi(v);
      sdl += dl;
      float4 Bv = *(const float4*)(ps + l*32 + n0);
      float e0 = __expf(dl*A[0]); h[0] = h[0]*e0 + du*Bv.x;
      float e1 = __expf(dl*A[1]); h[1] = h[1]*e1 + du*Bv.y;
      float e2 = __expf(dl*A[2]); h[2] = h[2]*e2 + du*Bv.z;
      float e3 = __expf(dl*A[3]); h[3] = h[3]*e3 + du*Bv.w;
    }
    #pragma unroll
    for (int j = 0; j < 4; ++j) {
      sHend[c][dloc][n0+j] = h[j];
      sPa[c-1][dloc][n0+j] = __expf(A[j]*sdl);
    }
  } else {
    // wave 3: its local state is never consumed — prefetch chunk 3 data to L2.
    unsigned ua = 0u; float fa = 0.f;
    for (int l = 3*CHUNK; l < 4*CHUNK; l += 2) {
      ua += pkp[(size_t)l*DI + d];
      fa += ps[l*32 + (lane & 31)];
    }
    asm volatile("" :: "v"(ua), "v"(fa));
  }
  __syncthreads();
  if (wv >= 1) {
    int c = wv;
    // Hstart fold from LDS (bit-identical to old scan_combine)
    #pragma unroll
    for (int j = 0; j < 4; ++j) {
      float hh = sHend[0][dloc][n0+j];
      if (c >= 2) hh = sPa[0][dloc][n0+j]*hh + sHend[1][dloc][n0+j];
      if (c == 3) hh = sPa[1][dloc][n0+j]*hh + sHend[2][dloc][n0+j];
      h[j] = hh;
    }
    #pragma unroll 2
    for (int l = c*CHUNK; l < (c+1)*CHUNK; ++l) {
      unsigned v = pkp[(size_t)l*DI + d];
      float dl = unpack_lo(v);
      float du = unpack_hi(v);
      float4 Bv = *(const float4*)(ps + l*32 + n0);
      float4 Cv = *(const float4*)(ps + l*32 + 16 + n0);
      float y;
      float e0 = __expf(dl*A[0]); h[0] = h[0]*e0 + du*Bv.x; y  = h[0]*Cv.x;
      float e1 = __expf(dl*A[1]); h[1] = h[1]*e1 + du*Bv.y; y += h[1]*Cv.y;
      float e2 = __expf(dl*A[2]); h[2] = h[2]*e2 + du*Bv.z; y += h[2]*Cv.z;
      float e3 = __expf(dl*A[3]); h[3] = h[3]*e3 + du*Bv.w; y += h[3]*Cv.w;
      y += __shfl_xor(y, 1);
      y += __shfl_xor(y, 2);
      if (ng == 0) oy[(size_t)l*DI + d] = f2bf(y);
    }
  }
}

// ---------- combine 4 directions + D*u + LayerNorm + gate with silu(z) -> bf16 ----------
__global__ __launch_bounds__(256) void combine_ln_kernel(const short* __restrict__ oyB,
    const short* __restrict__ xzB, const short* __restrict__ xcB,
    const float* __restrict__ Ds, const float* __restrict__ lng,
    const float* __restrict__ lnb, short* __restrict__ ygB) {
  int bl = blockIdx.x;
  int b = bl >> 8, l = bl & 255;
  int h = l >> 4, w = l & 15;
  int lT = (w << 4) | h;
  const short* oy = oyB + (size_t)b*KK*Lsp*DI;
  float vals[8];
  float sum = 0.f, sumsq = 0.f;
  #pragma unroll
  for (int i = 0; i < 8; ++i) {
    int d = threadIdx.x + i*256;
    float dsum = Ds[d] + Ds[DI + d] + Ds[2*DI + d] + Ds[3*DI + d];
    float yv = bf2f(oy[(size_t)(0*Lsp + l       )*DI + d])
             + bf2f(oy[(size_t)(2*Lsp + (255-l ))*DI + d])
             + bf2f(oy[(size_t)(1*Lsp + lT      )*DI + d])
             + bf2f(oy[(size_t)(3*Lsp + (255-lT))*DI + d])
             + bf2f(xcB[(size_t)bl*DI + d]) * dsum;
    vals[i] = yv; sum += yv; sumsq += yv*yv;
  }
  __shared__ float r1[256], r2[256];
  r1[threadIdx.x] = sum; r2[threadIdx.x] = sumsq; __syncthreads();
  for (int off = 128; off > 0; off >>= 1) {
    if (threadIdx.x < off) { r1[threadIdx.x] += r1[threadIdx.x+off]; r2[threadIdx.x] += r2[threadIdx.x+off]; }
    __syncthreads();
  }
  float mu = r1[0] * (1.f/2048.f);
  float var = r2[0] * (1.f/2048.f) - mu*mu;
  float rstd = rsqrtf(var + 1e-5f);
  const short* zrow = xzB + (size_t)bl*(2*DI) + DI;
  #pragma unroll
  for (int i = 0; i < 8; ++i) {
    int d = threadIdx.x + i*256;
    float z = bf2f(zrow[d]);
    float sz = z / (1.f + __expf(-z));
    ygB[(size_t)bl*DI + d] = f2bf(((vals[i]-mu)*rstd*lng[d] + lnb[d]) * sz);
  }
}

// ---------- cbr epilogue: bias + BN + exact GELU, write NCHW ----------
__global__ void cbr_epilogue(const float* __restrict__ o2, const float* __restrict__ cb,
    const float* __restrict__ g, const float* __restrict__ beta, const float* __restrict__ m_,
    const float* __restrict__ v_, float* __restrict__ out) {
  int idx = blockIdx.x*256 + threadIdx.x;   // (b*128+dd)*256 + l
  int l = idx & 255;
  int rest = idx >> 8;
  int dd = rest & 127;
  int b = rest >> 7;
  float s = o2[((size_t)b*Lsp + l)*DIM + dd] + cb[dd];
  float inv = g[dd] * rsqrtf(v_[dd] + 1e-5f);
  s = s*inv + (beta[dd] - m_[dd]*inv);
  out[idx] = s * 0.5f * (1.f + erff(s * 0.70710678118f));
}

extern "C" void kernel_launch(void* const* d_in, const int* in_sizes, int n_in,
                              void* d_out, int out_size, void* d_ws, size_t ws_size,
                              hipStream_t stream) {
  const float* x        = (const float*)d_in[0];
  const float* pool_w   = (const float*)d_in[1];
  const float* pool_b   = (const float*)d_in[2];
  const float* bn_g     = (const float*)d_in[3];
  const float* bn_b     = (const float*)d_in[4];
  const float* bn_m     = (const float*)d_in[5];
  const float* bn_v     = (const float*)d_in[6];
  const float* in_proj_w= (const float*)d_in[7];
  const float* conv_w   = (const float*)d_in[8];
  const float* conv_b   = (const float*)d_in[9];
  const float* x_proj_w = (const float*)d_in[10];
  const float* dt_w     = (const float*)d_in[11];
  const float* dt_b     = (const float*)d_in[12];
  const float* A_logs   = (const float*)d_in[13];
  const float* Ds       = (const float*)d_in[14];
  const float* ln_g     = (const float*)d_in[15];
  const float* ln_b     = (const float*)d_in[16];
  const float* out_proj_w=(const float*)d_in[17];
  const float* cbr_w    = (const float*)d_in[18];
  const float* cbr_b    = (const float*)d_in[19];
  const float* cbr_g    = (const float*)d_in[20];
  const float* cbr_beta = (const float*)d_in[21];
  const float* cbr_m    = (const float*)d_in[22];
  const float* cbr_v    = (const float*)d_in[23];
  float* out = (float*)d_out;

  if (ws_size < (size_t)WS_FLOATS * sizeof(float)) return;
  float* ws = (float*)d_ws;
  float* pooled   = ws + OFF_POOLED;
  float* pconv    = ws + OFF_PCONV;
  float* y0m      = ws + OFF_Y0M;
  float* P        = ws + OFF_XDBL;
  unsigned* pk    = (unsigned*)(ws + OFF_DELTA);       // packed (du|dl) bf16, scan order
  float* o2       = ws + OFF_O2;

  // overlays (lifetimes audited):
  short* featB = (short*)(ws + OFF_POOLED);            // written xT/feat_fill AFTER pconv, read B
  float* PS    = ws + OFF_POOLED;                      // written after D (featB dead), read F
  short* xzB   = (short*)(ws + OFF_XZ);                // written B (bf16), read C & G
  short* wInB  = (short*)(ws + OFF_DELTA);             // read B; pk written E
  short* wXB   = (short*)(ws + OFF_DELTA + 2097152);   // read D; pk written E
  short* wOB   = (short*)(ws + OFF_FEAT);              // read H
  short* wCB   = (short*)(ws + OFF_PCONV);             // written cvt after feat_fill, read I
  short* xcB   = (short*)(ws + OFF_O1);                // written C, read D/E & G; o1B after
  short* oyB   = (short*)(ws + OFF_OUTY);              // written scan_fused, read G
  short* dtwB  = (short*)(ws + OFF_OUTY + 4194304);    // read E (region after oyB's 16MB)
  short* PB    = (short*)(ws + OFF_OUTY + 4194304 + 262144); // written D (MODE5), read E
  short* ygB   = (short*)(ws + OFF_DELTA);             // written G (pk dead), read H
  short* o1B   = (short*)(ws + OFF_O1);                // written H, read I

  // stage A: pyramid pooling (xT AFTER pconv: featB overlays pooled)
  pool0_kernel<<<Bsz*DIM, 256, 0, stream>>>(x, pool_w, pool_b, bn_g, bn_b, bn_m, bn_v, y0m);
  pool_avg_kernel<<<Bsz*Cin, 288, 0, stream>>>(x, pooled);
  pconv_kernel<<<Bsz*275, 128, 0, stream>>>(pooled, pool_w, pool_b, bn_g, bn_b, bn_m, bn_v, pconv);
  xT_kernel<<<dim3(16, 8, Bsz), 256, 0, stream>>>(x, featB);
  feat_fill<<<Bsz*Lsp, 256, 0, stream>>>(y0m, pconv, featB);

  // weight conversions: one fused launch (enqueued after feat_fill -> pconv dead)
  f2bf5_kernel<<<3776, 256, 0, stream>>>(in_proj_w, wInB, x_proj_w, wXB,
      out_proj_w, wOB, cbr_w, wCB, dt_w, dtwB);

  // stage B: in_proj GEMM (M=1024, N=4096, K=1024), bf16 out
  gemm_bf<1><<<dim3(32, 8, 1), 256, 0, stream>>>(featB, wInB, xzB, nullptr,
      1024, 4096, 1024, 1024, 1024, 0, 0, 0, 0, nullptr, nullptr);

  // stage C: depthwise conv + silu -> bf16
  dwconv_kernel<<<Bsz*Lsp, 256, 0, stream>>>(xzB, conv_w, conv_b, xcB);

  // stage D: x_proj GEMM -> P (f32) + PB (bf16) in one epilogue; then PS pack
  gemm_bf<5><<<dim3(3, 8, 1), 256, 0, stream>>>(xcB, wXB, P, nullptr,
      1024, PW, 2048, 2048, 2048, 0, 0, 0, 0, nullptr, PB);
  ps_build<<<16, 256, 0, stream>>>(P, PS);

  // stage E: delta as ONE z-batched GEMM (z=k): (M=1024, N=2048, K=64),
  // native-softplus epilogue packs (du|dl) bf16 into pk at scan-order rows
  gemm_bf<4><<<dim3(16, 8, KK), 256, 0, stream>>>(PB, dtwB, pk, dt_b,
      1024, DI, 64, PW, RR, 96, DI*RR, (unsigned)(Bsz*Lsp*DI), DI, xcB, nullptr);

  // stage F: fused chunked scan (phase1 + LDS combine + phase2, one launch)
  scan_fused<<<dim3(Bsz*KK, DI/16), 256, 0, stream>>>(pk, PS, A_logs, oyB);

  // stage G: combine + D*u + LN + gate -> bf16 (pk dead; ygB overlays it)
  combine_ln_kernel<<<Bsz*Lsp, 256, 0, stream>>>(oyB, xzB, xcB, Ds, ln_g, ln_b, ygB);

  // stage H: out_proj GEMM (M=1024, N=1024, K=2048), bf16 out
  gemm_bf<1><<<dim3(8, 8, 1), 256, 0, stream>>>(ygB, wOB, o1B, nullptr,
      1024, 1024, 2048, 2048, 2048, 0, 0, 0, 0, nullptr, nullptr);

  // stage I: cbr GEMM (M=1024, N=128, K=1024), f32 out + epilogue
  gemm_bf<0><<<dim3(1, 8, 1), 256, 0, stream>>>(o1B, wCB, o2, nullptr,
      1024, DIM, 1024, 1024, 1024, 0, 0, 0, 0, nullptr, nullptr);
  cbr_epilogue<<<(Bsz*DIM*Lsp)/256, 256, 0, stream>>>(o2, cbr_b, cbr_g, cbr_beta, cbr_m, cbr_v, out);
}